// Round 1
// baseline (5380.385 us; speedup 1.0000x reference)
//
#include <hip/hip_runtime.h>
#include <math.h>

// Problem constants: B=32, N=32, P=64, Q=32, A=24, M=4, L=768, K=2

// ---------------- small utility kernels ----------------

__global__ void w78_kernel(const float* __restrict__ W7, const float* __restrict__ W8,
                           float* __restrict__ W78) {
    int i = blockIdx.x * 256 + threadIdx.x;
    if (i < 768 * 768) W78[i] = W7[i] + W8[i];
}

// 1/max(||row||, eps) per row of a (rows x 768) matrix
__global__ void rnorm_kernel(const float* __restrict__ X, float* __restrict__ out) {
    long row = blockIdx.x;
    const float* xr = X + row * 768;
    int t = threadIdx.x;
    float ss = 0.f;
    for (int l = t; l < 768; l += 256) { float v = xr[l]; ss += v * v; }
    for (int o = 32; o; o >>= 1) ss += __shfl_xor(ss, o);
    __shared__ float red[4];
    if ((t & 63) == 0) red[t >> 6] = ss;
    __syncthreads();
    if (t == 0) {
        float tot = red[0] + red[1] + red[2] + red[3];
        out[row] = 1.f / fmaxf(sqrtf(tot), 1e-8f);
    }
}

// For (b,n): compute max over p (64 rows) of normalized dot(Hp[b,n,p], col_c) for 128 cols
// cols 0..95 = Ha rows, 96..127 = Hq rows. Writes amax[b,n,c].
__global__ void simmax_kernel(const float* __restrict__ Hp, const float* __restrict__ Ha,
                              const float* __restrict__ Hq,
                              const float* __restrict__ rp, const float* __restrict__ ra,
                              const float* __restrict__ rq, float* __restrict__ amax) {
    int b = blockIdx.x >> 5, n = blockIdx.x & 31;
    __shared__ float As[16][64];
    __shared__ float Bs[16][128];
    __shared__ float red[16][128];
    int t = threadIdx.x;
    const float* Ap  = Hp + ((long)b * 2048 + n * 64) * 768;
    const float* Hab = Ha + (long)b * 96 * 768;
    const float* Hqb = Hq + (long)b * 32 * 768;
    int tx = t & 15, ty = t >> 4;
    int arow = t >> 2, kof = (t & 3) << 2;
    int r2 = arow + 64;
    const float* p1 = Hab + (long)arow * 768;                      // rows 0..63 < 96 -> Ha
    const float* p2 = (r2 < 96) ? (Hab + (long)r2 * 768) : (Hqb + (long)(r2 - 96) * 768);
    float acc[4][8] = {{0.f}};
    for (int k0 = 0; k0 < 768; k0 += 16) {
        float4 av = *(const float4*)(Ap + (long)arow * 768 + k0 + kof);
        float4 b1 = *(const float4*)(p1 + k0 + kof);
        float4 b2 = *(const float4*)(p2 + k0 + kof);
        __syncthreads();
        As[kof + 0][arow] = av.x; As[kof + 1][arow] = av.y;
        As[kof + 2][arow] = av.z; As[kof + 3][arow] = av.w;
        Bs[kof + 0][arow] = b1.x; Bs[kof + 1][arow] = b1.y;
        Bs[kof + 2][arow] = b1.z; Bs[kof + 3][arow] = b1.w;
        Bs[kof + 0][r2]   = b2.x; Bs[kof + 1][r2]   = b2.y;
        Bs[kof + 2][r2]   = b2.z; Bs[kof + 3][r2]   = b2.w;
        __syncthreads();
#pragma unroll
        for (int kk = 0; kk < 16; kk++) {
            float a[4], bb[8];
#pragma unroll
            for (int i = 0; i < 4; i++) a[i] = As[kk][(ty << 2) + i];
#pragma unroll
            for (int j = 0; j < 8; j++) bb[j] = Bs[kk][(tx << 3) + j];
#pragma unroll
            for (int i = 0; i < 4; i++)
#pragma unroll
                for (int j = 0; j < 8; j++) acc[i][j] += a[i] * bb[j];
        }
    }
    float rpv[4];
#pragma unroll
    for (int i = 0; i < 4; i++) rpv[i] = rp[(long)b * 2048 + n * 64 + (ty << 2) + i];
#pragma unroll
    for (int j = 0; j < 8; j++) {
        int c = (tx << 3) + j;
        float rc = (c < 96) ? ra[b * 96 + c] : rq[b * 32 + (c - 96)];
        float mx = acc[0][j] * rpv[0];
#pragma unroll
        for (int i = 1; i < 4; i++) mx = fmaxf(mx, acc[i][j] * rpv[i]);
        red[ty][c] = mx * rc;  // rc > 0, so scaling after max is valid
    }
    __syncthreads();
    if (ty == 0) {
#pragma unroll
        for (int j = 0; j < 8; j++) {
            int c = (tx << 3) + j;
            float m = red[0][c];
            for (int yy = 1; yy < 16; yy++) m = fmaxf(m, red[yy][c]);
            amax[((long)b * 32 + n) * 128 + c] = m;
        }
    }
}

__global__ void score_kernel(const float* __restrict__ amax, float* __restrict__ score) {
    int b = blockIdx.x, n = threadIdx.x;  // block 32
    const float* am = amax + ((long)b * 32 + n) * 128;
    float sa = 0.f, sq = 0.f;
    for (int c = 0; c < 96; c++) sa += am[c];
    for (int c = 96; c < 128; c++) sq += am[c];
    score[b * 32 + n] = sa / 24.f + sq / 32.f;
}

__global__ void top2_kernel(const float* __restrict__ score, int* __restrict__ idx) {
    int b = blockIdx.x;
    const float* s = score + b * 32;
    float m0 = -1e30f; int i0 = 0;
    for (int n = 0; n < 32; n++) if (s[n] > m0) { m0 = s[n]; i0 = n; }
    float m1 = -1e30f; int i1 = 0;
    for (int n = 0; n < 32; n++) if (n != i0 && s[n] > m1) { m1 = s[n]; i1 = n; }
    idx[b * 2] = i0; idx[b * 2 + 1] = i1;
}

__global__ void gather_kernel(const float* __restrict__ Hp, const int* __restrict__ idx,
                              float* __restrict__ Hps) {
    long i = (long)blockIdx.x * 256 + threadIdx.x;
    if (i >= (long)32 * 128 * 768) return;
    int l = (int)(i % 768);
    long r = i / 768;
    int x = (int)(r % 128); int b = (int)(r / 128);
    int k = x >> 6, p = x & 63;
    int n = idx[b * 2 + k];
    Hps[i] = Hp[((long)b * 2048 + n * 64 + p) * 768 + l];
}

// ---------------- tiled fp32 GEMM: C = act(A @ W [+bias] [+C]) ----------------
// A: batched rows, row r -> (b = r/X, x = r%X), ptr = A + b*sA + x*Kdim. Output cols = 768.
template <int ACT, int BIASF, int ACCF>
__global__ void gemm_kernel(const float* __restrict__ A, long sA, int X, int Kdim,
                            const float* __restrict__ W, const float* __restrict__ bias,
                            float* __restrict__ C, long sC, int Mtot) {
    __shared__ float As[16][64];
    __shared__ float Ws[16][64];
    int t = threadIdx.x;
    int rowBase = blockIdx.x << 6;
    int colBase = blockIdx.y << 6;
    int tx = t & 15, ty = t >> 4;
    int lrow = t >> 2, kof = (t & 3) << 2;
    int grow = rowBase + lrow;
    const float* Arow = nullptr;
    if (grow < Mtot) {
        int b = grow / X, x = grow - b * X;
        Arow = A + (long)b * sA + (long)x * Kdim;
    }
    int wk = t >> 4, wc = (t & 15) << 2;
    float acc[4][4] = {{0.f}};
    for (int k0 = 0; k0 < Kdim; k0 += 16) {
        float4 av = make_float4(0.f, 0.f, 0.f, 0.f);
        if (Arow) av = *(const float4*)(Arow + k0 + kof);
        float4 wv = *(const float4*)(W + (long)(k0 + wk) * 768 + colBase + wc);
        __syncthreads();
        As[kof + 0][lrow] = av.x; As[kof + 1][lrow] = av.y;
        As[kof + 2][lrow] = av.z; As[kof + 3][lrow] = av.w;
        Ws[wk][wc + 0] = wv.x; Ws[wk][wc + 1] = wv.y;
        Ws[wk][wc + 2] = wv.z; Ws[wk][wc + 3] = wv.w;
        __syncthreads();
#pragma unroll
        for (int kk = 0; kk < 16; kk++) {
            float a[4], w4[4];
#pragma unroll
            for (int i = 0; i < 4; i++) a[i] = As[kk][(ty << 2) + i];
#pragma unroll
            for (int j = 0; j < 4; j++) w4[j] = Ws[kk][(tx << 2) + j];
#pragma unroll
            for (int i = 0; i < 4; i++)
#pragma unroll
                for (int j = 0; j < 4; j++) acc[i][j] += a[i] * w4[j];
        }
    }
#pragma unroll
    for (int i = 0; i < 4; i++) {
        int r = rowBase + (ty << 2) + i;
        if (r >= Mtot) continue;
        int b = r / X, x = r - b * X;
        float* Crow = C + (long)b * sC + (long)x * 768;
#pragma unroll
        for (int j = 0; j < 4; j++) {
            int c = colBase + (tx << 2) + j;
            float v = acc[i][j];
            if (BIASF) v += bias[c];
            if (ACCF) v += Crow[c];
            if (ACT) v = fmaxf(v, 0.f);
            Crow[c] = v;
        }
    }
}

// ---------------- fused attention row: E[x,:] = [relu] softmax_y(GL[x]·Hy[y]) @ Hy ----------------
template <int RELU>
__global__ void attn_kernel(const float* __restrict__ GL, long sGL,
                            const float* __restrict__ Hy, long sHy,
                            float* __restrict__ E, long sE, int rowLenE,
                            int X, int Ylen) {
    int b = blockIdx.x / X, x = blockIdx.x - b * X;
    __shared__ float q[768];
    __shared__ float s[128];
    int t = threadIdx.x;
    const float* qrow = GL + (long)b * sGL + (long)x * 768;
    for (int l = t; l < 768; l += 256) q[l] = qrow[l];
    __syncthreads();
    const float* Hyb = Hy + (long)b * sHy;
    int wid = t >> 6, lane = t & 63;
    for (int y = wid; y < Ylen; y += 4) {
        const float* hr = Hyb + (long)y * 768;
        float p = 0.f;
        for (int l = lane; l < 768; l += 64) p += q[l] * hr[l];
        for (int o = 32; o; o >>= 1) p += __shfl_xor(p, o);
        if (lane == 0) s[y] = p;
    }
    __syncthreads();
    if (t == 0) {
        float m = s[0];
        for (int y = 1; y < Ylen; y++) m = fmaxf(m, s[y]);
        float sum = 0.f;
        for (int y = 0; y < Ylen; y++) { float e = expf(s[y] - m); s[y] = e; sum += e; }
        float inv = 1.f / sum;
        for (int y = 0; y < Ylen; y++) s[y] *= inv;
    }
    __syncthreads();
    float* Erow = E + (long)b * sE + (long)x * rowLenE;
    for (int l = t; l < 768; l += 256) {
        float acc = 0.f;
        for (int y = 0; y < Ylen; y++) acc += s[y] * Hyb[(long)y * 768 + l];
        if (RELU) acc = fmaxf(acc, 0.f);
        Erow[l] = acc;
    }
}

// out[b,l] = max over x of T[b,x,l]
__global__ void colmax_kernel(const float* __restrict__ T, long sT, int X,
                              float* __restrict__ out) {
    int b = blockIdx.x;
    int l = blockIdx.y * 256 + threadIdx.x;
    const float* Tb = T + (long)b * sT;
    float m = Tb[l];
    for (int x = 1; x < X; x++) m = fmaxf(m, Tb[(long)x * 768 + l]);
    out[(long)b * 768 + l] = m;
}

// H_o[:,i] = g*Hi + (1-g)*bar, g = sigmoid(gt)
__global__ void hogate_kernel(const float* __restrict__ gt, const float* __restrict__ bar,
                              const float* __restrict__ Ha, int i, float* __restrict__ Ho) {
    long idx = (long)blockIdx.x * 256 + threadIdx.x;
    if (idx >= (long)32 * 24 * 768) return;
    int l = (int)(idx % 768);
    long r = idx / 768;
    int a = (int)(r % 24); int b = (int)(r / 24);
    float g = 1.f / (1.f + expf(-gt[idx]));
    float hi = Ha[((long)b * 96 + i * 24 + a) * 768 + l];
    float bv = bar[idx];
    Ho[(((long)b * 4 + i) * 24 + a) * 768 + l] = g * hi + (1.f - g) * bv;
}

__global__ void matchgate_kernel(const float* __restrict__ gt, const float* __restrict__ Sxy,
                                 const float* __restrict__ Syx, float* __restrict__ out,
                                 int sOut) {
    int idx = blockIdx.x * 256 + threadIdx.x;
    if (idx >= 32 * 768) return;
    int b = idx / 768, l = idx % 768;
    float g = 1.f / (1.f + expf(-gt[idx]));
    out[(long)b * sOut + l] = g * Sxy[idx] + (1.f - g) * Syx[idx];
}

__global__ void logits_kernel(const float* __restrict__ Mpq, const float* __restrict__ Mpo,
                              const float* __restrict__ Mqo, const float* __restrict__ V,
                              float* __restrict__ lg) {
    int blk = blockIdx.x; int b = blk >> 2, i = blk & 3;
    int t = threadIdx.x;
    float p = 0.f;
    for (int c = t; c < 768; c += 256) p += Mpq[(long)b * 768 + c] * V[c];
    for (int c = t; c < 768; c += 256) p += Mpo[((long)b * 4 + i) * 768 + c] * V[768 + c];
    for (int c = t; c < 768; c += 256) p += Mqo[((long)b * 4 + i) * 768 + c] * V[1536 + c];
    for (int o = 32; o; o >>= 1) p += __shfl_xor(p, o);
    __shared__ float red[4];
    if ((t & 63) == 0) red[t >> 6] = p;
    __syncthreads();
    if (t == 0) lg[blk] = red[0] + red[1] + red[2] + red[3];
}

__global__ void lsm_kernel(const float* __restrict__ lg, float* __restrict__ out) {
    int b = threadIdx.x;
    if (b >= 32) return;
    float x0 = lg[b * 4 + 0], x1 = lg[b * 4 + 1], x2 = lg[b * 4 + 2], x3 = lg[b * 4 + 3];
    float m = fmaxf(fmaxf(x0, x1), fmaxf(x2, x3));
    float s = expf(x0 - m) + expf(x1 - m) + expf(x2 - m) + expf(x3 - m);
    float ls = m + logf(s);
    out[b * 4 + 0] = x0 - ls; out[b * 4 + 1] = x1 - ls;
    out[b * 4 + 2] = x2 - ls; out[b * 4 + 3] = x3 - ls;
}

// ---------------- host orchestration ----------------

extern "C" void kernel_launch(void* const* d_in, const int* in_sizes, int n_in,
                              void* d_out, int out_size, void* d_ws, size_t ws_size,
                              hipStream_t stream) {
    const float* Hp  = (const float*)d_in[0];
    const float* Hq  = (const float*)d_in[1];
    const float* Ha  = (const float*)d_in[2];
    const float* W5  = (const float*)d_in[3];
    const float* W6  = (const float*)d_in[4];
    const float* W7  = (const float*)d_in[5];
    const float* W8  = (const float*)d_in[6];
    const float* b8  = (const float*)d_in[7];
    const float* W9  = (const float*)d_in[8];
    const float* W10 = (const float*)d_in[9];
    const float* W11 = (const float*)d_in[10];
    const float* W12 = (const float*)d_in[11];
    const float* W13 = (const float*)d_in[12];
    const float* W14 = (const float*)d_in[13];
    const float* b14 = (const float*)d_in[14];
    const float* V   = (const float*)d_in[15];
    float* out = (float*)d_out;

    float* w = (float*)d_ws;
    size_t off = 0;
    auto alloc = [&](size_t nf) { float* p = w + off; off += nf; return p; };
    float* W78   = alloc((size_t)768 * 768);
    float* rp    = alloc((size_t)32 * 2048);
    float* ra    = alloc((size_t)32 * 96);
    float* rq    = alloc((size_t)32 * 32);
    float* amax  = alloc((size_t)32 * 32 * 128);
    float* score = alloc((size_t)32 * 32);
    int*   topidx= (int*)alloc(64);
    float* Hps   = alloc((size_t)32 * 128 * 768);
    float* Ho    = alloc((size_t)32 * 4 * 24 * 768);
    float* c1i   = alloc((size_t)32 * 24 * 768);
    float* hats  = alloc((size_t)32 * 24 * 2304);
    float* bar   = alloc((size_t)32 * 24 * 768);
    float* gt    = alloc((size_t)32 * 24 * 768);
    float* cache1= alloc((size_t)32 * 128 * 768);
    float* cache2= alloc((size_t)32 * 32 * 768);
    float* cache3= alloc((size_t)32 * 32 * 768);
    float* cache4= alloc((size_t)32 * 24 * 768);
    float* Ex    = alloc((size_t)32 * 128 * 768);
    float* Ey    = alloc((size_t)32 * 32 * 768);
    float* TX    = alloc((size_t)32 * 128 * 768);
    float* TY    = alloc((size_t)32 * 32 * 768);
    float* Sxy   = alloc((size_t)32 * 768);
    float* Syx   = alloc((size_t)32 * 768);
    float* gts   = alloc((size_t)32 * 768);
    float* Mpq   = alloc((size_t)32 * 768);
    float* Mpo   = alloc((size_t)32 * 4 * 768);
    float* Mqo   = alloc((size_t)32 * 4 * 768);
    float* lg    = alloc(128);
    (void)ws_size; (void)in_sizes; (void)n_in; (void)out_size;

    dim3 blk(256);

    // ---- stage 1: scoring + top-2 selection ----
    w78_kernel<<<(768 * 768 + 255) / 256, blk, 0, stream>>>(W7, W8, W78);
    rnorm_kernel<<<32 * 2048, blk, 0, stream>>>(Hp, rp);
    rnorm_kernel<<<32 * 96, blk, 0, stream>>>(Ha, ra);
    rnorm_kernel<<<32 * 32, blk, 0, stream>>>(Hq, rq);
    simmax_kernel<<<32 * 32, blk, 0, stream>>>(Hp, Ha, Hq, rp, ra, rq, amax);
    score_kernel<<<32, dim3(32), 0, stream>>>(amax, score);
    top2_kernel<<<32, dim3(1), 0, stream>>>(score, topidx);
    gather_kernel<<<(32 * 128 * 768 + 255) / 256, blk, 0, stream>>>(Hp, topidx, Hps);

    // ---- stage 2: H_o (gated cross-attention fusion over M=4) ----
    for (int i = 0; i < 4; i++) {
        gemm_kernel<0, 0, 0><<<dim3(12, 12), blk, 0, stream>>>(
            Ha + (long)i * 24 * 768, (long)96 * 768, 24, 768, W5, nullptr,
            c1i, (long)24 * 768, 768);
        int jj = 0;
        for (int j = 0; j < 4; j++) {
            if (j == i) continue;
            attn_kernel<1><<<32 * 24, blk, 0, stream>>>(
                c1i, (long)24 * 768, Ha + (long)j * 24 * 768, (long)96 * 768,
                hats + jj * 768, (long)24 * 2304, 2304, 24, 24);
            jj++;
        }
        gemm_kernel<0, 0, 0><<<dim3(12, 12), blk, 0, stream>>>(
            hats, (long)24 * 2304, 24, 2304, W6, nullptr, bar, (long)24 * 768, 768);
        gemm_kernel<0, 1, 0><<<dim3(12, 12), blk, 0, stream>>>(
            bar, (long)24 * 768, 24, 768, W78, b8, gt, (long)24 * 768, 768);
        hogate_kernel<<<(32 * 24 * 768 + 255) / 256, blk, 0, stream>>>(gt, bar, Ha, i, Ho);
    }

    // ---- stage 3: matching caches ----
    gemm_kernel<0, 0, 0><<<dim3(64, 12), blk, 0, stream>>>(
        Hps, (long)128 * 768, 128, 768, W9, nullptr, cache1, (long)128 * 768, 4096);
    gemm_kernel<0, 0, 0><<<dim3(16, 12), blk, 0, stream>>>(
        Hq, (long)32 * 768, 32, 768, W9, nullptr, cache2, (long)32 * 768, 1024);
    gemm_kernel<0, 0, 0><<<dim3(16, 12), blk, 0, stream>>>(
        Hq, (long)32 * 768, 32, 768, W10, nullptr, cache3, (long)32 * 768, 1024);

    auto do_match = [&](const float* Hx, long sHx, int X,
                        const float* Hy, long sHy, int Y,
                        const float* GLx, long sGLx,
                        const float* GRy, long sGRy,
                        float* Mout, int sOut) {
        attn_kernel<0><<<32 * X, blk, 0, stream>>>(GLx, sGLx, Hy, sHy,
                                                   Ex, (long)X * 768, 768, X, Y);
        attn_kernel<0><<<32 * Y, blk, 0, stream>>>(GRy, sGRy, Hx, sHx,
                                                   Ey, (long)Y * 768, 768, Y, X);
        gemm_kernel<1, 0, 0><<<dim3((32 * X + 63) / 64, 12), blk, 0, stream>>>(
            Ex, (long)X * 768, X, 768, W11, nullptr, TX, (long)X * 768, 32 * X);
        gemm_kernel<1, 0, 0><<<dim3((32 * Y + 63) / 64, 12), blk, 0, stream>>>(
            Ey, (long)Y * 768, Y, 768, W12, nullptr, TY, (long)Y * 768, 32 * Y);
        colmax_kernel<<<dim3(32, 3), blk, 0, stream>>>(TX, (long)X * 768, X, Sxy);
        colmax_kernel<<<dim3(32, 3), blk, 0, stream>>>(TY, (long)Y * 768, Y, Syx);
        gemm_kernel<0, 0, 0><<<dim3(1, 12), blk, 0, stream>>>(
            Sxy, 768L, 1, 768, W13, nullptr, gts, 768L, 32);
        gemm_kernel<0, 1, 1><<<dim3(1, 12), blk, 0, stream>>>(
            Syx, 768L, 1, 768, W14, b14, gts, 768L, 32);
        matchgate_kernel<<<96, blk, 0, stream>>>(gts, Sxy, Syx, Mout, sOut);
    };

    // M_pq = match(H_p_s, H_q, cache1, cache3)
    do_match(Hps, (long)128 * 768, 128, Hq, (long)32 * 768, 32,
             cache1, (long)128 * 768, cache3, (long)32 * 768, Mpq, 768);

    for (int i = 0; i < 4; i++) {
        const float* Hoi = Ho + (long)i * 24 * 768;
        long sHo = (long)4 * 24 * 768;
        gemm_kernel<0, 0, 0><<<dim3(12, 12), blk, 0, stream>>>(
            Hoi, sHo, 24, 768, W10, nullptr, cache4, (long)24 * 768, 768);
        // M_po_i = match(H_p_s, H_o_i, cache1, cache4)
        do_match(Hps, (long)128 * 768, 128, Hoi, sHo, 24,
                 cache1, (long)128 * 768, cache4, (long)24 * 768, Mpo + i * 768, 4 * 768);
        // M_qo_i = match(H_q, H_o_i, cache2, cache4)
        do_match(Hq, (long)32 * 768, 32, Hoi, sHo, 24,
                 cache2, (long)32 * 768, cache4, (long)24 * 768, Mqo + i * 768, 4 * 768);
    }

    // ---- stage 4: logits + log_softmax ----
    logits_kernel<<<128, blk, 0, stream>>>(Mpq, Mpo, Mqo, V, lg);
    lsm_kernel<<<1, dim3(32), 0, stream>>>(lg, out);
}

// Round 2
// 1450.862 us; speedup vs baseline: 3.7084x; 3.7084x over previous
//
#include <hip/hip_runtime.h>
#include <math.h>

// B=32, N=32, P=64, Q=32, A=24, M=4, L=768, K=2

// ---------------- prep: concatenated weights ----------------
__global__ void prep_kernel(const float* __restrict__ W7, const float* __restrict__ W8,
                            const float* __restrict__ W9, const float* __restrict__ W10,
                            const float* __restrict__ W11, const float* __restrict__ W12,
                            const float* __restrict__ W13, const float* __restrict__ W14,
                            float* __restrict__ W78, float* __restrict__ WqCat,
                            float* __restrict__ WpsCat, float* __restrict__ WhoCat,
                            float* __restrict__ W1314) {
    long i = (long)blockIdx.x * 256 + threadIdx.x;
    const long n0 = 589824, n1 = 2359296, n2 = 1179648, n3 = 1179648, n4 = 1179648;
    if (i < n0) { W78[i] = W7[i] + W8[i]; return; } i -= n0;
    if (i < n1) {
        int r = (int)(i / 3072), c = (int)(i % 3072); float v;
        if (c < 768) v = W9[r * 768 + c];
        else if (c < 1536) v = W10[r * 768 + c - 768];
        else if (c < 2304) v = W11[r * 768 + c - 1536];
        else v = W12[r * 768 + c - 2304];
        WqCat[i] = v; return;
    } i -= n1;
    if (i < n2) {
        int r = (int)(i / 1536), c = (int)(i % 1536);
        WpsCat[i] = (c < 768) ? W9[r * 768 + c] : W12[r * 768 + c - 768]; return;
    } i -= n2;
    if (i < n3) {
        int r = (int)(i / 1536), c = (int)(i % 1536);
        WhoCat[i] = (c < 768) ? W10[r * 768 + c] : W11[r * 768 + c - 768]; return;
    } i -= n3;
    if (i < n4) {
        int r = (int)(i / 768), c = (int)(i % 768);
        W1314[i] = (r < 768) ? W13[r * 768 + c] : W14[(r - 768) * 768 + c];
    }
}

// ---------------- stage 1: scoring ----------------
__global__ void rnorm_kernel(const float* __restrict__ X, float* __restrict__ out) {
    long row = blockIdx.x;
    const float* xr = X + row * 768;
    int t = threadIdx.x;
    float ss = 0.f;
    for (int l = t; l < 768; l += 256) { float v = xr[l]; ss += v * v; }
    for (int o = 32; o; o >>= 1) ss += __shfl_xor(ss, o);
    __shared__ float red[4];
    if ((t & 63) == 0) red[t >> 6] = ss;
    __syncthreads();
    if (t == 0) {
        float tot = red[0] + red[1] + red[2] + red[3];
        out[row] = 1.f / fmaxf(sqrtf(tot), 1e-8f);
    }
}

__global__ void simmax_kernel(const float* __restrict__ Hp, const float* __restrict__ Ha,
                              const float* __restrict__ Hq,
                              const float* __restrict__ rp, const float* __restrict__ ra,
                              const float* __restrict__ rq, float* __restrict__ amax) {
    int b = blockIdx.x >> 5, n = blockIdx.x & 31;
    __shared__ float As[16][64];
    __shared__ float Bs[16][128];
    __shared__ float red[16][128];
    int t = threadIdx.x;
    const float* Ap  = Hp + ((long)b * 2048 + n * 64) * 768;
    const float* Hab = Ha + (long)b * 96 * 768;
    const float* Hqb = Hq + (long)b * 32 * 768;
    int tx = t & 15, ty = t >> 4;
    int arow = t >> 2, kof = (t & 3) << 2;
    int r2 = arow + 64;
    const float* p1 = Hab + (long)arow * 768;
    const float* p2 = (r2 < 96) ? (Hab + (long)r2 * 768) : (Hqb + (long)(r2 - 96) * 768);
    float acc[4][8] = {{0.f}};
    for (int k0 = 0; k0 < 768; k0 += 16) {
        float4 av = *(const float4*)(Ap + (long)arow * 768 + k0 + kof);
        float4 b1 = *(const float4*)(p1 + k0 + kof);
        float4 b2 = *(const float4*)(p2 + k0 + kof);
        __syncthreads();
        As[kof + 0][arow] = av.x; As[kof + 1][arow] = av.y;
        As[kof + 2][arow] = av.z; As[kof + 3][arow] = av.w;
        Bs[kof + 0][arow] = b1.x; Bs[kof + 1][arow] = b1.y;
        Bs[kof + 2][arow] = b1.z; Bs[kof + 3][arow] = b1.w;
        Bs[kof + 0][r2]   = b2.x; Bs[kof + 1][r2]   = b2.y;
        Bs[kof + 2][r2]   = b2.z; Bs[kof + 3][r2]   = b2.w;
        __syncthreads();
#pragma unroll
        for (int kk = 0; kk < 16; kk++) {
            float a[4], bb[8];
#pragma unroll
            for (int i = 0; i < 4; i++) a[i] = As[kk][(ty << 2) + i];
#pragma unroll
            for (int j = 0; j < 8; j++) bb[j] = Bs[kk][tx + 16 * j];  // conflict-free
#pragma unroll
            for (int i = 0; i < 4; i++)
#pragma unroll
                for (int j = 0; j < 8; j++) acc[i][j] += a[i] * bb[j];
        }
    }
    float rpv[4];
#pragma unroll
    for (int i = 0; i < 4; i++) rpv[i] = rp[(long)b * 2048 + n * 64 + (ty << 2) + i];
#pragma unroll
    for (int j = 0; j < 8; j++) {
        int c = tx + 16 * j;
        float rc = (c < 96) ? ra[b * 96 + c] : rq[b * 32 + (c - 96)];
        float mx = acc[0][j] * rpv[0];
#pragma unroll
        for (int i = 1; i < 4; i++) mx = fmaxf(mx, acc[i][j] * rpv[i]);
        red[ty][c] = mx * rc;
    }
    __syncthreads();
    if (ty == 0) {
#pragma unroll
        for (int j = 0; j < 8; j++) {
            int c = tx + 16 * j;
            float m = red[0][c];
            for (int yy = 1; yy < 16; yy++) m = fmaxf(m, red[yy][c]);
            amax[((long)b * 32 + n) * 128 + c] = m;
        }
    }
}

__global__ void score_top2_kernel(const float* __restrict__ amax, int* __restrict__ idx) {
    int b = blockIdx.x, t = threadIdx.x;
    __shared__ float sc[32];
    if (t < 32) {
        const float* am = amax + ((long)b * 32 + t) * 128;
        float sa = 0.f, sq = 0.f;
        for (int c = 0; c < 96; c++) sa += am[c];
        for (int c = 96; c < 128; c++) sq += am[c];
        sc[t] = sa / 24.f + sq / 32.f;
    }
    __syncthreads();
    if (t == 0) {
        float m0 = -1e30f; int i0 = 0;
        for (int n = 0; n < 32; n++) if (sc[n] > m0) { m0 = sc[n]; i0 = n; }
        float m1 = -1e30f; int i1 = 0;
        for (int n = 0; n < 32; n++) if (n != i0 && sc[n] > m1) { m1 = sc[n]; i1 = n; }
        idx[b * 2] = i0; idx[b * 2 + 1] = i1;
    }
}

__global__ void gather_kernel(const float* __restrict__ Hp, const int* __restrict__ idx,
                              float* __restrict__ Hps) {
    long i = (long)blockIdx.x * 256 + threadIdx.x;
    if (i >= (long)32 * 128 * 768) return;
    int l = (int)(i % 768);
    long r = i / 768;
    int x = (int)(r % 128); int b = (int)(r / 128);
    int k = x >> 6, p = x & 63;
    int n = idx[b * 2 + k];
    Hps[i] = Hp[((long)b * 2048 + n * 64 + p) * 768 + l];
}

// ---------------- tiled fp32 GEMM: C = A @ W [+bias], output cols via grid.y ----------------
template <int BIASF>
__global__ void gemm_kernel(const float* __restrict__ A, int lda, int Kdim,
                            const float* __restrict__ W, int ldw,
                            const float* __restrict__ bias,
                            float* __restrict__ C, int ldc, int Mtot) {
    __shared__ float As[16][64];
    __shared__ float Ws[16][64];
    int t = threadIdx.x;
    int rowBase = blockIdx.x << 6;
    int colBase = blockIdx.y << 6;
    int tx = t & 15, ty = t >> 4;
    int lrow = t >> 2, kof = (t & 3) << 2;
    int grow = rowBase + lrow;
    const float* Arow = (grow < Mtot) ? (A + (long)grow * lda) : nullptr;
    int wk = t >> 4, wc = (t & 15) << 2;
    float acc[4][4] = {{0.f}};
    for (int k0 = 0; k0 < Kdim; k0 += 16) {
        float4 av = make_float4(0.f, 0.f, 0.f, 0.f);
        if (Arow) av = *(const float4*)(Arow + k0 + kof);
        float4 wv = *(const float4*)(W + (long)(k0 + wk) * ldw + colBase + wc);
        __syncthreads();
        As[kof + 0][lrow] = av.x; As[kof + 1][lrow] = av.y;
        As[kof + 2][lrow] = av.z; As[kof + 3][lrow] = av.w;
        Ws[wk][wc + 0] = wv.x; Ws[wk][wc + 1] = wv.y;
        Ws[wk][wc + 2] = wv.z; Ws[wk][wc + 3] = wv.w;
        __syncthreads();
#pragma unroll
        for (int kk = 0; kk < 16; kk++) {
            float a[4], w4[4];
#pragma unroll
            for (int i = 0; i < 4; i++) a[i] = As[kk][(ty << 2) + i];
#pragma unroll
            for (int j = 0; j < 4; j++) w4[j] = Ws[kk][(tx << 2) + j];
#pragma unroll
            for (int i = 0; i < 4; i++)
#pragma unroll
                for (int j = 0; j < 4; j++) acc[i][j] += a[i] * w4[j];
        }
    }
#pragma unroll
    for (int i = 0; i < 4; i++) {
        int r = rowBase + (ty << 2) + i;
        if (r >= Mtot) continue;
        float* Crow = C + (long)r * ldc;
#pragma unroll
        for (int j = 0; j < 4; j++) {
            int c = colBase + (tx << 2) + j;
            float v = acc[i][j];
            if (BIASF) v += bias[c];
            Crow[c] = v;
        }
    }
}

// ---------------- batched QK + softmax kernels ----------------
struct QSegT {
    const float* GL; const float* HY; float* G;
    long glB, hyB, gB;
    int ldGL, ldHY, X, Y;
};
struct QArgs { QSegT s[13]; };

// variant A: X<=128, Y<=32
__global__ __launch_bounds__(256) void qkA_kernel(QArgs args) {
    int seg = blockIdx.x >> 5, b = blockIdx.x & 31;
    QSegT sg = args.s[seg];
    __shared__ float As[16][128];
    __shared__ float Bs[16][32];
    __shared__ float sc[128 * 33];
    int t = threadIdx.x;
    int arow = t >> 1, akof = (t & 1) * 8;
    int brow = t >> 3, bkof = (t & 7) * 2;
    bool aok = arow < sg.X, bok = brow < sg.Y;
    const float* ga = sg.GL + (long)b * sg.glB + (long)arow * sg.ldGL;
    const float* hb = sg.HY + (long)b * sg.hyB + (long)brow * sg.ldHY;
    int tx = t & 63, ty = t >> 6;
    float acc0[8] = {0.f}, acc1[8] = {0.f};
    for (int k0 = 0; k0 < 768; k0 += 16) {
        float4 a0 = make_float4(0, 0, 0, 0), a1 = make_float4(0, 0, 0, 0);
        float b0 = 0.f, b1v = 0.f;
        if (aok) { a0 = *(const float4*)(ga + k0 + akof); a1 = *(const float4*)(ga + k0 + akof + 4); }
        if (bok) { b0 = hb[k0 + bkof]; b1v = hb[k0 + bkof + 1]; }
        __syncthreads();
        As[akof + 0][arow] = a0.x; As[akof + 1][arow] = a0.y;
        As[akof + 2][arow] = a0.z; As[akof + 3][arow] = a0.w;
        As[akof + 4][arow] = a1.x; As[akof + 5][arow] = a1.y;
        As[akof + 6][arow] = a1.z; As[akof + 7][arow] = a1.w;
        Bs[bkof][brow] = b0; Bs[bkof + 1][brow] = b1v;
        __syncthreads();
#pragma unroll
        for (int kk = 0; kk < 16; kk++) {
            float alo = As[kk][tx], ahi = As[kk][tx + 64];
#pragma unroll
            for (int j = 0; j < 8; j++) {
                float bv = Bs[kk][ty * 8 + j];
                acc0[j] += alo * bv; acc1[j] += ahi * bv;
            }
        }
    }
#pragma unroll
    for (int j = 0; j < 8; j++) {
        sc[tx * 33 + ty * 8 + j] = acc0[j];
        sc[(tx + 64) * 33 + ty * 8 + j] = acc1[j];
    }
    __syncthreads();
    if (t < sg.X) {
        float* row = sc + t * 33;
        int Y = sg.Y;
        float m = row[0];
        for (int y = 1; y < Y; y++) m = fmaxf(m, row[y]);
        float s = 0.f;
        for (int y = 0; y < Y; y++) { float e = expf(row[y] - m); row[y] = e; s += e; }
        float inv = 1.f / s;
        float* go = sg.G + (long)b * sg.gB + (long)t * Y;
        for (int y = 0; y < Y; y++) go[y] = row[y] * inv;
    }
}

// variant B: X<=32, Y==128
__global__ __launch_bounds__(256) void qkB_kernel(QArgs args) {
    int seg = blockIdx.x >> 5, b = blockIdx.x & 31;
    QSegT sg = args.s[seg];
    __shared__ float As[16][32];
    __shared__ float Bs[16][128];
    __shared__ float sc[32 * 129];
    int t = threadIdx.x;
    int arow = t >> 3, akof = (t & 7) * 2;
    int brow = t >> 1, bkof = (t & 1) * 8;
    bool aok = arow < sg.X;
    const float* ga = sg.GL + (long)b * sg.glB + (long)arow * sg.ldGL;
    const float* hb = sg.HY + (long)b * sg.hyB + (long)brow * sg.ldHY;
    int tx = t & 31, grp = t >> 5;
    float acc[16] = {0.f};
    for (int k0 = 0; k0 < 768; k0 += 16) {
        float a0 = 0.f, a1 = 0.f;
        if (aok) { a0 = ga[k0 + akof]; a1 = ga[k0 + akof + 1]; }
        float4 b0 = *(const float4*)(hb + k0 + bkof);
        float4 b1 = *(const float4*)(hb + k0 + bkof + 4);
        __syncthreads();
        As[akof][arow] = a0; As[akof + 1][arow] = a1;
        Bs[bkof + 0][brow] = b0.x; Bs[bkof + 1][brow] = b0.y;
        Bs[bkof + 2][brow] = b0.z; Bs[bkof + 3][brow] = b0.w;
        Bs[bkof + 4][brow] = b1.x; Bs[bkof + 5][brow] = b1.y;
        Bs[bkof + 6][brow] = b1.z; Bs[bkof + 7][brow] = b1.w;
        __syncthreads();
#pragma unroll
        for (int kk = 0; kk < 16; kk++) {
            float a = As[kk][tx];
#pragma unroll
            for (int j = 0; j < 16; j++) acc[j] += a * Bs[kk][grp * 16 + j];
        }
    }
#pragma unroll
    for (int j = 0; j < 16; j++) sc[tx * 129 + grp * 16 + j] = acc[j];
    __syncthreads();
    int row = t >> 3, lane = t & 7;
    if (row < sg.X) {
        float m = -1e30f;
        for (int k = 0; k < 16; k++) m = fmaxf(m, sc[row * 129 + lane + 8 * k]);
        for (int o = 1; o < 8; o <<= 1) m = fmaxf(m, __shfl_xor(m, o));
        float s = 0.f;
        for (int k = 0; k < 16; k++) {
            float e = expf(sc[row * 129 + lane + 8 * k] - m);
            sc[row * 129 + lane + 8 * k] = e; s += e;
        }
        for (int o = 1; o < 8; o <<= 1) s += __shfl_xor(s, o);
        float inv = 1.f / s;
        float* go = sg.G + (long)b * sg.gB + (long)row * 128;
        for (int k = 0; k < 16; k++) go[lane + 8 * k] = sc[row * 129 + lane + 8 * k] * inv;
    }
}

// ---------------- batched G@B: rows (relu) or max-reduced row ----------------
struct SSegT {
    const float* G; const float* B; float* out;
    long gB, bB, oB;
    int ldB, ldO, R, C, mode;  // mode 1: out[l] = max_r relu(sum_c G[r,c]B[c,l]); mode 0: store rows
};
struct SArgs { SSegT s[18]; };

__global__ __launch_bounds__(256) void gb_kernel(SArgs args) {
    int seg = blockIdx.x >> 5, b = blockIdx.x & 31;
    SSegT sg = args.s[seg];
    __shared__ float Gs[4096];
    int t = threadIdx.x;
    int n = sg.R * sg.C;
    for (int i = t; i < n; i += 256) Gs[i] = sg.G[(long)b * sg.gB + i];
    __syncthreads();
    const float* Bb = sg.B + (long)b * sg.bB;
    int C = sg.C, R = sg.R;
    for (int l0 = 0; l0 < 768; l0 += 256) {
        int l = l0 + t;
        if (sg.mode) {
            float mx = 0.f;
            for (int rb = 0; rb < R; rb += 8) {
                float a[8] = {0.f};
                for (int c = 0; c < C; c++) {
                    float bv = Bb[(long)c * sg.ldB + l];
#pragma unroll
                    for (int r8 = 0; r8 < 8; r8++) a[r8] += Gs[(rb + r8) * C + c] * bv;
                }
#pragma unroll
                for (int r8 = 0; r8 < 8; r8++) mx = fmaxf(mx, a[r8]);
            }
            sg.out[(long)b * sg.oB + l] = mx;
        } else {
            for (int rb = 0; rb < R; rb += 8) {
                float a[8] = {0.f};
                for (int c = 0; c < C; c++) {
                    float bv = Bb[(long)c * sg.ldB + l];
#pragma unroll
                    for (int r8 = 0; r8 < 8; r8++) a[r8] += Gs[(rb + r8) * C + c] * bv;
                }
#pragma unroll
                for (int r8 = 0; r8 < 8; r8++)
                    sg.out[(long)b * sg.oB + (long)(rb + r8) * sg.ldO + l] = fmaxf(a[r8], 0.f);
            }
        }
    }
}

// ---------------- elementwise ----------------
__global__ void hogate_kernel(const float* __restrict__ gt, const float* __restrict__ bar,
                              const float* __restrict__ Ha, float* __restrict__ Ho) {
    long idx = (long)blockIdx.x * 256 + threadIdx.x;
    if (idx >= (long)32 * 96 * 768) return;
    float g = 1.f / (1.f + expf(-gt[idx]));
    Ho[idx] = g * Ha[idx] + (1.f - g) * bar[idx];
}

__global__ void logits_kernel(const float* __restrict__ S, const float* __restrict__ gts,
                              const float* __restrict__ V, float* __restrict__ lg) {
    int blk = blockIdx.x; int b = blk >> 2, i = blk & 3;
    int t = threadIdx.x;
    int ms[3] = {0, 1 + i, 5 + i};
    float p = 0.f;
    for (int k = 0; k < 3; k++) {
        int m = ms[k];
        const float* Sr = S + (long)m * 49152 + (long)b * 1536;
        const float* gr = gts + ((long)m * 32 + b) * 768;
        const float* Vr = V + k * 768;
        for (int l = t; l < 768; l += 256) {
            float g = 1.f / (1.f + expf(-gr[l]));
            p += (g * Sr[l] + (1.f - g) * Sr[768 + l]) * Vr[l];
        }
    }
    for (int o = 32; o; o >>= 1) p += __shfl_xor(p, o);
    __shared__ float red[4];
    if ((t & 63) == 0) red[t >> 6] = p;
    __syncthreads();
    if (t == 0) lg[blk] = red[0] + red[1] + red[2] + red[3];
}

__global__ void lsm_kernel(const float* __restrict__ lg, float* __restrict__ out) {
    int b = threadIdx.x;
    if (b >= 32) return;
    float x0 = lg[b * 4 + 0], x1 = lg[b * 4 + 1], x2 = lg[b * 4 + 2], x3 = lg[b * 4 + 3];
    float m = fmaxf(fmaxf(x0, x1), fmaxf(x2, x3));
    float s = expf(x0 - m) + expf(x1 - m) + expf(x2 - m) + expf(x3 - m);
    float ls = m + logf(s);
    out[b * 4 + 0] = x0 - ls; out[b * 4 + 1] = x1 - ls;
    out[b * 4 + 2] = x2 - ls; out[b * 4 + 3] = x3 - ls;
}

// ---------------- host ----------------
extern "C" void kernel_launch(void* const* d_in, const int* in_sizes, int n_in,
                              void* d_out, int out_size, void* d_ws, size_t ws_size,
                              hipStream_t stream) {
    const float* Hp  = (const float*)d_in[0];
    const float* Hq  = (const float*)d_in[1];
    const float* Ha  = (const float*)d_in[2];
    const float* W5  = (const float*)d_in[3];
    const float* W6  = (const float*)d_in[4];
    const float* W7  = (const float*)d_in[5];
    const float* W8  = (const float*)d_in[6];
    const float* b8  = (const float*)d_in[7];
    const float* W9  = (const float*)d_in[8];
    const float* W10 = (const float*)d_in[9];
    const float* W11 = (const float*)d_in[10];
    const float* W12 = (const float*)d_in[11];
    const float* W13 = (const float*)d_in[12];
    const float* W14 = (const float*)d_in[13];
    const float* b14 = (const float*)d_in[14];
    const float* V   = (const float*)d_in[15];
    float* out = (float*)d_out;
    (void)in_sizes; (void)n_in; (void)out_size; (void)ws_size;

    float* w = (float*)d_ws;
    size_t off = 0;
    auto alloc = [&](size_t nf) { float* p = w + off; off += nf; return p; };
    float* W78    = alloc(589824);
    float* WqCat  = alloc(2359296);
    float* WpsCat = alloc(1179648);
    float* WhoCat = alloc(1179648);
    float* W1314  = alloc(1179648);
    float* rp     = alloc(65536);
    float* ra     = alloc(3072);
    float* rq     = alloc(1024);
    float* amax   = alloc(131072);
    int*   topidx = (int*)alloc(64);
    float* Hps    = alloc(3145728);
    float* HpsCat = alloc(6291456);   // [cache1 | HpsW12], ld 1536
    float* HqCat  = alloc(3145728);   // [cache2 | cache3 | HqW11 | HqW12], ld 3072
    float* C1     = alloc(2359296);   // Ha@W5; later reused as gt
    float* G2     = alloc(221184);
    float* BIG    = alloc(7077888);   // hats; then {HoCat, Gm, S, gts}
    float* bar    = alloc(2359296);
    float* Ho     = alloc(2359296);
    float* lg     = alloc(128);

    float* hats  = BIG;
    float* HoCat = BIG;                       // 3072 x 1536 = 4718592  [cache4 | HoW11]
    float* Gm    = BIG + 4718592;             // match G buffers
    float* S     = BIG + 5996544;             // 9 x 32 x 1536
    float* gts   = BIG + 6438912;             // 288 x 768
    float* gt    = C1;

    dim3 blk(256);

    // stage 1
    prep_kernel<<<25344, blk, 0, stream>>>(W7, W8, W9, W10, W11, W12, W13, W14,
                                           W78, WqCat, WpsCat, WhoCat, W1314);
    rnorm_kernel<<<65536, blk, 0, stream>>>(Hp, rp);
    rnorm_kernel<<<3072, blk, 0, stream>>>(Ha, ra);
    rnorm_kernel<<<1024, blk, 0, stream>>>(Hq, rq);
    simmax_kernel<<<1024, blk, 0, stream>>>(Hp, Ha, Hq, rp, ra, rq, amax);
    score_top2_kernel<<<32, dim3(64), 0, stream>>>(amax, topidx);
    gather_kernel<<<12288, blk, 0, stream>>>(Hp, topidx, Hps);

    // stage 2: C1 = Ha@W5
    gemm_kernel<0><<<dim3(48, 12), blk, 0, stream>>>(Ha, 768, 768, W5, 768, nullptr, C1, 768, 3072);

    // stage-2 QK (12 segs, 24x24)
    {
        QArgs qa; int si = 0;
        for (int i = 0; i < 4; i++)
            for (int j = 0; j < 4; j++) {
                if (j == i) continue;
                QSegT& s = qa.s[si];
                s.GL = C1 + (long)i * 24 * 768; s.glB = 96 * 768; s.ldGL = 768;
                s.HY = Ha + (long)j * 24 * 768; s.hyB = 96 * 768; s.ldHY = 768;
                s.G = G2 + (long)si * 18432; s.gB = 576;
                s.X = 24; s.Y = 24;
                si++;
            }
        qkA_kernel<<<12 * 32, blk, 0, stream>>>(qa);
    }
    // hats (12 segs, rows mode)
    {
        SArgs sa; int si = 0;
        for (int i = 0; i < 4; i++) {
            int jj = 0;
            for (int j = 0; j < 4; j++) {
                if (j == i) continue;
                SSegT& s = sa.s[si];
                s.G = G2 + (long)si * 18432; s.gB = 576;
                s.B = Ha + (long)j * 24 * 768; s.bB = 96 * 768; s.ldB = 768;
                s.out = hats + (long)i * 24 * 2304 + jj * 768; s.oB = (long)96 * 2304; s.ldO = 2304;
                s.R = 24; s.C = 24; s.mode = 0;
                si++; jj++;
            }
        }
        gb_kernel<<<12 * 32, blk, 0, stream>>>(sa);
    }
    // bar = hats@W6 ; gt = bar@W78 + b8 ; Ho
    gemm_kernel<0><<<dim3(48, 12), blk, 0, stream>>>(hats, 2304, 2304, W6, 768, nullptr, bar, 768, 3072);
    gemm_kernel<1><<<dim3(48, 12), blk, 0, stream>>>(bar, 768, 768, W78, 768, b8, gt, 768, 3072);
    hogate_kernel<<<9216, blk, 0, stream>>>(gt, bar, Ha, Ho);

    // projection caches
    gemm_kernel<0><<<dim3(16, 48), blk, 0, stream>>>(Hq, 768, 768, WqCat, 3072, nullptr, HqCat, 3072, 1024);
    gemm_kernel<0><<<dim3(64, 24), blk, 0, stream>>>(Hps, 768, 768, WpsCat, 1536, nullptr, HpsCat, 1536, 4096);
    gemm_kernel<0><<<dim3(48, 24), blk, 0, stream>>>(Ho, 768, 768, WhoCat, 1536, nullptr, HoCat, 1536, 3072);

    // match G offsets (floats, within Gm)
    const long gA0 = 0;                 // pq-X  128x32
    const long gA1 = 131072;            // po-X  128x24 x4
    const long gA5 = 524288;            // qo-X  32x24  x4
    const long gA9 = 622592;            // qo-Y  24x32  x4
    const long gB0 = 720896;            // pq-Y  32x128
    const long gB1 = 851968;            // po-Y  24x128 x4

    // match QK variant A (13 segs)
    {
        QArgs qa;
        // A0: pq-X
        qa.s[0] = { HpsCat, Hq, Gm + gA0, (long)128 * 1536, (long)32 * 768, 4096, 1536, 768, 128, 32 };
        for (int i = 0; i < 4; i++) {
            // A1-4: po-X
            qa.s[1 + i] = { HpsCat, Ho + (long)i * 24 * 768, Gm + gA1 + (long)i * 98304,
                            (long)128 * 1536, (long)96 * 768, 3072, 1536, 768, 128, 24 };
            // A5-8: qo-X
            qa.s[5 + i] = { HqCat, Ho + (long)i * 24 * 768, Gm + gA5 + (long)i * 24576,
                            (long)32 * 3072, (long)96 * 768, 768, 3072, 768, 32, 24 };
            // A9-12: qo-Y (GL = cache4_i, HY = Hq)
            qa.s[9 + i] = { HoCat + (long)i * 24 * 1536, Hq, Gm + gA9 + (long)i * 24576,
                            (long)96 * 1536, (long)32 * 768, 768, 1536, 768, 24, 32 };
        }
        qkA_kernel<<<13 * 32, blk, 0, stream>>>(qa);
    }
    // match QK variant B (5 segs, Y=128)
    {
        QArgs qa;
        qa.s[0] = { HqCat + 768, Hps, Gm + gB0, (long)32 * 3072, (long)128 * 768, 4096, 3072, 768, 32, 128 };
        for (int i = 0; i < 4; i++)
            qa.s[1 + i] = { HoCat + (long)i * 24 * 1536, Hps, Gm + gB1 + (long)i * 98304,
                            (long)96 * 1536, (long)128 * 768, 3072, 1536, 768, 24, 128 };
        qkB_kernel<<<5 * 32, blk, 0, stream>>>(qa);
    }
    // S (18 segs, max mode). S[m][b][1536]: cols 0..767 = Sxy, 768..1535 = Syx
    {
        SArgs sa;
        // s0: pq-X -> Sxy[m=0]
        sa.s[0] = { Gm + gA0, HqCat + 1536, S, 4096, (long)32 * 3072, 1536, 3072, 0, 128, 32, 1 };
        for (int i = 0; i < 4; i++) {
            // po-X -> Sxy[m=1+i]   (B = HoW11_i)
            sa.s[1 + i] = { Gm + gA1 + (long)i * 98304, HoCat + (long)i * 24 * 1536 + 768,
                            S + (long)(1 + i) * 49152, 3072, (long)96 * 1536, 1536, 1536, 0, 128, 24, 1 };
            // qo-X -> Sxy[m=5+i]
            sa.s[5 + i] = { Gm + gA5 + (long)i * 24576, HoCat + (long)i * 24 * 1536 + 768,
                            S + (long)(5 + i) * 49152, 768, (long)96 * 1536, 1536, 1536, 0, 32, 24, 1 };
        }
        // s9: pq-Y -> Syx[m=0]  (B = HpsW12)
        sa.s[9] = { Gm + gB0, HpsCat + 768, S + 768, 4096, (long)128 * 1536, 1536, 1536, 0, 32, 128, 1 };
        for (int i = 0; i < 4; i++) {
            // po-Y -> Syx[m=1+i]
            sa.s[10 + i] = { Gm + gB1 + (long)i * 98304, HpsCat + 768,
                             S + (long)(1 + i) * 49152 + 768, 3072, (long)128 * 1536, 1536, 1536, 0, 24, 128, 1 };
            // qo-Y -> Syx[m=5+i]  (B = HqW12)
            sa.s[14 + i] = { Gm + gA9 + (long)i * 24576, HqCat + 2304,
                             S + (long)(5 + i) * 49152 + 768, 768, (long)32 * 3072, 1536, 3072, 0, 24, 32, 1 };
        }
        gb_kernel<<<18 * 32, blk, 0, stream>>>(sa);
    }

    // gating: gts = [Sxy|Syx] @ [W13;W14] + b14  (288 x 1536 x 768)
    gemm_kernel<1><<<dim3(5, 12), blk, 0, stream>>>(S, 1536, 1536, W1314, 768, b14, gts, 768, 288);

    logits_kernel<<<128, blk, 0, stream>>>(S, gts, V, lg);
    lsm_kernel<<<1, dim3(32), 0, stream>>>(lg, out);
}

// Round 4
// 958.664 us; speedup vs baseline: 5.6124x; 1.5134x over previous
//
#include <hip/hip_runtime.h>
#include <math.h>

// B=32, N=32, P=64, Q=32, A=24, M=4, L=768, K=2

typedef __bf16 bf16x8 __attribute__((ext_vector_type(8)));
typedef float f32x4 __attribute__((ext_vector_type(4)));

// ---------------- prep: transposed weights (hi/lo bf16 for score-feeding, plain else) ----
// W5t(768x768 h/l), WsQT([W9|W10]^T 1536x768 h/l), W6t(768x2304 h/l),
// W1112T([W11|W12]^T 1536x768), W78t(768x768), W1314t(768x1536)  (all N x K)
__global__ void prep_kernel(const float* __restrict__ W5, const float* __restrict__ W6,
                            const float* __restrict__ W7, const float* __restrict__ W8,
                            const float* __restrict__ W9, const float* __restrict__ W10,
                            const float* __restrict__ W11, const float* __restrict__ W12,
                            const float* __restrict__ W13, const float* __restrict__ W14,
                            __bf16* __restrict__ W5t_h, __bf16* __restrict__ W5t_l,
                            __bf16* __restrict__ WsQT_h, __bf16* __restrict__ WsQT_l,
                            __bf16* __restrict__ W6t_h, __bf16* __restrict__ W6t_l,
                            __bf16* __restrict__ W1112T, __bf16* __restrict__ W78t,
                            __bf16* __restrict__ W1314t) {
    long i = (long)blockIdx.x * 256 + threadIdx.x;
    if (i < 589824) {
        int c = (int)(i / 768), r = (int)(i % 768);
        float v = W5[r * 768 + c];
        __bf16 h = (__bf16)v; W5t_h[i] = h; W5t_l[i] = (__bf16)(v - (float)h);
        return;
    } i -= 589824;
    if (i < 1179648) {
        int c = (int)(i / 768), r = (int)(i % 768);
        float v = (c < 768) ? W9[r * 768 + c] : W10[r * 768 + c - 768];
        __bf16 h = (__bf16)v; WsQT_h[i] = h; WsQT_l[i] = (__bf16)(v - (float)h);
        return;
    } i -= 1179648;
    if (i < 1769472) {
        int c = (int)(i / 2304), r = (int)(i % 2304);
        float v = W6[r * 768 + c];
        __bf16 h = (__bf16)v; W6t_h[i] = h; W6t_l[i] = (__bf16)(v - (float)h);
        return;
    } i -= 1769472;
    if (i < 1179648) {
        int c = (int)(i / 768), r = (int)(i % 768);
        W1112T[i] = (__bf16)((c < 768) ? W11[r * 768 + c] : W12[r * 768 + c - 768]);
        return;
    } i -= 1179648;
    if (i < 589824) {
        int c = (int)(i / 768), r = (int)(i % 768);
        W78t[i] = (__bf16)(W7[r * 768 + c] + W8[r * 768 + c]);
        return;
    } i -= 589824;
    if (i < 1179648) {
        int c = (int)(i / 1536), r = (int)(i % 1536);
        W1314t[i] = (__bf16)((r < 768) ? W13[r * 768 + c] : W14[(r - 768) * 768 + c]);
    }
}

__global__ void cvt2_kernel(const float* __restrict__ src, __bf16* __restrict__ h,
                            __bf16* __restrict__ l, long n) {
    long i = (long)blockIdx.x * 256 + threadIdx.x;
    if (i < n) {
        float v = src[i];
        __bf16 hv = (__bf16)v; h[i] = hv; l[i] = (__bf16)(v - (float)hv);
    }
}

// ---------------- stage 1: scoring (fp32 — selection must be exact) ----------------
__global__ void rnorm_kernel(const float* __restrict__ X, float* __restrict__ out) {
    long row = blockIdx.x;
    const float* xr = X + row * 768;
    int t = threadIdx.x;
    float ss = 0.f;
    for (int l = t; l < 768; l += 256) { float v = xr[l]; ss += v * v; }
    for (int o = 32; o; o >>= 1) ss += __shfl_xor(ss, o);
    __shared__ float red[4];
    if ((t & 63) == 0) red[t >> 6] = ss;
    __syncthreads();
    if (t == 0) {
        float tot = red[0] + red[1] + red[2] + red[3];
        out[row] = 1.f / fmaxf(sqrtf(tot), 1e-8f);
    }
}

__global__ void simmax_kernel(const float* __restrict__ Hp, const float* __restrict__ Ha,
                              const float* __restrict__ Hq,
                              const float* __restrict__ rp, const float* __restrict__ ra,
                              const float* __restrict__ rq, float* __restrict__ amax) {
    int b = blockIdx.x >> 5, n = blockIdx.x & 31;
    __shared__ float As[16][64];
    __shared__ float Bs[16][128];
    __shared__ float red[16][128];
    int t = threadIdx.x;
    const float* Ap  = Hp + ((long)b * 2048 + n * 64) * 768;
    const float* Hab = Ha + (long)b * 96 * 768;
    const float* Hqb = Hq + (long)b * 32 * 768;
    int tx = t & 15, ty = t >> 4;
    int arow = t >> 2, kof = (t & 3) << 2;
    int r2 = arow + 64;
    const float* p1 = Hab + (long)arow * 768;
    const float* p2 = (r2 < 96) ? (Hab + (long)r2 * 768) : (Hqb + (long)(r2 - 96) * 768);
    float acc[4][8] = {{0.f}};
    for (int k0 = 0; k0 < 768; k0 += 16) {
        float4 av = *(const float4*)(Ap + (long)arow * 768 + k0 + kof);
        float4 b1 = *(const float4*)(p1 + k0 + kof);
        float4 b2 = *(const float4*)(p2 + k0 + kof);
        __syncthreads();
        As[kof + 0][arow] = av.x; As[kof + 1][arow] = av.y;
        As[kof + 2][arow] = av.z; As[kof + 3][arow] = av.w;
        Bs[kof + 0][arow] = b1.x; Bs[kof + 1][arow] = b1.y;
        Bs[kof + 2][arow] = b1.z; Bs[kof + 3][arow] = b1.w;
        Bs[kof + 0][r2]   = b2.x; Bs[kof + 1][r2]   = b2.y;
        Bs[kof + 2][r2]   = b2.z; Bs[kof + 3][r2]   = b2.w;
        __syncthreads();
#pragma unroll
        for (int kk = 0; kk < 16; kk++) {
            float a[4], bb[8];
#pragma unroll
            for (int i = 0; i < 4; i++) a[i] = As[kk][(ty << 2) + i];
#pragma unroll
            for (int j = 0; j < 8; j++) bb[j] = Bs[kk][tx + 16 * j];
#pragma unroll
            for (int i = 0; i < 4; i++)
#pragma unroll
                for (int j = 0; j < 8; j++) acc[i][j] += a[i] * bb[j];
        }
    }
    float rpv[4];
#pragma unroll
    for (int i = 0; i < 4; i++) rpv[i] = rp[(long)b * 2048 + n * 64 + (ty << 2) + i];
#pragma unroll
    for (int j = 0; j < 8; j++) {
        int c = tx + 16 * j;
        float rc = (c < 96) ? ra[b * 96 + c] : rq[b * 32 + (c - 96)];
        float mx = acc[0][j] * rpv[0];
#pragma unroll
        for (int i = 1; i < 4; i++) mx = fmaxf(mx, acc[i][j] * rpv[i]);
        red[ty][c] = mx * rc;
    }
    __syncthreads();
    if (ty == 0) {
#pragma unroll
        for (int j = 0; j < 8; j++) {
            int c = tx + 16 * j;
            float m = red[0][c];
            for (int yy = 1; yy < 16; yy++) m = fmaxf(m, red[yy][c]);
            amax[((long)b * 32 + n) * 128 + c] = m;
        }
    }
}

__global__ void score_top2_kernel(const float* __restrict__ amax, int* __restrict__ idx) {
    int b = blockIdx.x, t = threadIdx.x;
    __shared__ float sc[32];
    if (t < 32) {
        const float* am = amax + ((long)b * 32 + t) * 128;
        float sa = 0.f, sq = 0.f;
        for (int c = 0; c < 96; c++) sa += am[c];
        for (int c = 96; c < 128; c++) sq += am[c];
        sc[t] = sa / 24.f + sq / 32.f;
    }
    __syncthreads();
    if (t == 0) {
        float m0 = -1e30f; int i0 = 0;
        for (int n = 0; n < 32; n++) if (sc[n] > m0) { m0 = sc[n]; i0 = n; }
        float m1 = -1e30f; int i1 = 0;
        for (int n = 0; n < 32; n++) if (n != i0 && sc[n] > m1) { m1 = sc[n]; i1 = n; }
        idx[b * 2] = i0; idx[b * 2 + 1] = i1;
    }
}

__global__ void gather_kernel(const float* __restrict__ Hp, const int* __restrict__ idx,
                              float* __restrict__ HpsF, __bf16* __restrict__ Hps_h,
                              __bf16* __restrict__ Hps_l) {
    long i = (long)blockIdx.x * 256 + threadIdx.x;
    if (i >= (long)32 * 128 * 768) return;
    int l = (int)(i % 768);
    long r = i / 768;
    int x = (int)(r % 128); int b = (int)(r / 128);
    int k = x >> 6, p = x & 63;
    int n = idx[b * 2 + k];
    float v = Hp[((long)b * 2048 + n * 64 + p) * 768 + l];
    HpsF[i] = v;
    __bf16 h = (__bf16)v; Hps_h[i] = h; Hps_l[i] = (__bf16)(v - (float)h);
}

// ---------------- bf16 MFMA GEMM (plain): C = A @ Wt^T [+bias] ----------------
// BOUT 0: fp32 out; 1: bf16 out only
template <int BIASF, int BOUT>
__global__ __launch_bounds__(256) void mgemm_kernel(
    const __bf16* __restrict__ A, int Kdim, int Mtot,
    const __bf16* __restrict__ Wt, const float* __restrict__ bias,
    float* __restrict__ C, int ldc, __bf16* __restrict__ Cb) {
    constexpr int LDT = 80;
    __shared__ alignas(16) __bf16 As[64 * LDT];
    __shared__ alignas(16) __bf16 Bs[64 * LDT];
    int t = threadIdx.x;
    int rowBase = blockIdx.x << 6, colBase = blockIdx.y << 6;
    int srow = t >> 2, skof = (t & 3) << 3;
    int arow = rowBase + srow;
    bool aok = arow < Mtot;
    const __bf16* Ap = A + (long)(aok ? arow : rowBase) * Kdim + skof;
    const __bf16* Wp = Wt + (long)(colBase + srow) * Kdim + skof;
    int w = t >> 6, l = t & 63;
    int wr = (w >> 1) << 5, wc = (w & 1) << 5;
    int fr = l & 15, g = l >> 4;
    f32x4 acc[2][2] = {};
    int nk = Kdim >> 6;
    for (int ks = 0; ks < nk; ks++) {
        bf16x8 a0 = *(const bf16x8*)(Ap);
        bf16x8 a1 = *(const bf16x8*)(Ap + 32);
        bf16x8 w0 = *(const bf16x8*)(Wp);
        bf16x8 w1 = *(const bf16x8*)(Wp + 32);
        Ap += 64; Wp += 64;
        __syncthreads();
        *(bf16x8*)(&As[srow * LDT + skof]) = a0;
        *(bf16x8*)(&As[srow * LDT + 32 + skof]) = a1;
        *(bf16x8*)(&Bs[srow * LDT + skof]) = w0;
        *(bf16x8*)(&Bs[srow * LDT + 32 + skof]) = w1;
        __syncthreads();
#pragma unroll
        for (int sub = 0; sub < 2; sub++) {
            int ko = sub * 32 + g * 8;
            bf16x8 fa0 = *(const bf16x8*)(&As[(wr + fr) * LDT + ko]);
            bf16x8 fa1 = *(const bf16x8*)(&As[(wr + 16 + fr) * LDT + ko]);
            bf16x8 fb0 = *(const bf16x8*)(&Bs[(wc + fr) * LDT + ko]);
            bf16x8 fb1 = *(const bf16x8*)(&Bs[(wc + 16 + fr) * LDT + ko]);
            acc[0][0] = __builtin_amdgcn_mfma_f32_16x16x32_bf16(fa0, fb0, acc[0][0], 0, 0, 0);
            acc[0][1] = __builtin_amdgcn_mfma_f32_16x16x32_bf16(fa0, fb1, acc[0][1], 0, 0, 0);
            acc[1][0] = __builtin_amdgcn_mfma_f32_16x16x32_bf16(fa1, fb0, acc[1][0], 0, 0, 0);
            acc[1][1] = __builtin_amdgcn_mfma_f32_16x16x32_bf16(fa1, fb1, acc[1][1], 0, 0, 0);
        }
    }
#pragma unroll
    for (int fi = 0; fi < 2; fi++)
#pragma unroll
    for (int fj = 0; fj < 2; fj++)
#pragma unroll
    for (int r = 0; r < 4; r++) {
        int row = rowBase + wr + fi * 16 + g * 4 + r;
        int col = colBase + wc + fj * 16 + (l & 15);
        if (row < Mtot) {
            float v = acc[fi][fj][r];
            if (BIASF) v += bias[col];
            if (BOUT == 0) C[(long)row * ldc + col] = v;
            else Cb[(long)row * ldc + col] = (__bf16)v;
        }
    }
}

// ---------------- bf16x3 split-precision MFMA GEMM: C = (Ah+Al)@(Wh+Wl)^T ----------------
// WH: also write bf16-hi copy of output
template <int WH>
__global__ __launch_bounds__(256) void mgemm3_kernel(
    const __bf16* __restrict__ Ah, const __bf16* __restrict__ Al, int Kdim, int Mtot,
    const __bf16* __restrict__ Wh, const __bf16* __restrict__ Wl,
    float* __restrict__ C, int ldc, __bf16* __restrict__ Cb) {
    constexpr int LDT = 80;
    __shared__ alignas(16) __bf16 Ahs[64 * LDT];
    __shared__ alignas(16) __bf16 Als[64 * LDT];
    __shared__ alignas(16) __bf16 Bhs[64 * LDT];
    __shared__ alignas(16) __bf16 Bls[64 * LDT];
    int t = threadIdx.x;
    int rowBase = blockIdx.x << 6, colBase = blockIdx.y << 6;
    int srow = t >> 2, skof = (t & 3) << 3;
    int arow = rowBase + srow;
    bool aok = arow < Mtot;
    long aoff = (long)(aok ? arow : rowBase) * Kdim + skof;
    long woff = (long)(colBase + srow) * Kdim + skof;
    const __bf16* Aph = Ah + aoff;
    const __bf16* Apl = Al + aoff;
    const __bf16* Wph = Wh + woff;
    const __bf16* Wpl = Wl + woff;
    int w = t >> 6, l = t & 63;
    int wr = (w >> 1) << 5, wc = (w & 1) << 5;
    int fr = l & 15, g = l >> 4;
    f32x4 acc[2][2] = {};
    int nk = Kdim >> 6;
    for (int ks = 0; ks < nk; ks++) {
        bf16x8 ah0 = *(const bf16x8*)(Aph);      bf16x8 ah1 = *(const bf16x8*)(Aph + 32);
        bf16x8 al0 = *(const bf16x8*)(Apl);      bf16x8 al1 = *(const bf16x8*)(Apl + 32);
        bf16x8 wh0 = *(const bf16x8*)(Wph);      bf16x8 wh1 = *(const bf16x8*)(Wph + 32);
        bf16x8 wl0 = *(const bf16x8*)(Wpl);      bf16x8 wl1 = *(const bf16x8*)(Wpl + 32);
        Aph += 64; Apl += 64; Wph += 64; Wpl += 64;
        __syncthreads();
        *(bf16x8*)(&Ahs[srow * LDT + skof]) = ah0; *(bf16x8*)(&Ahs[srow * LDT + 32 + skof]) = ah1;
        *(bf16x8*)(&Als[srow * LDT + skof]) = al0; *(bf16x8*)(&Als[srow * LDT + 32 + skof]) = al1;
        *(bf16x8*)(&Bhs[srow * LDT + skof]) = wh0; *(bf16x8*)(&Bhs[srow * LDT + 32 + skof]) = wh1;
        *(bf16x8*)(&Bls[srow * LDT + skof]) = wl0; *(bf16x8*)(&Bls[srow * LDT + 32 + skof]) = wl1;
        __syncthreads();
#pragma unroll
        for (int sub = 0; sub < 2; sub++) {
            int ko = sub * 32 + g * 8;
            bf16x8 fah[2], fal[2], fbh[2], fbl[2];
            fah[0] = *(const bf16x8*)(&Ahs[(wr + fr) * LDT + ko]);
            fah[1] = *(const bf16x8*)(&Ahs[(wr + 16 + fr) * LDT + ko]);
            fal[0] = *(const bf16x8*)(&Als[(wr + fr) * LDT + ko]);
            fal[1] = *(const bf16x8*)(&Als[(wr + 16 + fr) * LDT + ko]);
            fbh[0] = *(const bf16x8*)(&Bhs[(wc + fr) * LDT + ko]);
            fbh[1] = *(const bf16x8*)(&Bhs[(wc + 16 + fr) * LDT + ko]);
            fbl[0] = *(const bf16x8*)(&Bls[(wc + fr) * LDT + ko]);
            fbl[1] = *(const bf16x8*)(&Bls[(wc + 16 + fr) * LDT + ko]);
#pragma unroll
            for (int i = 0; i < 2; i++)
#pragma unroll
            for (int j = 0; j < 2; j++) {
                acc[i][j] = __builtin_amdgcn_mfma_f32_16x16x32_bf16(fah[i], fbh[j], acc[i][j], 0, 0, 0);
                acc[i][j] = __builtin_amdgcn_mfma_f32_16x16x32_bf16(fah[i], fbl[j], acc[i][j], 0, 0, 0);
                acc[i][j] = __builtin_amdgcn_mfma_f32_16x16x32_bf16(fal[i], fbh[j], acc[i][j], 0, 0, 0);
            }
        }
    }
#pragma unroll
    for (int fi = 0; fi < 2; fi++)
#pragma unroll
    for (int fj = 0; fj < 2; fj++)
#pragma unroll
    for (int r = 0; r < 4; r++) {
        int row = rowBase + wr + fi * 16 + g * 4 + r;
        int col = colBase + wc + fj * 16 + (l & 15);
        if (row < Mtot) {
            float v = acc[fi][fj][r];
            C[(long)row * ldc + col] = v;
            if (WH) Cb[(long)row * ldc + col] = (__bf16)v;
        }
    }
}

// ---------------- batched QK + softmax (fp32 scores) ----------------
struct QSegT {
    const float* GL; const float* HY; float* G;
    long glB, hyB, gB;
    int ldGL, ldHY, X, Y;
};
struct QArgs { QSegT s[13]; };

// variant A: X<=128, Y<=32
__global__ __launch_bounds__(256) void qkA_kernel(QArgs args) {
    int seg = blockIdx.x >> 5, b = blockIdx.x & 31;
    QSegT sg = args.s[seg];
    __shared__ float As[16][128];
    __shared__ float Bs[16][32];
    __shared__ float sc[128 * 33];
    int t = threadIdx.x;
    int arow = t >> 1, akof = (t & 1) * 8;
    int brow = t >> 3, bkof = (t & 7) * 2;
    bool aok = arow < sg.X, bok = brow < sg.Y;
    const float* ga = sg.GL + (long)b * sg.glB + (long)arow * sg.ldGL;
    const float* hb = sg.HY + (long)b * sg.hyB + (long)brow * sg.ldHY;
    int tx = t & 63, ty = t >> 6;
    float acc0[8] = {0.f}, acc1[8] = {0.f};
    for (int k0 = 0; k0 < 768; k0 += 16) {
        float4 a0 = make_float4(0, 0, 0, 0), a1 = make_float4(0, 0, 0, 0);
        float b0 = 0.f, b1v = 0.f;
        if (aok) { a0 = *(const float4*)(ga + k0 + akof); a1 = *(const float4*)(ga + k0 + akof + 4); }
        if (bok) { b0 = hb[k0 + bkof]; b1v = hb[k0 + bkof + 1]; }
        __syncthreads();
        As[akof + 0][arow] = a0.x; As[akof + 1][arow] = a0.y;
        As[akof + 2][arow] = a0.z; As[akof + 3][arow] = a0.w;
        As[akof + 4][arow] = a1.x; As[akof + 5][arow] = a1.y;
        As[akof + 6][arow] = a1.z; As[akof + 7][arow] = a1.w;
        Bs[bkof][brow] = b0; Bs[bkof + 1][brow] = b1v;
        __syncthreads();
#pragma unroll
        for (int kk = 0; kk < 16; kk++) {
            float alo = As[kk][tx], ahi = As[kk][tx + 64];
#pragma unroll
            for (int j = 0; j < 8; j++) {
                float bv = Bs[kk][ty * 8 + j];
                acc0[j] += alo * bv; acc1[j] += ahi * bv;
            }
        }
    }
#pragma unroll
    for (int j = 0; j < 8; j++) {
        sc[tx * 33 + ty * 8 + j] = acc0[j];
        sc[(tx + 64) * 33 + ty * 8 + j] = acc1[j];
    }
    __syncthreads();
    if (t < sg.X) {
        float* row = sc + t * 33;
        int Y = sg.Y;
        float m = row[0];
        for (int y = 1; y < Y; y++) m = fmaxf(m, row[y]);
        float s = 0.f;
        for (int y = 0; y < Y; y++) { float e = expf(row[y] - m); row[y] = e; s += e; }
        float inv = 1.f / s;
        float* go = sg.G + (long)b * sg.gB + (long)t * Y;
        for (int y = 0; y < Y; y++) go[y] = row[y] * inv;
    }
}

// variant B: X<=32, Y==128
__global__ __launch_bounds__(256) void qkB_kernel(QArgs args) {
    int seg = blockIdx.x >> 5, b = blockIdx.x & 31;
    QSegT sg = args.s[seg];
    __shared__ float As[16][32];
    __shared__ float Bs[16][128];
    __shared__ float sc[32 * 129];
    int t = threadIdx.x;
    int arow = t >> 3, akof = (t & 7) * 2;
    int brow = t >> 1, bkof = (t & 1) * 8;
    bool aok = arow < sg.X;
    const float* ga = sg.GL + (long)b * sg.glB + (long)arow * sg.ldGL;
    const float* hb = sg.HY + (long)b * sg.hyB + (long)brow * sg.ldHY;
    int tx = t & 31, grp = t >> 5;
    float acc[16] = {0.f};
    for (int k0 = 0; k0 < 768; k0 += 16) {
        float a0 = 0.f, a1 = 0.f;
        if (aok) { a0 = ga[k0 + akof]; a1 = ga[k0 + akof + 1]; }
        float4 b0 = *(const float4*)(hb + k0 + bkof);
        float4 b1 = *(const float4*)(hb + k0 + bkof + 4);
        __syncthreads();
        As[akof][arow] = a0; As[akof + 1][arow] = a1;
        Bs[bkof + 0][brow] = b0.x; Bs[bkof + 1][brow] = b0.y;
        Bs[bkof + 2][brow] = b0.z; Bs[bkof + 3][brow] = b0.w;
        Bs[bkof + 4][brow] = b1.x; Bs[bkof + 5][brow] = b1.y;
        Bs[bkof + 6][brow] = b1.z; Bs[bkof + 7][brow] = b1.w;
        __syncthreads();
#pragma unroll
        for (int kk = 0; kk < 16; kk++) {
            float a = As[kk][tx];
#pragma unroll
            for (int j = 0; j < 16; j++) acc[j] += a * Bs[kk][grp * 16 + j];
        }
    }
#pragma unroll
    for (int j = 0; j < 16; j++) sc[tx * 129 + grp * 16 + j] = acc[j];
    __syncthreads();
    int row = t >> 3, lane = t & 7;
    if (row < sg.X) {
        float m = -1e30f;
        for (int k = 0; k < 16; k++) m = fmaxf(m, sc[row * 129 + lane + 8 * k]);
        for (int o = 1; o < 8; o <<= 1) m = fmaxf(m, __shfl_xor(m, o));
        float s = 0.f;
        for (int k = 0; k < 16; k++) {
            float e = expf(sc[row * 129 + lane + 8 * k] - m);
            sc[row * 129 + lane + 8 * k] = e; s += e;
        }
        for (int o = 1; o < 8; o <<= 1) s += __shfl_xor(s, o);
        float inv = 1.f / s;
        float* go = sg.G + (long)b * sg.gB + (long)row * 128;
        for (int k = 0; k < 16; k++) go[lane + 8 * k] = sc[row * 129 + lane + 8 * k] * inv;
    }
}

// ---------------- batched G@B ----------------
struct SSegT {
    const float* G; const void* B; float* outF; __bf16* outH; __bf16* outL;
    long gB, bB, oB;
    int ldB, ldO, R, C, mode;  // mode1: max-reduce -> outF + outH; mode0: relu rows -> outH/outL
};
struct SArgs { SSegT s[18]; };

template <int BFB>
__global__ __launch_bounds__(256) void gb_kernel(SArgs args) {
    int seg = blockIdx.x >> 5, b = blockIdx.x & 31;
    SSegT sg = args.s[seg];
    __shared__ float Gs[4096];
    int t = threadIdx.x;
    int n = sg.R * sg.C;
    for (int i = t; i < n; i += 256) Gs[i] = sg.G[(long)b * sg.gB + i];
    __syncthreads();
    int C = sg.C, R = sg.R;
    const float* BbF = (const float*)sg.B + (long)b * sg.bB;
    const __bf16* BbH = (const __bf16*)sg.B + (long)b * sg.bB;
    for (int l0 = 0; l0 < 768; l0 += 256) {
        int l = l0 + t;
        if (sg.mode) {
            float mx = 0.f;
            for (int rb = 0; rb < R; rb += 8) {
                float a[8] = {0.f};
                for (int c = 0; c < C; c++) {
                    float bv = BFB ? (float)BbH[(long)c * sg.ldB + l] : BbF[(long)c * sg.ldB + l];
#pragma unroll
                    for (int r8 = 0; r8 < 8; r8++) a[r8] += Gs[(rb + r8) * C + c] * bv;
                }
#pragma unroll
                for (int r8 = 0; r8 < 8; r8++) mx = fmaxf(mx, a[r8]);
            }
            sg.outF[(long)b * sg.oB + l] = mx;
            sg.outH[(long)b * sg.oB + l] = (__bf16)mx;
        } else {
            for (int rb = 0; rb < R; rb += 8) {
                float a[8] = {0.f};
                for (int c = 0; c < C; c++) {
                    float bv = BFB ? (float)BbH[(long)c * sg.ldB + l] : BbF[(long)c * sg.ldB + l];
#pragma unroll
                    for (int r8 = 0; r8 < 8; r8++) a[r8] += Gs[(rb + r8) * C + c] * bv;
                }
#pragma unroll
                for (int r8 = 0; r8 < 8; r8++) {
                    float v = fmaxf(a[r8], 0.f);
                    __bf16 h = (__bf16)v;
                    long o = (long)b * sg.oB + (long)(rb + r8) * sg.ldO + l;
                    sg.outH[o] = h;
                    sg.outL[o] = (__bf16)(v - (float)h);
                }
            }
        }
    }
}

// ---------------- elementwise ----------------
__global__ void hogate_kernel(const float* __restrict__ gt, const float* __restrict__ bar,
                              const float* __restrict__ Ha, float* __restrict__ Ho,
                              __bf16* __restrict__ Ho_h, __bf16* __restrict__ Ho_l) {
    long idx = (long)blockIdx.x * 256 + threadIdx.x;
    if (idx >= (long)32 * 96 * 768) return;
    float g = 1.f / (1.f + expf(-gt[idx]));
    float v = g * Ha[idx] + (1.f - g) * bar[idx];
    Ho[idx] = v;
    __bf16 h = (__bf16)v; Ho_h[idx] = h; Ho_l[idx] = (__bf16)(v - (float)h);
}

__global__ void logits_kernel(const float* __restrict__ S, const float* __restrict__ gts,
                              const float* __restrict__ V, float* __restrict__ lg) {
    int blk = blockIdx.x; int b = blk >> 2, i = blk & 3;
    int t = threadIdx.x;
    int ms[3] = {0, 1 + i, 5 + i};
    float p = 0.f;
    for (int k = 0; k < 3; k++) {
        int m = ms[k];
        const float* Sr = S + (long)m * 49152 + (long)b * 1536;
        const float* gr = gts + ((long)m * 32 + b) * 768;
        const float* Vr = V + k * 768;
        for (int l = t; l < 768; l += 256) {
            float g = 1.f / (1.f + expf(-gr[l]));
            p += (g * Sr[l] + (1.f - g) * Sr[768 + l]) * Vr[l];
        }
    }
    for (int o = 32; o; o >>= 1) p += __shfl_xor(p, o);
    __shared__ float red[4];
    if ((t & 63) == 0) red[t >> 6] = p;
    __syncthreads();
    if (t == 0) lg[blk] = red[0] + red[1] + red[2] + red[3];
}

__global__ void lsm_kernel(const float* __restrict__ lg, float* __restrict__ out) {
    int b = threadIdx.x;
    if (b >= 32) return;
    float x0 = lg[b * 4 + 0], x1 = lg[b * 4 + 1], x2 = lg[b * 4 + 2], x3 = lg[b * 4 + 3];
    float m = fmaxf(fmaxf(x0, x1), fmaxf(x2, x3));
    float s = expf(x0 - m) + expf(x1 - m) + expf(x2 - m) + expf(x3 - m);
    float ls = m + logf(s);
    out[b * 4 + 0] = x0 - ls; out[b * 4 + 1] = x1 - ls;
    out[b * 4 + 2] = x2 - ls; out[b * 4 + 3] = x3 - ls;
}

// ---------------- host ----------------
extern "C" void kernel_launch(void* const* d_in, const int* in_sizes, int n_in,
                              void* d_out, int out_size, void* d_ws, size_t ws_size,
                              hipStream_t stream) {
    const float* Hp  = (const float*)d_in[0];
    const float* Hq  = (const float*)d_in[1];
    const float* Ha  = (const float*)d_in[2];
    const float* W5  = (const float*)d_in[3];
    const float* W6  = (const float*)d_in[4];
    const float* W7  = (const float*)d_in[5];
    const float* W8  = (const float*)d_in[6];
    const float* b8  = (const float*)d_in[7];
    const float* W9  = (const float*)d_in[8];
    const float* W10 = (const float*)d_in[9];
    const float* W11 = (const float*)d_in[10];
    const float* W12 = (const float*)d_in[11];
    const float* W13 = (const float*)d_in[12];
    const float* W14 = (const float*)d_in[13];
    const float* b14 = (const float*)d_in[14];
    const float* V   = (const float*)d_in[15];
    float* out = (float*)d_out;
    (void)in_sizes; (void)n_in; (void)out_size; (void)ws_size;

    char* base = (char*)d_ws;
    size_t off = 0;
    auto take = [&](size_t bytes) { char* p = base + off; off += (bytes + 15) & ~15UL; return p; };

    // bf16 weights
    __bf16* W5t_h  = (__bf16*)take(1179648);
    __bf16* W5t_l  = (__bf16*)take(1179648);
    __bf16* WsQT_h = (__bf16*)take(2359296);
    __bf16* WsQT_l = (__bf16*)take(2359296);
    __bf16* W6t_h  = (__bf16*)take(3538944);
    __bf16* W6t_l  = (__bf16*)take(3538944);
    __bf16* W1112T = (__bf16*)take(2359296);
    __bf16* W78t   = (__bf16*)take(1179648);
    __bf16* W1314t = (__bf16*)take(2359296);
    // fp32
    float* rp     = (float*)take(262144);
    float* ra     = (float*)take(12288);
    float* rq     = (float*)take(4096);
    float* amax   = (float*)take(524288);
    int*   topidx = (int*)take(256);
    float* HpsF   = (float*)take(12582912);
    float* C1     = (float*)take(9437184);   // Ha@W5; reused later as gt
    float* HqSens = (float*)take(6291456);   // [c2|c3] ld 1536
    float* cache1 = (float*)take(12582912);  // Hps@W9, ld 768
    float* bar    = (float*)take(9437184);
    float* Ho     = (float*)take(9437184);
    float* G2     = (float*)take(884736);
    float* lg     = (float*)take(512);
    // bf16 activations
    char* HaReg   = take(9437184);           // Ha_h/l; later bar_h + S_h
    __bf16* Ha_h  = (__bf16*)HaReg;
    __bf16* Ha_l  = (__bf16*)(HaReg + 4718592);
    __bf16* bar_h = (__bf16*)HaReg;                 // alias (Ha dead after C1)
    __bf16* S_h   = (__bf16*)(HaReg + 4718592);     // alias
    __bf16* Hq_h  = (__bf16*)take(1572864);
    __bf16* Hq_l  = (__bf16*)take(1572864);
    __bf16* Hps_h = (__bf16*)take(6291456);
    __bf16* Hps_l = (__bf16*)take(6291456);
    __bf16* Ho_h  = (__bf16*)take(4718592);
    __bf16* Ho_l  = (__bf16*)take(4718592);
    char* HatsReg = take(28311552);          // hats_h/l; later cache4,HoW11_bf,Gm,S,gts
    __bf16* hats_h = (__bf16*)HatsReg;
    __bf16* hats_l = (__bf16*)(HatsReg + 14155776);
    float*  cache4    = (float*)HatsReg;                       // alias (post-bar)
    __bf16* HoW11_bf  = (__bf16*)(HatsReg + 9437184);
    float*  Gm        = (float*)(HatsReg + 14155776);
    float*  S         = (float*)(HatsReg + 19136512);
    float*  gts       = (float*)(HatsReg + 20905984);
    __bf16* HqS2_bf   = (__bf16*)take(3145728);   // [HqW11|HqW12] ld 1536
    __bf16* HpsW12_bf = (__bf16*)take(6291456);   // ld 768
    float* gt = C1;

    dim3 blk(256);

    // prep + converts
    prep_kernel<<<25344, blk, 0, stream>>>(W5, W6, W7, W8, W9, W10, W11, W12, W13, W14,
                                           W5t_h, W5t_l, WsQT_h, WsQT_l, W6t_h, W6t_l,
                                           W1112T, W78t, W1314t);
    cvt2_kernel<<<9216, blk, 0, stream>>>(Ha, Ha_h, Ha_l, 2359296);
    cvt2_kernel<<<3072, blk, 0, stream>>>(Hq, Hq_h, Hq_l, 786432);

    // stage 1 (fp32, exact selection)
    rnorm_kernel<<<65536, blk, 0, stream>>>(Hp, rp);
    rnorm_kernel<<<3072, blk, 0, stream>>>(Ha, ra);
    rnorm_kernel<<<1024, blk, 0, stream>>>(Hq, rq);
    simmax_kernel<<<1024, blk, 0, stream>>>(Hp, Ha, Hq, rp, ra, rq, amax);
    score_top2_kernel<<<32, dim3(64), 0, stream>>>(amax, topidx);
    gather_kernel<<<12288, blk, 0, stream>>>(Hp, topidx, HpsF, Hps_h, Hps_l);

    // score-feeding caches (bf16x3 == fp32-grade)
    mgemm3_kernel<0><<<dim3(48, 12), blk, 0, stream>>>(Ha_h, Ha_l, 768, 3072, W5t_h, W5t_l, C1, 768, nullptr);
    mgemm3_kernel<0><<<dim3(16, 24), blk, 0, stream>>>(Hq_h, Hq_l, 768, 1024, WsQT_h, WsQT_l, HqSens, 1536, nullptr);
    mgemm3_kernel<0><<<dim3(64, 12), blk, 0, stream>>>(Hps_h, Hps_l, 768, 4096, WsQT_h, WsQT_l, cache1, 768, nullptr);
    // S-path products (plain bf16, bf16 out)
    mgemm_kernel<0, 1><<<dim3(16, 24), blk, 0, stream>>>(Hq_h, 768, 1024, W1112T, nullptr, nullptr, 1536, HqS2_bf);
    mgemm_kernel<0, 1><<<dim3(64, 12), blk, 0, stream>>>(Hps_h, 768, 4096, W1112T + (long)768 * 768, nullptr, nullptr, 768, HpsW12_bf);

    // stage-2 QK (12 segs, 24x24)
    {
        QArgs qa{}; int si = 0;
        for (int i = 0; i < 4; i++)
            for (int j = 0; j < 4; j++) {
                if (j == i) continue;
                QSegT& s = qa.s[si];
                s.GL = C1 + (long)i * 24 * 768; s.glB = 73728; s.ldGL = 768;
                s.HY = Ha + (long)j * 24 * 768; s.hyB = 73728; s.ldHY = 768;
                s.G = G2 + (long)si * 18432; s.gB = 576;
                s.X = 24; s.Y = 24;
                si++;
            }
        qkA_kernel<<<12 * 32, blk, 0, stream>>>(qa);
    }
    // hats (12 segs, rows mode -> hi/lo bf16)
    {
        SArgs sa{}; int si = 0;
        for (int i = 0; i < 4; i++) {
            int jj = 0;
            for (int j = 0; j < 4; j++) {
                if (j == i) continue;
                SSegT& s = sa.s[si];
                s.G = G2 + (long)si * 18432; s.gB = 576;
                s.B = (const void*)(Ha + (long)j * 24 * 768); s.bB = 73728; s.ldB = 768;
                s.outF = nullptr;
                s.outH = hats_h + (long)i * 24 * 2304 + jj * 768;
                s.outL = hats_l + (long)i * 24 * 2304 + jj * 768;
                s.oB = 221184; s.ldO = 2304;
                s.R = 24; s.C = 24; s.mode = 0;
                si++; jj++;
            }
        }
        gb_kernel<0><<<12 * 32, blk, 0, stream>>>(sa);
    }
    // bar = hats@W6 (bf16x3, f32 + hi out); gt = bar@W78 + b8; Ho
    mgemm3_kernel<1><<<dim3(48, 12), blk, 0, stream>>>(hats_h, hats_l, 2304, 3072, W6t_h, W6t_l, bar, 768, bar_h);
    mgemm_kernel<1, 0><<<dim3(48, 12), blk, 0, stream>>>(bar_h, 768, 3072, W78t, b8, gt, 768, nullptr);
    hogate_kernel<<<9216, blk, 0, stream>>>(gt, bar, Ha, Ho, Ho_h, Ho_l);
    // cache4 = Ho@W10 (bf16x3); HoW11 (plain)
    mgemm3_kernel<0><<<dim3(48, 12), blk, 0, stream>>>(Ho_h, Ho_l, 768, 3072, WsQT_h + (long)768 * 768, WsQT_l + (long)768 * 768, cache4, 768, nullptr);
    mgemm_kernel<0, 1><<<dim3(48, 12), blk, 0, stream>>>(Ho_h, 768, 3072, W1112T, nullptr, nullptr, 768, HoW11_bf);

    // match G offsets (floats, within Gm)
    const long gA0 = 0, gA1 = 131072, gA5 = 524288, gA9 = 622592, gB0 = 720896, gB1 = 851968;

    {
        QArgs qa{};
        qa.s[0].GL = cache1; qa.s[0].glB = 98304; qa.s[0].ldGL = 768;
        qa.s[0].HY = Hq;     qa.s[0].hyB = 24576; qa.s[0].ldHY = 768;
        qa.s[0].G = Gm + gA0; qa.s[0].gB = 4096; qa.s[0].X = 128; qa.s[0].Y = 32;
        for (int i = 0; i < 4; i++) {
            QSegT& a1 = qa.s[1 + i];
            a1.GL = cache1; a1.glB = 98304; a1.ldGL = 768;
            a1.HY = Ho + (long)i * 24 * 768; a1.hyB = 73728; a1.ldHY = 768;
            a1.G = Gm + gA1 + (long)i * 98304; a1.gB = 3072; a1.X = 128; a1.Y = 24;
            QSegT& a5 = qa.s[5 + i];
            a5.GL = HqSens; a5.glB = 49152; a5.ldGL = 1536;
            a5.HY = Ho + (long)i * 24 * 768; a5.hyB = 73728; a5.ldHY = 768;
            a5.G = Gm + gA5 + (long)i * 24576; a5.gB = 768; a5.X = 32; a5.Y = 24;
            QSegT& a9 = qa.s[9 + i];
            a9.GL = cache4 + (long)i * 24 * 768; a9.glB = 73728; a9.ldGL = 768;
            a9.HY = Hq; a9.hyB = 24576; a9.ldHY = 768;
            a9.G = Gm + gA9 + (long)i * 24576; a9.gB = 768; a9.X = 24; a9.Y = 32;
        }
        qkA_kernel<<<13 * 32, blk, 0, stream>>>(qa);
    }
    {
        QArgs qa{};
        qa.s[0].GL = HqSens + 768; qa.s[0].glB = 49152; qa.s[0].ldGL = 1536;
        qa.s[0].HY = HpsF; qa.s[0].hyB = 98304; qa.s[0].ldHY = 768;
        qa.s[0].G = Gm + gB0; qa.s[0].gB = 4096; qa.s[0].X = 32; qa.s[0].Y = 128;
        for (int i = 0; i < 4; i++) {
            QSegT& s = qa.s[1 + i];
            s.GL = cache4 + (long)i * 24 * 768; s.glB = 73728; s.ldGL = 768;
            s.HY = HpsF; s.hyB = 98304; s.ldHY = 768;
            s.G = Gm + gB1 + (long)i * 98304; s.gB = 3072; s.X = 24; s.Y = 128;
        }
        qkB_kernel<<<5 * 32, blk, 0, stream>>>(qa);
    }
    // S (18 segs, max mode, bf16 B)
    {
        SArgs sa{};
        auto set = [&](int k, const float* G, long gB, const __bf16* Bp, long bB, int ldB,
                       float* oF, __bf16* oH, int R, int C) {
            SSegT& s = sa.s[k];
            s.G = G; s.gB = gB; s.B = (const void*)Bp; s.bB = bB; s.ldB = ldB;
            s.outF = oF; s.outH = oH; s.outL = nullptr; s.oB = 1536; s.ldO = 0;
            s.R = R; s.C = C; s.mode = 1;
        };
        set(0, Gm + gA0, 4096, HqS2_bf, 49152, 1536, S, S_h, 128, 32);
        for (int i = 0; i < 4; i++) {
            set(1 + i, Gm + gA1 + (long)i * 98304, 3072, HoW11_bf + (long)i * 24 * 768, 73728, 768,
                S + (long)(1 + i) * 49152, S_h + (long)(1 + i) * 49152, 128, 24);
            set(5 + i, Gm + gA5 + (long)i * 24576, 768, HoW11_bf + (long)i * 24 * 768, 73728, 768,
                S + (long)(5 + i) * 49152, S_h + (long)(5 + i) * 49152, 32, 24);
        }
        set(9, Gm + gB0, 4096, HpsW12_bf, 98304, 768, S + 768, S_h + 768, 32, 128);
        for (int i = 0; i < 4; i++) {
            set(10 + i, Gm + gB1 + (long)i * 98304, 3072, HpsW12_bf, 98304, 768,
                S + (long)(1 + i) * 49152 + 768, S_h + (long)(1 + i) * 49152 + 768, 24, 128);
            set(14 + i, Gm + gA9 + (long)i * 24576, 768, HqS2_bf + 768, 49152, 1536,
                S + (long)(5 + i) * 49152 + 768, S_h + (long)(5 + i) * 49152 + 768, 24, 32);
        }
        gb_kernel<1><<<18 * 32, blk, 0, stream>>>(sa);
    }

    // gating: gts = [Sxy|Syx] @ [W13;W14] + b14 (plain bf16 MFMA)
    mgemm_kernel<1, 0><<<dim3(5, 12), blk, 0, stream>>>(S_h, 1536, 288, W1314t, b14, gts, 768, nullptr);

    logits_kernel<<<128, blk, 0, stream>>>(S, gts, V, lg);
    lsm_kernel<<<1, dim3(32), 0, stream>>>(lg, out);
}

// Round 5
// 779.717 us; speedup vs baseline: 6.9004x; 1.2295x over previous
//
#include <hip/hip_runtime.h>
#include <math.h>

// B=32, N=32, P=64, Q=32, A=24, M=4, L=768, K=2

typedef __bf16 bf16x8 __attribute__((ext_vector_type(8)));
typedef float f32x4 __attribute__((ext_vector_type(4)));

// ---------------- prep: transposed weights (hi/lo bf16 for score-feeding, plain else) ----
__global__ void prep_kernel(const float* __restrict__ W5, const float* __restrict__ W6,
                            const float* __restrict__ W7, const float* __restrict__ W8,
                            const float* __restrict__ W9, const float* __restrict__ W10,
                            const float* __restrict__ W11, const float* __restrict__ W12,
                            const float* __restrict__ W13, const float* __restrict__ W14,
                            __bf16* __restrict__ W5t_h, __bf16* __restrict__ W5t_l,
                            __bf16* __restrict__ WsQT_h, __bf16* __restrict__ WsQT_l,
                            __bf16* __restrict__ W6t_h, __bf16* __restrict__ W6t_l,
                            __bf16* __restrict__ W1112T, __bf16* __restrict__ W78t,
                            __bf16* __restrict__ W1314t) {
    long i = (long)blockIdx.x * 256 + threadIdx.x;
    if (i < 589824) {
        int c = (int)(i / 768), r = (int)(i % 768);
        float v = W5[r * 768 + c];
        __bf16 h = (__bf16)v; W5t_h[i] = h; W5t_l[i] = (__bf16)(v - (float)h);
        return;
    } i -= 589824;
    if (i < 1179648) {
        int c = (int)(i / 768), r = (int)(i % 768);
        float v = (c < 768) ? W9[r * 768 + c] : W10[r * 768 + c - 768];
        __bf16 h = (__bf16)v; WsQT_h[i] = h; WsQT_l[i] = (__bf16)(v - (float)h);
        return;
    } i -= 1179648;
    if (i < 1769472) {
        int c = (int)(i / 2304), r = (int)(i % 2304);
        float v = W6[r * 768 + c];
        __bf16 h = (__bf16)v; W6t_h[i] = h; W6t_l[i] = (__bf16)(v - (float)h);
        return;
    } i -= 1769472;
    if (i < 1179648) {
        int c = (int)(i / 768), r = (int)(i % 768);
        W1112T[i] = (__bf16)((c < 768) ? W11[r * 768 + c] : W12[r * 768 + c - 768]);
        return;
    } i -= 1179648;
    if (i < 589824) {
        int c = (int)(i / 768), r = (int)(i % 768);
        W78t[i] = (__bf16)(W7[r * 768 + c] + W8[r * 768 + c]);
        return;
    } i -= 589824;
    if (i < 1179648) {
        int c = (int)(i / 1536), r = (int)(i % 1536);
        W1314t[i] = (__bf16)((r < 768) ? W13[r * 768 + c] : W14[(r - 768) * 768 + c]);
    }
}

__global__ void cvt2_kernel(const float* __restrict__ src, __bf16* __restrict__ h,
                            __bf16* __restrict__ l, long n) {
    long i = (long)blockIdx.x * 256 + threadIdx.x;
    if (i < n) {
        float v = src[i];
        __bf16 hv = (__bf16)v; h[i] = hv; l[i] = (__bf16)(v - (float)hv);
    }
}

// ---------------- stage 1: scoring ----------------
__global__ void rnorm_kernel(const float* __restrict__ X, float* __restrict__ out) {
    long row = blockIdx.x;
    const float* xr = X + row * 768;
    int t = threadIdx.x;
    float ss = 0.f;
    for (int l = t; l < 768; l += 256) { float v = xr[l]; ss += v * v; }
    for (int o = 32; o; o >>= 1) ss += __shfl_xor(ss, o);
    __shared__ float red[4];
    if ((t & 63) == 0) red[t >> 6] = ss;
    __syncthreads();
    if (t == 0) {
        float tot = red[0] + red[1] + red[2] + red[3];
        out[row] = 1.f / fmaxf(sqrtf(tot), 1e-8f);
    }
}

// MFMA bf16x3 simmax with fused Hp row norms.
// Per (b,n): A = Hp[b, n*64 .. n*64+63] (64x768 fp32, converted in-kernel),
// B = [Ha_h/l rows 0..95 | Hq_h/l rows 0..31] (128x768 bf16 h/l).
// amax[b,n,c] = max_p (A[p]·B[c]) * rp[p] * rc[c]
__global__ __launch_bounds__(256) void simmax_kernel(
    const float* __restrict__ Hp,
    const __bf16* __restrict__ Ha_h, const __bf16* __restrict__ Ha_l,
    const __bf16* __restrict__ Hq_h, const __bf16* __restrict__ Hq_l,
    const float* __restrict__ ra, const float* __restrict__ rq,
    float* __restrict__ amax) {
    constexpr int LDT = 72;  // 144B stride: 2-way bank aliasing on b128 (free)
    __shared__ alignas(16) __bf16 Ah[64 * LDT];
    __shared__ alignas(16) __bf16 Al[64 * LDT];
    __shared__ alignas(16) __bf16 Bh[128 * LDT];
    __shared__ alignas(16) __bf16 Bl[128 * LDT];
    __shared__ float rp_lds[64];
    __shared__ float wred[4][128];
    int b = blockIdx.x >> 5, n = blockIdx.x & 31;
    int t = threadIdx.x;
    const float* Ap = Hp + ((long)b * 2048 + n * 64) * 768;
    int srow = t >> 2, kq = (t & 3) << 4;       // A staging: row, 16-float chunk
    int brow = t >> 1, kh = (t & 1) << 5;       // B staging: row, 32-elt chunk
    const __bf16 *Bsh, *Bsl;
    if (brow < 96) {
        Bsh = Ha_h + (long)b * 73728 + (long)brow * 768;
        Bsl = Ha_l + (long)b * 73728 + (long)brow * 768;
    } else {
        Bsh = Hq_h + (long)b * 24576 + (long)(brow - 96) * 768;
        Bsl = Hq_l + (long)b * 24576 + (long)(brow - 96) * 768;
    }
    int w = t >> 6, l = t & 63;
    int fr = l & 15, g = l >> 4;
    int wr = w << 4;
    f32x4 acc[8] = {};
    float ss = 0.f;
    const float* Arow = Ap + (long)srow * 768 + kq;
    for (int k0 = 0; k0 < 768; k0 += 64) {
        float4 av0 = *(const float4*)(Arow + k0 + 0);
        float4 av1 = *(const float4*)(Arow + k0 + 4);
        float4 av2 = *(const float4*)(Arow + k0 + 8);
        float4 av3 = *(const float4*)(Arow + k0 + 12);
        bf16x8 vbh0 = *(const bf16x8*)(Bsh + k0 + kh);
        bf16x8 vbh1 = *(const bf16x8*)(Bsh + k0 + kh + 8);
        bf16x8 vbh2 = *(const bf16x8*)(Bsh + k0 + kh + 16);
        bf16x8 vbh3 = *(const bf16x8*)(Bsh + k0 + kh + 24);
        bf16x8 vbl0 = *(const bf16x8*)(Bsl + k0 + kh);
        bf16x8 vbl1 = *(const bf16x8*)(Bsl + k0 + kh + 8);
        bf16x8 vbl2 = *(const bf16x8*)(Bsl + k0 + kh + 16);
        bf16x8 vbl3 = *(const bf16x8*)(Bsl + k0 + kh + 24);
        float va[16];
        *(float4*)(va + 0) = av0; *(float4*)(va + 4) = av1;
        *(float4*)(va + 8) = av2; *(float4*)(va + 12) = av3;
        bf16x8 h0, h1, l0, l1;
#pragma unroll
        for (int i = 0; i < 8; i++) {
            float v = va[i]; __bf16 hv = (__bf16)v;
            h0[i] = hv; l0[i] = (__bf16)(v - (float)hv); ss += v * v;
            v = va[8 + i]; hv = (__bf16)v;
            h1[i] = hv; l1[i] = (__bf16)(v - (float)hv); ss += v * v;
        }
        __syncthreads();
        *(bf16x8*)(&Ah[srow * LDT + kq]) = h0;
        *(bf16x8*)(&Ah[srow * LDT + kq + 8]) = h1;
        *(bf16x8*)(&Al[srow * LDT + kq]) = l0;
        *(bf16x8*)(&Al[srow * LDT + kq + 8]) = l1;
        *(bf16x8*)(&Bh[brow * LDT + kh]) = vbh0;
        *(bf16x8*)(&Bh[brow * LDT + kh + 8]) = vbh1;
        *(bf16x8*)(&Bh[brow * LDT + kh + 16]) = vbh2;
        *(bf16x8*)(&Bh[brow * LDT + kh + 24]) = vbh3;
        *(bf16x8*)(&Bl[brow * LDT + kh]) = vbl0;
        *(bf16x8*)(&Bl[brow * LDT + kh + 8]) = vbl1;
        *(bf16x8*)(&Bl[brow * LDT + kh + 16]) = vbl2;
        *(bf16x8*)(&Bl[brow * LDT + kh + 24]) = vbl3;
        __syncthreads();
#pragma unroll
        for (int sub = 0; sub < 2; sub++) {
            int kb = sub * 32 + g * 8;
            bf16x8 fah = *(const bf16x8*)(&Ah[(wr + fr) * LDT + kb]);
            bf16x8 fal = *(const bf16x8*)(&Al[(wr + fr) * LDT + kb]);
#pragma unroll
            for (int c = 0; c < 8; c++) {
                bf16x8 fbh = *(const bf16x8*)(&Bh[(c * 16 + fr) * LDT + kb]);
                bf16x8 fbl = *(const bf16x8*)(&Bl[(c * 16 + fr) * LDT + kb]);
                acc[c] = __builtin_amdgcn_mfma_f32_16x16x32_bf16(fah, fbh, acc[c], 0, 0, 0);
                acc[c] = __builtin_amdgcn_mfma_f32_16x16x32_bf16(fah, fbl, acc[c], 0, 0, 0);
                acc[c] = __builtin_amdgcn_mfma_f32_16x16x32_bf16(fal, fbh, acc[c], 0, 0, 0);
            }
        }
    }
    // row norms: 4 consecutive lanes share a row
    ss += __shfl_xor(ss, 1);
    ss += __shfl_xor(ss, 2);
    if ((t & 3) == 0) rp_lds[srow] = 1.f / fmaxf(sqrtf(ss), 1e-8f);
    __syncthreads();
    float rpv[4];
#pragma unroll
    for (int r = 0; r < 4; r++) rpv[r] = rp_lds[wr + g * 4 + r];
#pragma unroll
    for (int c = 0; c < 8; c++) {
        float mx = acc[c][0] * rpv[0];
        mx = fmaxf(mx, acc[c][1] * rpv[1]);
        mx = fmaxf(mx, acc[c][2] * rpv[2]);
        mx = fmaxf(mx, acc[c][3] * rpv[3]);
        mx = fmaxf(mx, __shfl_xor(mx, 16));
        mx = fmaxf(mx, __shfl_xor(mx, 32));
        if (g == 0) wred[w][c * 16 + fr] = mx;
    }
    __syncthreads();
    if (t < 128) {
        float m = fmaxf(fmaxf(wred[0][t], wred[1][t]), fmaxf(wred[2][t], wred[3][t]));
        float rc = (t < 96) ? ra[b * 96 + t] : rq[b * 32 + (t - 96)];
        amax[((long)b * 32 + n) * 128 + t] = m * rc;
    }
}

__global__ void score_top2_kernel(const float* __restrict__ amax, int* __restrict__ idx) {
    int b = blockIdx.x, t = threadIdx.x;
    __shared__ float sc[32];
    if (t < 32) {
        const float* am = amax + ((long)b * 32 + t) * 128;
        float sa = 0.f, sq = 0.f;
        for (int c = 0; c < 96; c++) sa += am[c];
        for (int c = 96; c < 128; c++) sq += am[c];
        sc[t] = sa / 24.f + sq / 32.f;
    }
    __syncthreads();
    if (t == 0) {
        float m0 = -1e30f; int i0 = 0;
        for (int n = 0; n < 32; n++) if (sc[n] > m0) { m0 = sc[n]; i0 = n; }
        float m1 = -1e30f; int i1 = 0;
        for (int n = 0; n < 32; n++) if (n != i0 && sc[n] > m1) { m1 = sc[n]; i1 = n; }
        idx[b * 2] = i0; idx[b * 2 + 1] = i1;
    }
}

__global__ void gather_kernel(const float* __restrict__ Hp, const int* __restrict__ idx,
                              float* __restrict__ HpsF, __bf16* __restrict__ Hps_h,
                              __bf16* __restrict__ Hps_l) {
    long i = (long)blockIdx.x * 256 + threadIdx.x;
    if (i >= (long)32 * 128 * 768) return;
    int l = (int)(i % 768);
    long r = i / 768;
    int x = (int)(r % 128); int b = (int)(r / 128);
    int k = x >> 6, p = x & 63;
    int n = idx[b * 2 + k];
    float v = Hp[((long)b * 2048 + n * 64 + p) * 768 + l];
    HpsF[i] = v;
    __bf16 h = (__bf16)v; Hps_h[i] = h; Hps_l[i] = (__bf16)(v - (float)h);
}

// ---------------- bf16 MFMA GEMM (plain): C = A @ Wt^T [+bias] ----------------
template <int BIASF, int BOUT>
__global__ __launch_bounds__(256) void mgemm_kernel(
    const __bf16* __restrict__ A, int Kdim, int Mtot,
    const __bf16* __restrict__ Wt, const float* __restrict__ bias,
    float* __restrict__ C, int ldc, __bf16* __restrict__ Cb) {
    constexpr int LDT = 80;
    __shared__ alignas(16) __bf16 As[64 * LDT];
    __shared__ alignas(16) __bf16 Bs[64 * LDT];
    int t = threadIdx.x;
    int rowBase = blockIdx.x << 6, colBase = blockIdx.y << 6;
    int srow = t >> 2, skof = (t & 3) << 3;
    int arow = rowBase + srow;
    bool aok = arow < Mtot;
    const __bf16* Ap = A + (long)(aok ? arow : rowBase) * Kdim + skof;
    const __bf16* Wp = Wt + (long)(colBase + srow) * Kdim + skof;
    int w = t >> 6, l = t & 63;
    int wr = (w >> 1) << 5, wc = (w & 1) << 5;
    int fr = l & 15, g = l >> 4;
    f32x4 acc[2][2] = {};
    int nk = Kdim >> 6;
    for (int ks = 0; ks < nk; ks++) {
        bf16x8 a0 = *(const bf16x8*)(Ap);
        bf16x8 a1 = *(const bf16x8*)(Ap + 32);
        bf16x8 w0 = *(const bf16x8*)(Wp);
        bf16x8 w1 = *(const bf16x8*)(Wp + 32);
        Ap += 64; Wp += 64;
        __syncthreads();
        *(bf16x8*)(&As[srow * LDT + skof]) = a0;
        *(bf16x8*)(&As[srow * LDT + 32 + skof]) = a1;
        *(bf16x8*)(&Bs[srow * LDT + skof]) = w0;
        *(bf16x8*)(&Bs[srow * LDT + 32 + skof]) = w1;
        __syncthreads();
#pragma unroll
        for (int sub = 0; sub < 2; sub++) {
            int ko = sub * 32 + g * 8;
            bf16x8 fa0 = *(const bf16x8*)(&As[(wr + fr) * LDT + ko]);
            bf16x8 fa1 = *(const bf16x8*)(&As[(wr + 16 + fr) * LDT + ko]);
            bf16x8 fb0 = *(const bf16x8*)(&Bs[(wc + fr) * LDT + ko]);
            bf16x8 fb1 = *(const bf16x8*)(&Bs[(wc + 16 + fr) * LDT + ko]);
            acc[0][0] = __builtin_amdgcn_mfma_f32_16x16x32_bf16(fa0, fb0, acc[0][0], 0, 0, 0);
            acc[0][1] = __builtin_amdgcn_mfma_f32_16x16x32_bf16(fa0, fb1, acc[0][1], 0, 0, 0);
            acc[1][0] = __builtin_amdgcn_mfma_f32_16x16x32_bf16(fa1, fb0, acc[1][0], 0, 0, 0);
            acc[1][1] = __builtin_amdgcn_mfma_f32_16x16x32_bf16(fa1, fb1, acc[1][1], 0, 0, 0);
        }
    }
#pragma unroll
    for (int fi = 0; fi < 2; fi++)
#pragma unroll
    for (int fj = 0; fj < 2; fj++)
#pragma unroll
    for (int r = 0; r < 4; r++) {
        int row = rowBase + wr + fi * 16 + g * 4 + r;
        int col = colBase + wc + fj * 16 + (l & 15);
        if (row < Mtot) {
            float v = acc[fi][fj][r];
            if (BIASF) v += bias[col];
            if (BOUT == 0) C[(long)row * ldc + col] = v;
            else Cb[(long)row * ldc + col] = (__bf16)v;
        }
    }
}

// ---------------- bf16x3 split-precision MFMA GEMM ----------------
template <int WH>
__global__ __launch_bounds__(256) void mgemm3_kernel(
    const __bf16* __restrict__ Ah, const __bf16* __restrict__ Al, int Kdim, int Mtot,
    const __bf16* __restrict__ Wh, const __bf16* __restrict__ Wl,
    float* __restrict__ C, int ldc, __bf16* __restrict__ Cb) {
    constexpr int LDT = 80;
    __shared__ alignas(16) __bf16 Ahs[64 * LDT];
    __shared__ alignas(16) __bf16 Als[64 * LDT];
    __shared__ alignas(16) __bf16 Bhs[64 * LDT];
    __shared__ alignas(16) __bf16 Bls[64 * LDT];
    int t = threadIdx.x;
    int rowBase = blockIdx.x << 6, colBase = blockIdx.y << 6;
    int srow = t >> 2, skof = (t & 3) << 3;
    int arow = rowBase + srow;
    bool aok = arow < Mtot;
    long aoff = (long)(aok ? arow : rowBase) * Kdim + skof;
    long woff = (long)(colBase + srow) * Kdim + skof;
    const __bf16* Aph = Ah + aoff;
    const __bf16* Apl = Al + aoff;
    const __bf16* Wph = Wh + woff;
    const __bf16* Wpl = Wl + woff;
    int w = t >> 6, l = t & 63;
    int wr = (w >> 1) << 5, wc = (w & 1) << 5;
    int fr = l & 15, g = l >> 4;
    f32x4 acc[2][2] = {};
    int nk = Kdim >> 6;
    for (int ks = 0; ks < nk; ks++) {
        bf16x8 ah0 = *(const bf16x8*)(Aph);      bf16x8 ah1 = *(const bf16x8*)(Aph + 32);
        bf16x8 al0 = *(const bf16x8*)(Apl);      bf16x8 al1 = *(const bf16x8*)(Apl + 32);
        bf16x8 wh0 = *(const bf16x8*)(Wph);      bf16x8 wh1 = *(const bf16x8*)(Wph + 32);
        bf16x8 wl0 = *(const bf16x8*)(Wpl);      bf16x8 wl1 = *(const bf16x8*)(Wpl + 32);
        Aph += 64; Apl += 64; Wph += 64; Wpl += 64;
        __syncthreads();
        *(bf16x8*)(&Ahs[srow * LDT + skof]) = ah0; *(bf16x8*)(&Ahs[srow * LDT + 32 + skof]) = ah1;
        *(bf16x8*)(&Als[srow * LDT + skof]) = al0; *(bf16x8*)(&Als[srow * LDT + 32 + skof]) = al1;
        *(bf16x8*)(&Bhs[srow * LDT + skof]) = wh0; *(bf16x8*)(&Bhs[srow * LDT + 32 + skof]) = wh1;
        *(bf16x8*)(&Bls[srow * LDT + skof]) = wl0; *(bf16x8*)(&Bls[srow * LDT + 32 + skof]) = wl1;
        __syncthreads();
#pragma unroll
        for (int sub = 0; sub < 2; sub++) {
            int ko = sub * 32 + g * 8;
            bf16x8 fah[2], fal[2], fbh[2], fbl[2];
            fah[0] = *(const bf16x8*)(&Ahs[(wr + fr) * LDT + ko]);
            fah[1] = *(const bf16x8*)(&Ahs[(wr + 16 + fr) * LDT + ko]);
            fal[0] = *(const bf16x8*)(&Als[(wr + fr) * LDT + ko]);
            fal[1] = *(const bf16x8*)(&Als[(wr + 16 + fr) * LDT + ko]);
            fbh[0] = *(const bf16x8*)(&Bhs[(wc + fr) * LDT + ko]);
            fbh[1] = *(const bf16x8*)(&Bhs[(wc + 16 + fr) * LDT + ko]);
            fbl[0] = *(const bf16x8*)(&Bls[(wc + fr) * LDT + ko]);
            fbl[1] = *(const bf16x8*)(&Bls[(wc + 16 + fr) * LDT + ko]);
#pragma unroll
            for (int i = 0; i < 2; i++)
#pragma unroll
            for (int j = 0; j < 2; j++) {
                acc[i][j] = __builtin_amdgcn_mfma_f32_16x16x32_bf16(fah[i], fbh[j], acc[i][j], 0, 0, 0);
                acc[i][j] = __builtin_amdgcn_mfma_f32_16x16x32_bf16(fah[i], fbl[j], acc[i][j], 0, 0, 0);
                acc[i][j] = __builtin_amdgcn_mfma_f32_16x16x32_bf16(fal[i], fbh[j], acc[i][j], 0, 0, 0);
            }
        }
    }
#pragma unroll
    for (int fi = 0; fi < 2; fi++)
#pragma unroll
    for (int fj = 0; fj < 2; fj++)
#pragma unroll
    for (int r = 0; r < 4; r++) {
        int row = rowBase + wr + fi * 16 + g * 4 + r;
        int col = colBase + wc + fj * 16 + (l & 15);
        if (row < Mtot) {
            float v = acc[fi][fj][r];
            C[(long)row * ldc + col] = v;
            if (WH) Cb[(long)row * ldc + col] = (__bf16)v;
        }
    }
}

// ---------------- batched QK + softmax (fp32 scores) ----------------
struct QSegT {
    const float* GL; const float* HY; float* G;
    long glB, hyB, gB;
    int ldGL, ldHY, X, Y;
};
struct QArgs { QSegT s[13]; };

__global__ __launch_bounds__(256) void qkA_kernel(QArgs args) {
    int seg = blockIdx.x >> 5, b = blockIdx.x & 31;
    QSegT sg = args.s[seg];
    __shared__ float As[16][128];
    __shared__ float Bs[16][32];
    __shared__ float sc[128 * 33];
    int t = threadIdx.x;
    int arow = t >> 1, akof = (t & 1) * 8;
    int brow = t >> 3, bkof = (t & 7) * 2;
    bool aok = arow < sg.X, bok = brow < sg.Y;
    const float* ga = sg.GL + (long)b * sg.glB + (long)arow * sg.ldGL;
    const float* hb = sg.HY + (long)b * sg.hyB + (long)brow * sg.ldHY;
    int tx = t & 63, ty = t >> 6;
    float acc0[8] = {0.f}, acc1[8] = {0.f};
    for (int k0 = 0; k0 < 768; k0 += 16) {
        float4 a0 = make_float4(0, 0, 0, 0), a1 = make_float4(0, 0, 0, 0);
        float b0 = 0.f, b1v = 0.f;
        if (aok) { a0 = *(const float4*)(ga + k0 + akof); a1 = *(const float4*)(ga + k0 + akof + 4); }
        if (bok) { b0 = hb[k0 + bkof]; b1v = hb[k0 + bkof + 1]; }
        __syncthreads();
        As[akof + 0][arow] = a0.x; As[akof + 1][arow] = a0.y;
        As[akof + 2][arow] = a0.z; As[akof + 3][arow] = a0.w;
        As[akof + 4][arow] = a1.x; As[akof + 5][arow] = a1.y;
        As[akof + 6][arow] = a1.z; As[akof + 7][arow] = a1.w;
        Bs[bkof][brow] = b0; Bs[bkof + 1][brow] = b1v;
        __syncthreads();
#pragma unroll
        for (int kk = 0; kk < 16; kk++) {
            float alo = As[kk][tx], ahi = As[kk][tx + 64];
#pragma unroll
            for (int j = 0; j < 8; j++) {
                float bv = Bs[kk][ty * 8 + j];
                acc0[j] += alo * bv; acc1[j] += ahi * bv;
            }
        }
    }
#pragma unroll
    for (int j = 0; j < 8; j++) {
        sc[tx * 33 + ty * 8 + j] = acc0[j];
        sc[(tx + 64) * 33 + ty * 8 + j] = acc1[j];
    }
    __syncthreads();
    if (t < sg.X) {
        float* row = sc + t * 33;
        int Y = sg.Y;
        float m = row[0];
        for (int y = 1; y < Y; y++) m = fmaxf(m, row[y]);
        float s = 0.f;
        for (int y = 0; y < Y; y++) { float e = expf(row[y] - m); row[y] = e; s += e; }
        float inv = 1.f / s;
        float* go = sg.G + (long)b * sg.gB + (long)t * Y;
        for (int y = 0; y < Y; y++) go[y] = row[y] * inv;
    }
}

__global__ __launch_bounds__(256) void qkB_kernel(QArgs args) {
    int seg = blockIdx.x >> 5, b = blockIdx.x & 31;
    QSegT sg = args.s[seg];
    __shared__ float As[16][32];
    __shared__ float Bs[16][128];
    __shared__ float sc[32 * 129];
    int t = threadIdx.x;
    int arow = t >> 3, akof = (t & 7) * 2;
    int brow = t >> 1, bkof = (t & 1) * 8;
    bool aok = arow < sg.X;
    const float* ga = sg.GL + (long)b * sg.glB + (long)arow * sg.ldGL;
    const float* hb = sg.HY + (long)b * sg.hyB + (long)brow * sg.ldHY;
    int tx = t & 31, grp = t >> 5;
    float acc[16] = {0.f};
    for (int k0 = 0; k0 < 768; k0 += 16) {
        float a0 = 0.f, a1 = 0.f;
        if (aok) { a0 = ga[k0 + akof]; a1 = ga[k0 + akof + 1]; }
        float4 b0 = *(const float4*)(hb + k0 + bkof);
        float4 b1 = *(const float4*)(hb + k0 + bkof + 4);
        __syncthreads();
        As[akof][arow] = a0; As[akof + 1][arow] = a1;
        Bs[bkof + 0][brow] = b0.x; Bs[bkof + 1][brow] = b0.y;
        Bs[bkof + 2][brow] = b0.z; Bs[bkof + 3][brow] = b0.w;
        Bs[bkof + 4][brow] = b1.x; Bs[bkof + 5][brow] = b1.y;
        Bs[bkof + 6][brow] = b1.z; Bs[bkof + 7][brow] = b1.w;
        __syncthreads();
#pragma unroll
        for (int kk = 0; kk < 16; kk++) {
            float a = As[kk][tx];
#pragma unroll
            for (int j = 0; j < 16; j++) acc[j] += a * Bs[kk][grp * 16 + j];
        }
    }
#pragma unroll
    for (int j = 0; j < 16; j++) sc[tx * 129 + grp * 16 + j] = acc[j];
    __syncthreads();
    int row = t >> 3, lane = t & 7;
    if (row < sg.X) {
        float m = -1e30f;
        for (int k = 0; k < 16; k++) m = fmaxf(m, sc[row * 129 + lane + 8 * k]);
        for (int o = 1; o < 8; o <<= 1) m = fmaxf(m, __shfl_xor(m, o));
        float s = 0.f;
        for (int k = 0; k < 16; k++) {
            float e = expf(sc[row * 129 + lane + 8 * k] - m);
            sc[row * 129 + lane + 8 * k] = e; s += e;
        }
        for (int o = 1; o < 8; o <<= 1) s += __shfl_xor(s, o);
        float inv = 1.f / s;
        float* go = sg.G + (long)b * sg.gB + (long)row * 128;
        for (int k = 0; k < 16; k++) go[lane + 8 * k] = sc[row * 129 + lane + 8 * k] * inv;
    }
}

// ---------------- batched G@B ----------------
struct SSegT {
    const float* G; const void* B; float* outF; __bf16* outH; __bf16* outL;
    long gB, bB, oB;
    int ldB, ldO, R, C, mode;
};
struct SArgs { SSegT s[18]; };

template <int BFB>
__global__ __launch_bounds__(256) void gb_kernel(SArgs args) {
    int seg = blockIdx.x >> 5, b = blockIdx.x & 31;
    SSegT sg = args.s[seg];
    __shared__ float Gs[4096];
    int t = threadIdx.x;
    int n = sg.R * sg.C;
    for (int i = t; i < n; i += 256) Gs[i] = sg.G[(long)b * sg.gB + i];
    __syncthreads();
    int C = sg.C, R = sg.R;
    const float* BbF = (const float*)sg.B + (long)b * sg.bB;
    const __bf16* BbH = (const __bf16*)sg.B + (long)b * sg.bB;
    for (int l0 = 0; l0 < 768; l0 += 256) {
        int l = l0 + t;
        if (sg.mode) {
            float mx = 0.f;
            for (int rb = 0; rb < R; rb += 8) {
                float a[8] = {0.f};
                for (int c = 0; c < C; c++) {
                    float bv = BFB ? (float)BbH[(long)c * sg.ldB + l] : BbF[(long)c * sg.ldB + l];
#pragma unroll
                    for (int r8 = 0; r8 < 8; r8++) a[r8] += Gs[(rb + r8) * C + c] * bv;
                }
#pragma unroll
                for (int r8 = 0; r8 < 8; r8++) mx = fmaxf(mx, a[r8]);
            }
            sg.outF[(long)b * sg.oB + l] = mx;
            sg.outH[(long)b * sg.oB + l] = (__bf16)mx;
        } else {
            for (int rb = 0; rb < R; rb += 8) {
                float a[8] = {0.f};
                for (int c = 0; c < C; c++) {
                    float bv = BFB ? (float)BbH[(long)c * sg.ldB + l] : BbF[(long)c * sg.ldB + l];
#pragma unroll
                    for (int r8 = 0; r8 < 8; r8++) a[r8] += Gs[(rb + r8) * C + c] * bv;
                }
#pragma unroll
                for (int r8 = 0; r8 < 8; r8++) {
                    float v = fmaxf(a[r8], 0.f);
                    __bf16 h = (__bf16)v;
                    long o = (long)b * sg.oB + (long)(rb + r8) * sg.ldO + l;
                    sg.outH[o] = h;
                    sg.outL[o] = (__bf16)(v - (float)h);
                }
            }
        }
    }
}

// ---------------- elementwise ----------------
__global__ void hogate_kernel(const float* __restrict__ gt, const float* __restrict__ bar,
                              const float* __restrict__ Ha, float* __restrict__ Ho,
                              __bf16* __restrict__ Ho_h, __bf16* __restrict__ Ho_l) {
    long idx = (long)blockIdx.x * 256 + threadIdx.x;
    if (idx >= (long)32 * 96 * 768) return;
    float g = 1.f / (1.f + expf(-gt[idx]));
    float v = g * Ha[idx] + (1.f - g) * bar[idx];
    Ho[idx] = v;
    __bf16 h = (__bf16)v; Ho_h[idx] = h; Ho_l[idx] = (__bf16)(v - (float)h);
}

__global__ void logits_kernel(const float* __restrict__ S, const float* __restrict__ gts,
                              const float* __restrict__ V, float* __restrict__ lg) {
    int blk = blockIdx.x; int b = blk >> 2, i = blk & 3;
    int t = threadIdx.x;
    int ms[3] = {0, 1 + i, 5 + i};
    float p = 0.f;
    for (int k = 0; k < 3; k++) {
        int m = ms[k];
        const float* Sr = S + (long)m * 49152 + (long)b * 1536;
        const float* gr = gts + ((long)m * 32 + b) * 768;
        const float* Vr = V + k * 768;
        for (int l = t; l < 768; l += 256) {
            float g = 1.f / (1.f + expf(-gr[l]));
            p += (g * Sr[l] + (1.f - g) * Sr[768 + l]) * Vr[l];
        }
    }
    for (int o = 32; o; o >>= 1) p += __shfl_xor(p, o);
    __shared__ float red[4];
    if ((t & 63) == 0) red[t >> 6] = p;
    __syncthreads();
    if (t == 0) lg[blk] = red[0] + red[1] + red[2] + red[3];
}

__global__ void lsm_kernel(const float* __restrict__ lg, float* __restrict__ out) {
    int b = threadIdx.x;
    if (b >= 32) return;
    float x0 = lg[b * 4 + 0], x1 = lg[b * 4 + 1], x2 = lg[b * 4 + 2], x3 = lg[b * 4 + 3];
    float m = fmaxf(fmaxf(x0, x1), fmaxf(x2, x3));
    float s = expf(x0 - m) + expf(x1 - m) + expf(x2 - m) + expf(x3 - m);
    float ls = m + logf(s);
    out[b * 4 + 0] = x0 - ls; out[b * 4 + 1] = x1 - ls;
    out[b * 4 + 2] = x2 - ls; out[b * 4 + 3] = x3 - ls;
}

// ---------------- host ----------------
extern "C" void kernel_launch(void* const* d_in, const int* in_sizes, int n_in,
                              void* d_out, int out_size, void* d_ws, size_t ws_size,
                              hipStream_t stream) {
    const float* Hp  = (const float*)d_in[0];
    const float* Hq  = (const float*)d_in[1];
    const float* Ha  = (const float*)d_in[2];
    const float* W5  = (const float*)d_in[3];
    const float* W6  = (const float*)d_in[4];
    const float* W7  = (const float*)d_in[5];
    const float* W8  = (const float*)d_in[6];
    const float* b8  = (const float*)d_in[7];
    const float* W9  = (const float*)d_in[8];
    const float* W10 = (const float*)d_in[9];
    const float* W11 = (const float*)d_in[10];
    const float* W12 = (const float*)d_in[11];
    const float* W13 = (const float*)d_in[12];
    const float* W14 = (const float*)d_in[13];
    const float* b14 = (const float*)d_in[14];
    const float* V   = (const float*)d_in[15];
    float* out = (float*)d_out;
    (void)in_sizes; (void)n_in; (void)out_size; (void)ws_size;

    char* base = (char*)d_ws;
    size_t off = 0;
    auto take = [&](size_t bytes) { char* p = base + off; off += (bytes + 15) & ~15UL; return p; };

    // bf16 weights
    __bf16* W5t_h  = (__bf16*)take(1179648);
    __bf16* W5t_l  = (__bf16*)take(1179648);
    __bf16* WsQT_h = (__bf16*)take(2359296);
    __bf16* WsQT_l = (__bf16*)take(2359296);
    __bf16* W6t_h  = (__bf16*)take(3538944);
    __bf16* W6t_l  = (__bf16*)take(3538944);
    __bf16* W1112T = (__bf16*)take(2359296);
    __bf16* W78t   = (__bf16*)take(1179648);
    __bf16* W1314t = (__bf16*)take(2359296);
    // fp32
    float* ra     = (float*)take(12288);
    float* rq     = (float*)take(4096);
    float* amax   = (float*)take(524288);
    int*   topidx = (int*)take(256);
    float* HpsF   = (float*)take(12582912);
    float* C1     = (float*)take(9437184);   // Ha@W5; reused later as gt
    float* HqSens = (float*)take(6291456);   // [c2|c3] ld 1536
    float* cache1 = (float*)take(12582912);  // Hps@W9, ld 768
    float* bar    = (float*)take(9437184);
    float* Ho     = (float*)take(9437184);
    float* G2     = (float*)take(884736);
    float* lg     = (float*)take(512);
    // bf16 activations
    char* HaReg   = take(9437184);           // Ha_h/l; later bar_h + S_h
    __bf16* Ha_h  = (__bf16*)HaReg;
    __bf16* Ha_l  = (__bf16*)(HaReg + 4718592);
    __bf16* bar_h = (__bf16*)HaReg;                 // alias (Ha_h dead after simmax+C1)
    __bf16* S_h   = (__bf16*)(HaReg + 4718592);     // alias (Ha_l dead after simmax+C1)
    __bf16* Hq_h  = (__bf16*)take(1572864);
    __bf16* Hq_l  = (__bf16*)take(1572864);
    __bf16* Hps_h = (__bf16*)take(6291456);
    __bf16* Hps_l = (__bf16*)take(6291456);
    __bf16* Ho_h  = (__bf16*)take(4718592);
    __bf16* Ho_l  = (__bf16*)take(4718592);
    char* HatsReg = take(28311552);          // hats_h/l; later cache4,HoW11_bf,Gm,S,gts
    __bf16* hats_h = (__bf16*)HatsReg;
    __bf16* hats_l = (__bf16*)(HatsReg + 14155776);
    float*  cache4    = (float*)HatsReg;                       // alias (post-bar)
    __bf16* HoW11_bf  = (__bf16*)(HatsReg + 9437184);
    float*  Gm        = (float*)(HatsReg + 14155776);
    float*  S         = (float*)(HatsReg + 19136512);
    float*  gts       = (float*)(HatsReg + 20905984);
    __bf16* HqS2_bf   = (__bf16*)take(3145728);   // [HqW11|HqW12] ld 1536
    __bf16* HpsW12_bf = (__bf16*)take(6291456);   // ld 768
    float* gt = C1;

    dim3 blk(256);

    // prep + converts
    prep_kernel<<<25344, blk, 0, stream>>>(W5, W6, W7, W8, W9, W10, W11, W12, W13, W14,
                                           W5t_h, W5t_l, WsQT_h, WsQT_l, W6t_h, W6t_l,
                                           W1112T, W78t, W1314t);
    cvt2_kernel<<<9216, blk, 0, stream>>>(Ha, Ha_h, Ha_l, 2359296);
    cvt2_kernel<<<3072, blk, 0, stream>>>(Hq, Hq_h, Hq_l, 786432);

    // stage 1: B-side norms (tiny) + fused MFMA simmax (Hp norms computed in-kernel)
    rnorm_kernel<<<3072, blk, 0, stream>>>(Ha, ra);
    rnorm_kernel<<<1024, blk, 0, stream>>>(Hq, rq);
    simmax_kernel<<<1024, blk, 0, stream>>>(Hp, Ha_h, Ha_l, Hq_h, Hq_l, ra, rq, amax);
    score_top2_kernel<<<32, dim3(64), 0, stream>>>(amax, topidx);
    gather_kernel<<<12288, blk, 0, stream>>>(Hp, topidx, HpsF, Hps_h, Hps_l);

    // score-feeding caches (bf16x3 == fp32-grade)
    mgemm3_kernel<0><<<dim3(48, 12), blk, 0, stream>>>(Ha_h, Ha_l, 768, 3072, W5t_h, W5t_l, C1, 768, nullptr);
    mgemm3_kernel<0><<<dim3(16, 24), blk, 0, stream>>>(Hq_h, Hq_l, 768, 1024, WsQT_h, WsQT_l, HqSens, 1536, nullptr);
    mgemm3_kernel<0><<<dim3(64, 12), blk, 0, stream>>>(Hps_h, Hps_l, 768, 4096, WsQT_h, WsQT_l, cache1, 768, nullptr);
    // S-path products (plain bf16, bf16 out)
    mgemm_kernel<0, 1><<<dim3(16, 24), blk, 0, stream>>>(Hq_h, 768, 1024, W1112T, nullptr, nullptr, 1536, HqS2_bf);
    mgemm_kernel<0, 1><<<dim3(64, 12), blk, 0, stream>>>(Hps_h, 768, 4096, W1112T + (long)768 * 768, nullptr, nullptr, 768, HpsW12_bf);

    // stage-2 QK (12 segs, 24x24)
    {
        QArgs qa{}; int si = 0;
        for (int i = 0; i < 4; i++)
            for (int j = 0; j < 4; j++) {
                if (j == i) continue;
                QSegT& s = qa.s[si];
                s.GL = C1 + (long)i * 24 * 768; s.glB = 73728; s.ldGL = 768;
                s.HY = Ha + (long)j * 24 * 768; s.hyB = 73728; s.ldHY = 768;
                s.G = G2 + (long)si * 18432; s.gB = 576;
                s.X = 24; s.Y = 24;
                si++;
            }
        qkA_kernel<<<12 * 32, blk, 0, stream>>>(qa);
    }
    // hats (12 segs, rows mode -> hi/lo bf16)
    {
        SArgs sa{}; int si = 0;
        for (int i = 0; i < 4; i++) {
            int jj = 0;
            for (int j = 0; j < 4; j++) {
                if (j == i) continue;
                SSegT& s = sa.s[si];
                s.G = G2 + (long)si * 18432; s.gB = 576;
                s.B = (const void*)(Ha + (long)j * 24 * 768); s.bB = 73728; s.ldB = 768;
                s.outF = nullptr;
                s.outH = hats_h + (long)i * 24 * 2304 + jj * 768;
                s.outL = hats_l + (long)i * 24 * 2304 + jj * 768;
                s.oB = 221184; s.ldO = 2304;
                s.R = 24; s.C = 24; s.mode = 0;
                si++; jj++;
            }
        }
        gb_kernel<0><<<12 * 32, blk, 0, stream>>>(sa);
    }
    // bar = hats@W6 (bf16x3, f32 + hi out); gt = bar@W78 + b8; Ho
    mgemm3_kernel<1><<<dim3(48, 12), blk, 0, stream>>>(hats_h, hats_l, 2304, 3072, W6t_h, W6t_l, bar, 768, bar_h);
    mgemm_kernel<1, 0><<<dim3(48, 12), blk, 0, stream>>>(bar_h, 768, 3072, W78t, b8, gt, 768, nullptr);
    hogate_kernel<<<9216, blk, 0, stream>>>(gt, bar, Ha, Ho, Ho_h, Ho_l);
    // cache4 = Ho@W10 (bf16x3); HoW11 (plain)
    mgemm3_kernel<0><<<dim3(48, 12), blk, 0, stream>>>(Ho_h, Ho_l, 768, 3072, WsQT_h + (long)768 * 768, WsQT_l + (long)768 * 768, cache4, 768, nullptr);
    mgemm_kernel<0, 1><<<dim3(48, 12), blk, 0, stream>>>(Ho_h, 768, 3072, W1112T, nullptr, nullptr, 768, HoW11_bf);

    // match G offsets (floats, within Gm)
    const long gA0 = 0, gA1 = 131072, gA5 = 524288, gA9 = 622592, gB0 = 720896, gB1 = 851968;

    {
        QArgs qa{};
        qa.s[0].GL = cache1; qa.s[0].glB = 98304; qa.s[0].ldGL = 768;
        qa.s[0].HY = Hq;     qa.s[0].hyB = 24576; qa.s[0].ldHY = 768;
        qa.s[0].G = Gm + gA0; qa.s[0].gB = 4096; qa.s[0].X = 128; qa.s[0].Y = 32;
        for (int i = 0; i < 4; i++) {
            QSegT& a1 = qa.s[1 + i];
            a1.GL = cache1; a1.glB = 98304; a1.ldGL = 768;
            a1.HY = Ho + (long)i * 24 * 768; a1.hyB = 73728; a1.ldHY = 768;
            a1.G = Gm + gA1 + (long)i * 98304; a1.gB = 3072; a1.X = 128; a1.Y = 24;
            QSegT& a5 = qa.s[5 + i];
            a5.GL = HqSens; a5.glB = 49152; a5.ldGL = 1536;
            a5.HY = Ho + (long)i * 24 * 768; a5.hyB = 73728; a5.ldHY = 768;
            a5.G = Gm + gA5 + (long)i * 24576; a5.gB = 768; a5.X = 32; a5.Y = 24;
            QSegT& a9 = qa.s[9 + i];
            a9.GL = cache4 + (long)i * 24 * 768; a9.glB = 73728; a9.ldGL = 768;
            a9.HY = Hq; a9.hyB = 24576; a9.ldHY = 768;
            a9.G = Gm + gA9 + (long)i * 24576; a9.gB = 768; a9.X = 24; a9.Y = 32;
        }
        qkA_kernel<<<13 * 32, blk, 0, stream>>>(qa);
    }
    {
        QArgs qa{};
        qa.s[0].GL = HqSens + 768; qa.s[0].glB = 49152; qa.s[0].ldGL = 1536;
        qa.s[0].HY = HpsF; qa.s[0].hyB = 98304; qa.s[0].ldHY = 768;
        qa.s[0].G = Gm + gB0; qa.s[0].gB = 4096; qa.s[0].X = 32; qa.s[0].Y = 128;
        for (int i = 0; i < 4; i++) {
            QSegT& s = qa.s[1 + i];
            s.GL = cache4 + (long)i * 24 * 768; s.glB = 73728; s.ldGL = 768;
            s.HY = HpsF; s.hyB = 98304; s.ldHY = 768;
            s.G = Gm + gB1 + (long)i * 98304; s.gB = 3072; s.X = 24; s.Y = 128;
        }
        qkB_kernel<<<5 * 32, blk, 0, stream>>>(qa);
    }
    // S (18 segs, max mode, bf16 B)
    {
        SArgs sa{};
        auto set = [&](int k, const float* G, long gB, const __bf16* Bp, long bB, int ldB,
                       float* oF, __bf16* oH, int R, int C) {
            SSegT& s = sa.s[k];
            s.G = G; s.gB = gB; s.B = (const void*)Bp; s.bB = bB; s.ldB = ldB;
            s.outF = oF; s.outH = oH; s.outL = nullptr; s.oB = 1536; s.ldO = 0;
            s.R = R; s.C = C; s.mode = 1;
        };
        set(0, Gm + gA0, 4096, HqS2_bf, 49152, 1536, S, S_h, 128, 32);
        for (int i = 0; i < 4; i++) {
            set(1 + i, Gm + gA1 + (long)i * 98304, 3072, HoW11_bf + (long)i * 24 * 768, 73728, 768,
                S + (long)(1 + i) * 49152, S_h + (long)(1 + i) * 49152, 128, 24);
            set(5 + i, Gm + gA5 + (long)i * 24576, 768, HoW11_bf + (long)i * 24 * 768, 73728, 768,
                S + (long)(5 + i) * 49152, S_h + (long)(5 + i) * 49152, 32, 24);
        }
        set(9, Gm + gB0, 4096, HpsW12_bf, 98304, 768, S + 768, S_h + 768, 32, 128);
        for (int i = 0; i < 4; i++) {
            set(10 + i, Gm + gB1 + (long)i * 98304, 3072, HpsW12_bf, 98304, 768,
                S + (long)(1 + i) * 49152 + 768, S_h + (long)(1 + i) * 49152 + 768, 24, 128);
            set(14 + i, Gm + gA9 + (long)i * 24576, 768, HqS2_bf + 768, 49152, 1536,
                S + (long)(5 + i) * 49152 + 768, S_h + (long)(5 + i) * 49152 + 768, 24, 32);
        }
        gb_kernel<1><<<18 * 32, blk, 0, stream>>>(sa);
    }

    // gating: gts = [Sxy|Syx] @ [W13;W14] + b14 (plain bf16 MFMA)
    mgemm_kernel<1, 0><<<dim3(5, 12), blk, 0, stream>>>(S_h, 1536, 288, W1314t, b14, gts, 768, nullptr);

    logits_kernel<<<128, blk, 0, stream>>>(S, gts, V, lg);
    lsm_kernel<<<1, dim3(32), 0, stream>>>(lg, out);
}

// Round 6
// 622.569 us; speedup vs baseline: 8.6422x; 1.2524x over previous
//
#include <hip/hip_runtime.h>
#include <math.h>

// B=32, N=32, P=64, Q=32, A=24, M=4, L=768, K=2

typedef __bf16 bf16x8 __attribute__((ext_vector_type(8)));
typedef float f32x4 __attribute__((ext_vector_type(4)));

// ---------------- prep: transposed weights (hi/lo bf16 for score-feeding, plain else) ----
__global__ void prep_kernel(const float* __restrict__ W5, const float* __restrict__ W6,
                            const float* __restrict__ W7, const float* __restrict__ W8,
                            const float* __restrict__ W9, const float* __restrict__ W10,
                            const float* __restrict__ W11, const float* __restrict__ W12,
                            const float* __restrict__ W13, const float* __restrict__ W14,
                            __bf16* __restrict__ W5t_h, __bf16* __restrict__ W5t_l,
                            __bf16* __restrict__ WsQT_h, __bf16* __restrict__ WsQT_l,
                            __bf16* __restrict__ W6t_h, __bf16* __restrict__ W6t_l,
                            __bf16* __restrict__ W1112T, __bf16* __restrict__ W78t,
                            __bf16* __restrict__ W1314t) {
    long i = (long)blockIdx.x * 256 + threadIdx.x;
    if (i < 589824) {
        int c = (int)(i / 768), r = (int)(i % 768);
        float v = W5[r * 768 + c];
        __bf16 h = (__bf16)v; W5t_h[i] = h; W5t_l[i] = (__bf16)(v - (float)h);
        return;
    } i -= 589824;
    if (i < 1179648) {
        int c = (int)(i / 768), r = (int)(i % 768);
        float v = (c < 768) ? W9[r * 768 + c] : W10[r * 768 + c - 768];
        __bf16 h = (__bf16)v; WsQT_h[i] = h; WsQT_l[i] = (__bf16)(v - (float)h);
        return;
    } i -= 1179648;
    if (i < 1769472) {
        int c = (int)(i / 2304), r = (int)(i % 2304);
        float v = W6[r * 768 + c];
        __bf16 h = (__bf16)v; W6t_h[i] = h; W6t_l[i] = (__bf16)(v - (float)h);
        return;
    } i -= 1769472;
    if (i < 1179648) {
        int c = (int)(i / 768), r = (int)(i % 768);
        W1112T[i] = (__bf16)((c < 768) ? W11[r * 768 + c] : W12[r * 768 + c - 768]);
        return;
    } i -= 1179648;
    if (i < 589824) {
        int c = (int)(i / 768), r = (int)(i % 768);
        W78t[i] = (__bf16)(W7[r * 768 + c] + W8[r * 768 + c]);
        return;
    } i -= 589824;
    if (i < 1179648) {
        int c = (int)(i / 1536), r = (int)(i % 1536);
        W1314t[i] = (__bf16)((r < 768) ? W13[r * 768 + c] : W14[(r - 768) * 768 + c]);
    }
}

__global__ void cvt2_kernel(const float* __restrict__ src, __bf16* __restrict__ h,
                            __bf16* __restrict__ l, long n) {
    long i = (long)blockIdx.x * 256 + threadIdx.x;
    if (i < n) {
        float v = src[i];
        __bf16 hv = (__bf16)v; h[i] = hv; l[i] = (__bf16)(v - (float)hv);
    }
}

// ---------------- stage 1: scoring ----------------
__global__ void rnorm_kernel(const float* __restrict__ X, float* __restrict__ out) {
    long row = blockIdx.x;
    const float* xr = X + row * 768;
    int t = threadIdx.x;
    float ss = 0.f;
    for (int l = t; l < 768; l += 256) { float v = xr[l]; ss += v * v; }
    for (int o = 32; o; o >>= 1) ss += __shfl_xor(ss, o);
    __shared__ float red[4];
    if ((t & 63) == 0) red[t >> 6] = ss;
    __syncthreads();
    if (t == 0) {
        float tot = red[0] + red[1] + red[2] + red[3];
        out[row] = 1.f / fmaxf(sqrtf(tot), 1e-8f);
    }
}

// MFMA bf16x3 simmax with fused Hp row norms.
__global__ __launch_bounds__(256) void simmax_kernel(
    const float* __restrict__ Hp,
    const __bf16* __restrict__ Ha_h, const __bf16* __restrict__ Ha_l,
    const __bf16* __restrict__ Hq_h, const __bf16* __restrict__ Hq_l,
    const float* __restrict__ ra, const float* __restrict__ rq,
    float* __restrict__ amax) {
    constexpr int LDT = 72;
    __shared__ alignas(16) __bf16 Ah[64 * LDT];
    __shared__ alignas(16) __bf16 Al[64 * LDT];
    __shared__ alignas(16) __bf16 Bh[128 * LDT];
    __shared__ alignas(16) __bf16 Bl[128 * LDT];
    __shared__ float rp_lds[64];
    __shared__ float wred[4][128];
    int b = blockIdx.x >> 5, n = blockIdx.x & 31;
    int t = threadIdx.x;
    const float* Ap = Hp + ((long)b * 2048 + n * 64) * 768;
    int srow = t >> 2, kq = (t & 3) << 4;
    int brow = t >> 1, kh = (t & 1) << 5;
    const __bf16 *Bsh, *Bsl;
    if (brow < 96) {
        Bsh = Ha_h + (long)b * 73728 + (long)brow * 768;
        Bsl = Ha_l + (long)b * 73728 + (long)brow * 768;
    } else {
        Bsh = Hq_h + (long)b * 24576 + (long)(brow - 96) * 768;
        Bsl = Hq_l + (long)b * 24576 + (long)(brow - 96) * 768;
    }
    int w = t >> 6, l = t & 63;
    int fr = l & 15, g = l >> 4;
    int wr = w << 4;
    f32x4 acc[8] = {};
    float ss = 0.f;
    const float* Arow = Ap + (long)srow * 768 + kq;
    for (int k0 = 0; k0 < 768; k0 += 64) {
        float4 av0 = *(const float4*)(Arow + k0 + 0);
        float4 av1 = *(const float4*)(Arow + k0 + 4);
        float4 av2 = *(const float4*)(Arow + k0 + 8);
        float4 av3 = *(const float4*)(Arow + k0 + 12);
        bf16x8 vbh0 = *(const bf16x8*)(Bsh + k0 + kh);
        bf16x8 vbh1 = *(const bf16x8*)(Bsh + k0 + kh + 8);
        bf16x8 vbh2 = *(const bf16x8*)(Bsh + k0 + kh + 16);
        bf16x8 vbh3 = *(const bf16x8*)(Bsh + k0 + kh + 24);
        bf16x8 vbl0 = *(const bf16x8*)(Bsl + k0 + kh);
        bf16x8 vbl1 = *(const bf16x8*)(Bsl + k0 + kh + 8);
        bf16x8 vbl2 = *(const bf16x8*)(Bsl + k0 + kh + 16);
        bf16x8 vbl3 = *(const bf16x8*)(Bsl + k0 + kh + 24);
        float va[16];
        *(float4*)(va + 0) = av0; *(float4*)(va + 4) = av1;
        *(float4*)(va + 8) = av2; *(float4*)(va + 12) = av3;
        bf16x8 h0, h1, l0, l1;
#pragma unroll
        for (int i = 0; i < 8; i++) {
            float v = va[i]; __bf16 hv = (__bf16)v;
            h0[i] = hv; l0[i] = (__bf16)(v - (float)hv); ss += v * v;
            v = va[8 + i]; hv = (__bf16)v;
            h1[i] = hv; l1[i] = (__bf16)(v - (float)hv); ss += v * v;
        }
        __syncthreads();
        *(bf16x8*)(&Ah[srow * LDT + kq]) = h0;
        *(bf16x8*)(&Ah[srow * LDT + kq + 8]) = h1;
        *(bf16x8*)(&Al[srow * LDT + kq]) = l0;
        *(bf16x8*)(&Al[srow * LDT + kq + 8]) = l1;
        *(bf16x8*)(&Bh[brow * LDT + kh]) = vbh0;
        *(bf16x8*)(&Bh[brow * LDT + kh + 8]) = vbh1;
        *(bf16x8*)(&Bh[brow * LDT + kh + 16]) = vbh2;
        *(bf16x8*)(&Bh[brow * LDT + kh + 24]) = vbh3;
        *(bf16x8*)(&Bl[brow * LDT + kh]) = vbl0;
        *(bf16x8*)(&Bl[brow * LDT + kh + 8]) = vbl1;
        *(bf16x8*)(&Bl[brow * LDT + kh + 16]) = vbl2;
        *(bf16x8*)(&Bl[brow * LDT + kh + 24]) = vbl3;
        __syncthreads();
#pragma unroll
        for (int sub = 0; sub < 2; sub++) {
            int kb = sub * 32 + g * 8;
            bf16x8 fah = *(const bf16x8*)(&Ah[(wr + fr) * LDT + kb]);
            bf16x8 fal = *(const bf16x8*)(&Al[(wr + fr) * LDT + kb]);
#pragma unroll
            for (int c = 0; c < 8; c++) {
                bf16x8 fbh = *(const bf16x8*)(&Bh[(c * 16 + fr) * LDT + kb]);
                bf16x8 fbl = *(const bf16x8*)(&Bl[(c * 16 + fr) * LDT + kb]);
                acc[c] = __builtin_amdgcn_mfma_f32_16x16x32_bf16(fah, fbh, acc[c], 0, 0, 0);
                acc[c] = __builtin_amdgcn_mfma_f32_16x16x32_bf16(fah, fbl, acc[c], 0, 0, 0);
                acc[c] = __builtin_amdgcn_mfma_f32_16x16x32_bf16(fal, fbh, acc[c], 0, 0, 0);
            }
        }
    }
    ss += __shfl_xor(ss, 1);
    ss += __shfl_xor(ss, 2);
    if ((t & 3) == 0) rp_lds[srow] = 1.f / fmaxf(sqrtf(ss), 1e-8f);
    __syncthreads();
    float rpv[4];
#pragma unroll
    for (int r = 0; r < 4; r++) rpv[r] = rp_lds[wr + g * 4 + r];
#pragma unroll
    for (int c = 0; c < 8; c++) {
        float mx = acc[c][0] * rpv[0];
        mx = fmaxf(mx, acc[c][1] * rpv[1]);
        mx = fmaxf(mx, acc[c][2] * rpv[2]);
        mx = fmaxf(mx, acc[c][3] * rpv[3]);
        mx = fmaxf(mx, __shfl_xor(mx, 16));
        mx = fmaxf(mx, __shfl_xor(mx, 32));
        if (g == 0) wred[w][c * 16 + fr] = mx;
    }
    __syncthreads();
    if (t < 128) {
        float m = fmaxf(fmaxf(wred[0][t], wred[1][t]), fmaxf(wred[2][t], wred[3][t]));
        float rc = (t < 96) ? ra[b * 96 + t] : rq[b * 32 + (t - 96)];
        amax[((long)b * 32 + n) * 128 + t] = m * rc;
    }
}

__global__ void score_top2_kernel(const float* __restrict__ amax, int* __restrict__ idx) {
    int b = blockIdx.x, t = threadIdx.x;
    __shared__ float sc[32];
    if (t < 32) {
        const float* am = amax + ((long)b * 32 + t) * 128;
        float sa = 0.f, sq = 0.f;
        for (int c = 0; c < 96; c++) sa += am[c];
        for (int c = 96; c < 128; c++) sq += am[c];
        sc[t] = sa / 24.f + sq / 32.f;
    }
    __syncthreads();
    if (t == 0) {
        float m0 = -1e30f; int i0 = 0;
        for (int n = 0; n < 32; n++) if (sc[n] > m0) { m0 = sc[n]; i0 = n; }
        float m1 = -1e30f; int i1 = 0;
        for (int n = 0; n < 32; n++) if (n != i0 && sc[n] > m1) { m1 = sc[n]; i1 = n; }
        idx[b * 2] = i0; idx[b * 2 + 1] = i1;
    }
}

__global__ void gather_kernel(const float* __restrict__ Hp, const int* __restrict__ idx,
                              float* __restrict__ HpsF, __bf16* __restrict__ Hps_h,
                              __bf16* __restrict__ Hps_l) {
    long i = (long)blockIdx.x * 256 + threadIdx.x;
    if (i >= (long)32 * 128 * 768) return;
    int l = (int)(i % 768);
    long r = i / 768;
    int x = (int)(r % 128); int b = (int)(r / 128);
    int k = x >> 6, p = x & 63;
    int n = idx[b * 2 + k];
    float v = Hp[((long)b * 2048 + n * 64 + p) * 768 + l];
    HpsF[i] = v;
    __bf16 h = (__bf16)v; Hps_h[i] = h; Hps_l[i] = (__bf16)(v - (float)h);
}

// ---------------- bf16 MFMA GEMM (plain): C = A @ Wt^T [+bias] ----------------
template <int BIASF, int BOUT>
__global__ __launch_bounds__(256) void mgemm_kernel(
    const __bf16* __restrict__ A, int Kdim, int Mtot,
    const __bf16* __restrict__ Wt, const float* __restrict__ bias,
    float* __restrict__ C, int ldc, __bf16* __restrict__ Cb) {
    constexpr int LDT = 80;
    __shared__ alignas(16) __bf16 As[64 * LDT];
    __shared__ alignas(16) __bf16 Bs[64 * LDT];
    int t = threadIdx.x;
    int rowBase = blockIdx.x << 6, colBase = blockIdx.y << 6;
    int srow = t >> 2, skof = (t & 3) << 3;
    int arow = rowBase + srow;
    bool aok = arow < Mtot;
    const __bf16* Ap = A + (long)(aok ? arow : rowBase) * Kdim + skof;
    const __bf16* Wp = Wt + (long)(colBase + srow) * Kdim + skof;
    int w = t >> 6, l = t & 63;
    int wr = (w >> 1) << 5, wc = (w & 1) << 5;
    int fr = l & 15, g = l >> 4;
    f32x4 acc[2][2] = {};
    int nk = Kdim >> 6;
    for (int ks = 0; ks < nk; ks++) {
        bf16x8 a0 = *(const bf16x8*)(Ap);
        bf16x8 a1 = *(const bf16x8*)(Ap + 32);
        bf16x8 w0 = *(const bf16x8*)(Wp);
        bf16x8 w1 = *(const bf16x8*)(Wp + 32);
        Ap += 64; Wp += 64;
        __syncthreads();
        *(bf16x8*)(&As[srow * LDT + skof]) = a0;
        *(bf16x8*)(&As[srow * LDT + 32 + skof]) = a1;
        *(bf16x8*)(&Bs[srow * LDT + skof]) = w0;
        *(bf16x8*)(&Bs[srow * LDT + 32 + skof]) = w1;
        __syncthreads();
#pragma unroll
        for (int sub = 0; sub < 2; sub++) {
            int ko = sub * 32 + g * 8;
            bf16x8 fa0 = *(const bf16x8*)(&As[(wr + fr) * LDT + ko]);
            bf16x8 fa1 = *(const bf16x8*)(&As[(wr + 16 + fr) * LDT + ko]);
            bf16x8 fb0 = *(const bf16x8*)(&Bs[(wc + fr) * LDT + ko]);
            bf16x8 fb1 = *(const bf16x8*)(&Bs[(wc + 16 + fr) * LDT + ko]);
            acc[0][0] = __builtin_amdgcn_mfma_f32_16x16x32_bf16(fa0, fb0, acc[0][0], 0, 0, 0);
            acc[0][1] = __builtin_amdgcn_mfma_f32_16x16x32_bf16(fa0, fb1, acc[0][1], 0, 0, 0);
            acc[1][0] = __builtin_amdgcn_mfma_f32_16x16x32_bf16(fa1, fb0, acc[1][0], 0, 0, 0);
            acc[1][1] = __builtin_amdgcn_mfma_f32_16x16x32_bf16(fa1, fb1, acc[1][1], 0, 0, 0);
        }
    }
#pragma unroll
    for (int fi = 0; fi < 2; fi++)
#pragma unroll
    for (int fj = 0; fj < 2; fj++)
#pragma unroll
    for (int r = 0; r < 4; r++) {
        int row = rowBase + wr + fi * 16 + g * 4 + r;
        int col = colBase + wc + fj * 16 + (l & 15);
        if (row < Mtot) {
            float v = acc[fi][fj][r];
            if (BIASF) v += bias[col];
            if (BOUT == 0) C[(long)row * ldc + col] = v;
            else Cb[(long)row * ldc + col] = (__bf16)v;
        }
    }
}

// ---------------- bf16x3 split-precision MFMA GEMM ----------------
template <int WH>
__global__ __launch_bounds__(256) void mgemm3_kernel(
    const __bf16* __restrict__ Ah, const __bf16* __restrict__ Al, int Kdim, int Mtot,
    const __bf16* __restrict__ Wh, const __bf16* __restrict__ Wl,
    float* __restrict__ C, int ldc, __bf16* __restrict__ Cb) {
    constexpr int LDT = 80;
    __shared__ alignas(16) __bf16 Ahs[64 * LDT];
    __shared__ alignas(16) __bf16 Als[64 * LDT];
    __shared__ alignas(16) __bf16 Bhs[64 * LDT];
    __shared__ alignas(16) __bf16 Bls[64 * LDT];
    int t = threadIdx.x;
    int rowBase = blockIdx.x << 6, colBase = blockIdx.y << 6;
    int srow = t >> 2, skof = (t & 3) << 3;
    int arow = rowBase + srow;
    bool aok = arow < Mtot;
    long aoff = (long)(aok ? arow : rowBase) * Kdim + skof;
    long woff = (long)(colBase + srow) * Kdim + skof;
    const __bf16* Aph = Ah + aoff;
    const __bf16* Apl = Al + aoff;
    const __bf16* Wph = Wh + woff;
    const __bf16* Wpl = Wl + woff;
    int w = t >> 6, l = t & 63;
    int wr = (w >> 1) << 5, wc = (w & 1) << 5;
    int fr = l & 15, g = l >> 4;
    f32x4 acc[2][2] = {};
    int nk = Kdim >> 6;
    for (int ks = 0; ks < nk; ks++) {
        bf16x8 ah0 = *(const bf16x8*)(Aph);      bf16x8 ah1 = *(const bf16x8*)(Aph + 32);
        bf16x8 al0 = *(const bf16x8*)(Apl);      bf16x8 al1 = *(const bf16x8*)(Apl + 32);
        bf16x8 wh0 = *(const bf16x8*)(Wph);      bf16x8 wh1 = *(const bf16x8*)(Wph + 32);
        bf16x8 wl0 = *(const bf16x8*)(Wpl);      bf16x8 wl1 = *(const bf16x8*)(Wpl + 32);
        Aph += 64; Apl += 64; Wph += 64; Wpl += 64;
        __syncthreads();
        *(bf16x8*)(&Ahs[srow * LDT + skof]) = ah0; *(bf16x8*)(&Ahs[srow * LDT + 32 + skof]) = ah1;
        *(bf16x8*)(&Als[srow * LDT + skof]) = al0; *(bf16x8*)(&Als[srow * LDT + 32 + skof]) = al1;
        *(bf16x8*)(&Bhs[srow * LDT + skof]) = wh0; *(bf16x8*)(&Bhs[srow * LDT + 32 + skof]) = wh1;
        *(bf16x8*)(&Bls[srow * LDT + skof]) = wl0; *(bf16x8*)(&Bls[srow * LDT + 32 + skof]) = wl1;
        __syncthreads();
#pragma unroll
        for (int sub = 0; sub < 2; sub++) {
            int ko = sub * 32 + g * 8;
            bf16x8 fah[2], fal[2], fbh[2], fbl[2];
            fah[0] = *(const bf16x8*)(&Ahs[(wr + fr) * LDT + ko]);
            fah[1] = *(const bf16x8*)(&Ahs[(wr + 16 + fr) * LDT + ko]);
            fal[0] = *(const bf16x8*)(&Als[(wr + fr) * LDT + ko]);
            fal[1] = *(const bf16x8*)(&Als[(wr + 16 + fr) * LDT + ko]);
            fbh[0] = *(const bf16x8*)(&Bhs[(wc + fr) * LDT + ko]);
            fbh[1] = *(const bf16x8*)(&Bhs[(wc + 16 + fr) * LDT + ko]);
            fbl[0] = *(const bf16x8*)(&Bls[(wc + fr) * LDT + ko]);
            fbl[1] = *(const bf16x8*)(&Bls[(wc + 16 + fr) * LDT + ko]);
#pragma unroll
            for (int i = 0; i < 2; i++)
#pragma unroll
            for (int j = 0; j < 2; j++) {
                acc[i][j] = __builtin_amdgcn_mfma_f32_16x16x32_bf16(fah[i], fbh[j], acc[i][j], 0, 0, 0);
                acc[i][j] = __builtin_amdgcn_mfma_f32_16x16x32_bf16(fah[i], fbl[j], acc[i][j], 0, 0, 0);
                acc[i][j] = __builtin_amdgcn_mfma_f32_16x16x32_bf16(fal[i], fbh[j], acc[i][j], 0, 0, 0);
            }
        }
    }
#pragma unroll
    for (int fi = 0; fi < 2; fi++)
#pragma unroll
    for (int fj = 0; fj < 2; fj++)
#pragma unroll
    for (int r = 0; r < 4; r++) {
        int row = rowBase + wr + fi * 16 + g * 4 + r;
        int col = colBase + wc + fj * 16 + (l & 15);
        if (row < Mtot) {
            float v = acc[fi][fj][r];
            C[(long)row * ldc + col] = v;
            if (WH) Cb[(long)row * ldc + col] = (__bf16)v;
        }
    }
}

// ---------------- batched QK + softmax (fp32 scores) ----------------
struct QSegT {
    const float* GL; const float* HY; float* G;
    long glB, hyB, gB;
    int ldGL, ldHY, X, Y;
};
struct QArgs { QSegT s[13]; };

__global__ __launch_bounds__(256) void qkA_kernel(QArgs args) {
    int seg = blockIdx.x >> 5, b = blockIdx.x & 31;
    QSegT sg = args.s[seg];
    __shared__ float As[16][128];
    __shared__ float Bs[16][32];
    __shared__ float sc[128 * 33];
    int t = threadIdx.x;
    int arow = t >> 1, akof = (t & 1) * 8;
    int brow = t >> 3, bkof = (t & 7) * 2;
    bool aok = arow < sg.X, bok = brow < sg.Y;
    const float* ga = sg.GL + (long)b * sg.glB + (long)arow * sg.ldGL;
    const float* hb = sg.HY + (long)b * sg.hyB + (long)brow * sg.ldHY;
    int tx = t & 63, ty = t >> 6;
    float acc0[8] = {0.f}, acc1[8] = {0.f};
    for (int k0 = 0; k0 < 768; k0 += 16) {
        float4 a0 = make_float4(0, 0, 0, 0), a1 = make_float4(0, 0, 0, 0);
        float b0 = 0.f, b1v = 0.f;
        if (aok) { a0 = *(const float4*)(ga + k0 + akof); a1 = *(const float4*)(ga + k0 + akof + 4); }
        if (bok) { b0 = hb[k0 + bkof]; b1v = hb[k0 + bkof + 1]; }
        __syncthreads();
        As[akof + 0][arow] = a0.x; As[akof + 1][arow] = a0.y;
        As[akof + 2][arow] = a0.z; As[akof + 3][arow] = a0.w;
        As[akof + 4][arow] = a1.x; As[akof + 5][arow] = a1.y;
        As[akof + 6][arow] = a1.z; As[akof + 7][arow] = a1.w;
        Bs[bkof][brow] = b0; Bs[bkof + 1][brow] = b1v;
        __syncthreads();
#pragma unroll
        for (int kk = 0; kk < 16; kk++) {
            float alo = As[kk][tx], ahi = As[kk][tx + 64];
#pragma unroll
            for (int j = 0; j < 8; j++) {
                float bv = Bs[kk][ty * 8 + j];
                acc0[j] += alo * bv; acc1[j] += ahi * bv;
            }
        }
    }
#pragma unroll
    for (int j = 0; j < 8; j++) {
        sc[tx * 33 + ty * 8 + j] = acc0[j];
        sc[(tx + 64) * 33 + ty * 8 + j] = acc1[j];
    }
    __syncthreads();
    if (t < sg.X) {
        float* row = sc + t * 33;
        int Y = sg.Y;
        float m = row[0];
        for (int y = 1; y < Y; y++) m = fmaxf(m, row[y]);
        float s = 0.f;
        for (int y = 0; y < Y; y++) { float e = expf(row[y] - m); row[y] = e; s += e; }
        float inv = 1.f / s;
        float* go = sg.G + (long)b * sg.gB + (long)t * Y;
        for (int y = 0; y < Y; y++) go[y] = row[y] * inv;
    }
}

__global__ __launch_bounds__(256) void qkB_kernel(QArgs args) {
    int seg = blockIdx.x >> 5, b = blockIdx.x & 31;
    QSegT sg = args.s[seg];
    __shared__ float As[16][32];
    __shared__ float Bs[16][128];
    __shared__ float sc[32 * 129];
    int t = threadIdx.x;
    int arow = t >> 3, akof = (t & 7) * 2;
    int brow = t >> 1, bkof = (t & 1) * 8;
    bool aok = arow < sg.X;
    const float* ga = sg.GL + (long)b * sg.glB + (long)arow * sg.ldGL;
    const float* hb = sg.HY + (long)b * sg.hyB + (long)brow * sg.ldHY;
    int tx = t & 31, grp = t >> 5;
    float acc[16] = {0.f};
    for (int k0 = 0; k0 < 768; k0 += 16) {
        float a0 = 0.f, a1 = 0.f;
        if (aok) { a0 = ga[k0 + akof]; a1 = ga[k0 + akof + 1]; }
        float4 b0 = *(const float4*)(hb + k0 + bkof);
        float4 b1 = *(const float4*)(hb + k0 + bkof + 4);
        __syncthreads();
        As[akof][arow] = a0; As[akof + 1][arow] = a1;
        Bs[bkof + 0][brow] = b0.x; Bs[bkof + 1][brow] = b0.y;
        Bs[bkof + 2][brow] = b0.z; Bs[bkof + 3][brow] = b0.w;
        Bs[bkof + 4][brow] = b1.x; Bs[bkof + 5][brow] = b1.y;
        Bs[bkof + 6][brow] = b1.z; Bs[bkof + 7][brow] = b1.w;
        __syncthreads();
#pragma unroll
        for (int kk = 0; kk < 16; kk++) {
            float a = As[kk][tx];
#pragma unroll
            for (int j = 0; j < 16; j++) acc[j] += a * Bs[kk][grp * 16 + j];
        }
    }
#pragma unroll
    for (int j = 0; j < 16; j++) sc[tx * 129 + grp * 16 + j] = acc[j];
    __syncthreads();
    int row = t >> 3, lane = t & 7;
    if (row < sg.X) {
        float m = -1e30f;
        for (int k = 0; k < 16; k++) m = fmaxf(m, sc[row * 129 + lane + 8 * k]);
        for (int o = 1; o < 8; o <<= 1) m = fmaxf(m, __shfl_xor(m, o));
        float s = 0.f;
        for (int k = 0; k < 16; k++) {
            float e = expf(sc[row * 129 + lane + 8 * k] - m);
            sc[row * 129 + lane + 8 * k] = e; s += e;
        }
        for (int o = 1; o < 8; o <<= 1) s += __shfl_xor(s, o);
        float inv = 1.f / s;
        float* go = sg.G + (long)b * sg.gB + (long)row * 128;
        for (int k = 0; k < 16; k++) go[lane + 8 * k] = sc[row * 129 + lane + 8 * k] * inv;
    }
}

// ---------------- MFMA batched G@B ----------------
// hats: out rows = relu((Gh+Gl) @ (Bh+Bl)) -> h/l bf16, R=C=24
struct HSeg { const float* G; const __bf16* Bh; const __bf16* Bl;
              __bf16* outH; __bf16* outL; long gB, bB, oB; };
struct HArgs { HSeg s[12]; };

__global__ __launch_bounds__(256) void gbm_hats_kernel(HArgs args) {
    constexpr int R = 24, C = 24, Rk = 32, Ck = 32, Cpad = 40;
    __shared__ alignas(16) __bf16 SH[2 * Rk * Cpad + 2 * 64 * Cpad];
    __bf16* Gh = SH; __bf16* Gl = SH + Rk * Cpad;
    __bf16* Bth = SH + 2 * Rk * Cpad; __bf16* Btl = Bth + 64 * Cpad;
    int seg = blockIdx.x >> 5, b = blockIdx.x & 31;
    HSeg sg = args.s[seg];
    int t = threadIdx.x;
    int w = t >> 6, l = t & 63, fr = l & 15, g = l >> 4;
    const float* Gp = sg.G + (long)b * sg.gB;
    for (int idx = t; idx < Rk * Ck; idx += 256) {
        int r = idx >> 5, k = idx & 31;
        float v = (r < R && k < C) ? Gp[r * C + k] : 0.f;
        __bf16 h = (__bf16)v;
        Gh[r * Cpad + k] = h; Gl[r * Cpad + k] = (__bf16)(v - (float)h);
    }
    const __bf16* Bhb = sg.Bh + (long)b * sg.bB;
    const __bf16* Blb = sg.Bl + (long)b * sg.bB;
    int bl = t & 63, bc0 = t >> 6;
    for (int n0 = 0; n0 < 768; n0 += 64) {
        __syncthreads();
        for (int c = bc0; c < Ck; c += 4) {
            __bf16 hv = (__bf16)0.f, lv = (__bf16)0.f;
            if (c < C) { hv = Bhb[(long)c * 768 + n0 + bl]; lv = Blb[(long)c * 768 + n0 + bl]; }
            Bth[bl * Cpad + c] = hv; Btl[bl * Cpad + c] = lv;
        }
        __syncthreads();
        bf16x8 bh = *(const bf16x8*)(&Bth[(w * 16 + fr) * Cpad + g * 8]);
        bf16x8 blv = *(const bf16x8*)(&Btl[(w * 16 + fr) * Cpad + g * 8]);
        f32x4 acc[2] = {};
#pragma unroll
        for (int m = 0; m < 2; m++) {
            bf16x8 ah = *(const bf16x8*)(&Gh[(m * 16 + fr) * Cpad + g * 8]);
            bf16x8 al = *(const bf16x8*)(&Gl[(m * 16 + fr) * Cpad + g * 8]);
            acc[m] = __builtin_amdgcn_mfma_f32_16x16x32_bf16(ah, bh, acc[m], 0, 0, 0);
            acc[m] = __builtin_amdgcn_mfma_f32_16x16x32_bf16(al, bh, acc[m], 0, 0, 0);
            acc[m] = __builtin_amdgcn_mfma_f32_16x16x32_bf16(ah, blv, acc[m], 0, 0, 0);
        }
#pragma unroll
        for (int m = 0; m < 2; m++)
#pragma unroll
        for (int r = 0; r < 4; r++) {
            int row = m * 16 + g * 4 + r;
            if (row < R) {
                float v = fmaxf(acc[m][r], 0.f);
                __bf16 h = (__bf16)v;
                long o = (long)b * sg.oB + (long)row * 2304 + n0 + w * 16 + fr;
                sg.outH[o] = h; sg.outL[o] = (__bf16)(v - (float)h);
            }
        }
    }
}

// S-phase: out[col] = max_r ((Gh+Gl) @ B)[r,col] (relu via 0-init), B bf16
struct SSeg2 { const float* G; const __bf16* B; float* outF; __bf16* outH;
               long gB, bB, oB; int ldB, shape; };
struct SArgs2 { SSeg2 s[18]; };

template <int R, int C>
__device__ __forceinline__ void gbm_s_impl(__bf16* SH, const SSeg2& sg, int b, int t) {
    constexpr int Rk = (R + 15) & ~15;
    constexpr int Ck = (C + 31) & ~31;
    constexpr int Cpad = Ck + 8;
    constexpr int NM = Rk / 16;
    __bf16* Gh = SH; __bf16* Gl = SH + Rk * Cpad;
    __bf16* Bt = SH + 2 * Rk * Cpad;
    int w = t >> 6, l = t & 63, fr = l & 15, g = l >> 4;
    const float* Gp = sg.G + (long)b * sg.gB;
    for (int idx = t; idx < Rk * Ck; idx += 256) {
        int r = idx / Ck, k = idx - r * Ck;
        float v = (r < R && k < C) ? Gp[r * C + k] : 0.f;
        __bf16 h = (__bf16)v;
        Gh[r * Cpad + k] = h; Gl[r * Cpad + k] = (__bf16)(v - (float)h);
    }
    const __bf16* Bb = sg.B + (long)b * sg.bB;
    int bl = t & 63, bc0 = t >> 6;
    for (int n0 = 0; n0 < 768; n0 += 64) {
        __syncthreads();
        for (int c = bc0; c < Ck; c += 4) {
            __bf16 hv = (__bf16)0.f;
            if (c < C) hv = Bb[(long)c * sg.ldB + n0 + bl];
            Bt[bl * Cpad + c] = hv;
        }
        __syncthreads();
        f32x4 acc[NM] = {};
#pragma unroll
        for (int ks = 0; ks < Ck; ks += 32) {
            bf16x8 bh = *(const bf16x8*)(&Bt[(w * 16 + fr) * Cpad + ks + g * 8]);
#pragma unroll
            for (int m = 0; m < NM; m++) {
                bf16x8 ah = *(const bf16x8*)(&Gh[(m * 16 + fr) * Cpad + ks + g * 8]);
                bf16x8 al = *(const bf16x8*)(&Gl[(m * 16 + fr) * Cpad + ks + g * 8]);
                acc[m] = __builtin_amdgcn_mfma_f32_16x16x32_bf16(ah, bh, acc[m], 0, 0, 0);
                acc[m] = __builtin_amdgcn_mfma_f32_16x16x32_bf16(al, bh, acc[m], 0, 0, 0);
            }
        }
        float mx = 0.f;
#pragma unroll
        for (int m = 0; m < NM; m++)
#pragma unroll
            for (int r = 0; r < 4; r++) mx = fmaxf(mx, acc[m][r]);
        mx = fmaxf(mx, __shfl_xor(mx, 16));
        mx = fmaxf(mx, __shfl_xor(mx, 32));
        if (g == 0) {
            int col = n0 + w * 16 + fr;
            sg.outF[(long)b * sg.oB + col] = mx;
            sg.outH[(long)b * sg.oB + col] = (__bf16)mx;
        }
    }
}

__global__ __launch_bounds__(256) void gbm_s_kernel(SArgs2 args) {
    __shared__ alignas(16) __bf16 SH[17408];
    int seg = blockIdx.x >> 5, b = blockIdx.x & 31;
    SSeg2 sg = args.s[seg];
    int t = threadIdx.x;
    switch (sg.shape) {
        case 0: gbm_s_impl<128, 32>(SH, sg, b, t); break;
        case 1: gbm_s_impl<128, 24>(SH, sg, b, t); break;
        case 2: gbm_s_impl<32, 24>(SH, sg, b, t); break;
        case 3: gbm_s_impl<32, 128>(SH, sg, b, t); break;
        case 4: gbm_s_impl<24, 128>(SH, sg, b, t); break;
        default: gbm_s_impl<24, 32>(SH, sg, b, t); break;
    }
}

// ---------------- elementwise ----------------
__global__ void hogate_kernel(const float* __restrict__ gt, const float* __restrict__ bar,
                              const float* __restrict__ Ha, float* __restrict__ Ho,
                              __bf16* __restrict__ Ho_h, __bf16* __restrict__ Ho_l) {
    long idx = (long)blockIdx.x * 256 + threadIdx.x;
    if (idx >= (long)32 * 96 * 768) return;
    float g = 1.f / (1.f + expf(-gt[idx]));
    float v = g * Ha[idx] + (1.f - g) * bar[idx];
    Ho[idx] = v;
    __bf16 h = (__bf16)v; Ho_h[idx] = h; Ho_l[idx] = (__bf16)(v - (float)h);
}

__global__ void logits_kernel(const float* __restrict__ S, const float* __restrict__ gts,
                              const float* __restrict__ V, float* __restrict__ lg) {
    int blk = blockIdx.x; int b = blk >> 2, i = blk & 3;
    int t = threadIdx.x;
    int ms[3] = {0, 1 + i, 5 + i};
    float p = 0.f;
    for (int k = 0; k < 3; k++) {
        int m = ms[k];
        const float* Sr = S + (long)m * 49152 + (long)b * 1536;
        const float* gr = gts + ((long)m * 32 + b) * 768;
        const float* Vr = V + k * 768;
        for (int l = t; l < 768; l += 256) {
            float g = 1.f / (1.f + expf(-gr[l]));
            p += (g * Sr[l] + (1.f - g) * Sr[768 + l]) * Vr[l];
        }
    }
    for (int o = 32; o; o >>= 1) p += __shfl_xor(p, o);
    __shared__ float red[4];
    if ((t & 63) == 0) red[t >> 6] = p;
    __syncthreads();
    if (t == 0) lg[blk] = red[0] + red[1] + red[2] + red[3];
}

__global__ void lsm_kernel(const float* __restrict__ lg, float* __restrict__ out) {
    int b = threadIdx.x;
    if (b >= 32) return;
    float x0 = lg[b * 4 + 0], x1 = lg[b * 4 + 1], x2 = lg[b * 4 + 2], x3 = lg[b * 4 + 3];
    float m = fmaxf(fmaxf(x0, x1), fmaxf(x2, x3));
    float s = expf(x0 - m) + expf(x1 - m) + expf(x2 - m) + expf(x3 - m);
    float ls = m + logf(s);
    out[b * 4 + 0] = x0 - ls; out[b * 4 + 1] = x1 - ls;
    out[b * 4 + 2] = x2 - ls; out[b * 4 + 3] = x3 - ls;
}

// ---------------- host ----------------
extern "C" void kernel_launch(void* const* d_in, const int* in_sizes, int n_in,
                              void* d_out, int out_size, void* d_ws, size_t ws_size,
                              hipStream_t stream) {
    const float* Hp  = (const float*)d_in[0];
    const float* Hq  = (const float*)d_in[1];
    const float* Ha  = (const float*)d_in[2];
    const float* W5  = (const float*)d_in[3];
    const float* W6  = (const float*)d_in[4];
    const float* W7  = (const float*)d_in[5];
    const float* W8  = (const float*)d_in[6];
    const float* b8  = (const float*)d_in[7];
    const float* W9  = (const float*)d_in[8];
    const float* W10 = (const float*)d_in[9];
    const float* W11 = (const float*)d_in[10];
    const float* W12 = (const float*)d_in[11];
    const float* W13 = (const float*)d_in[12];
    const float* W14 = (const float*)d_in[13];
    const float* b14 = (const float*)d_in[14];
    const float* V   = (const float*)d_in[15];
    float* out = (float*)d_out;
    (void)in_sizes; (void)n_in; (void)out_size; (void)ws_size;

    char* base = (char*)d_ws;
    size_t off = 0;
    auto take = [&](size_t bytes) { char* p = base + off; off += (bytes + 15) & ~15UL; return p; };

    // bf16 weights
    __bf16* W5t_h  = (__bf16*)take(1179648);
    __bf16* W5t_l  = (__bf16*)take(1179648);
    __bf16* WsQT_h = (__bf16*)take(2359296);
    __bf16* WsQT_l = (__bf16*)take(2359296);
    __bf16* W6t_h  = (__bf16*)take(3538944);
    __bf16* W6t_l  = (__bf16*)take(3538944);
    __bf16* W1112T = (__bf16*)take(2359296);
    __bf16* W78t   = (__bf16*)take(1179648);
    __bf16* W1314t = (__bf16*)take(2359296);
    // fp32
    float* ra     = (float*)take(12288);
    float* rq     = (float*)take(4096);
    float* amax   = (float*)take(524288);
    int*   topidx = (int*)take(256);
    float* HpsF   = (float*)take(12582912);
    float* C1     = (float*)take(9437184);   // Ha@W5; reused later as gt
    float* HqSens = (float*)take(6291456);   // [c2|c3] ld 1536
    float* cache1 = (float*)take(12582912);  // Hps@W9, ld 768
    float* bar    = (float*)take(9437184);
    float* Ho     = (float*)take(9437184);
    float* G2     = (float*)take(884736);
    float* lg     = (float*)take(512);
    // bf16 activations
    char* HaReg   = take(9437184);           // Ha_h/l; later bar_h + S_h
    __bf16* Ha_h  = (__bf16*)HaReg;
    __bf16* Ha_l  = (__bf16*)(HaReg + 4718592);
    __bf16* bar_h = (__bf16*)HaReg;                 // alias
    __bf16* S_h   = (__bf16*)(HaReg + 4718592);     // alias
    __bf16* Hq_h  = (__bf16*)take(1572864);
    __bf16* Hq_l  = (__bf16*)take(1572864);
    __bf16* Hps_h = (__bf16*)take(6291456);
    __bf16* Hps_l = (__bf16*)take(6291456);
    __bf16* Ho_h  = (__bf16*)take(4718592);
    __bf16* Ho_l  = (__bf16*)take(4718592);
    char* HatsReg = take(28311552);          // hats_h/l; later cache4,HoW11_bf,Gm,S,gts
    __bf16* hats_h = (__bf16*)HatsReg;
    __bf16* hats_l = (__bf16*)(HatsReg + 14155776);
    float*  cache4    = (float*)HatsReg;
    __bf16* HoW11_bf  = (__bf16*)(HatsReg + 9437184);
    float*  Gm        = (float*)(HatsReg + 14155776);
    float*  S         = (float*)(HatsReg + 19136512);
    float*  gts       = (float*)(HatsReg + 20905984);
    __bf16* HqS2_bf   = (__bf16*)take(3145728);   // [HqW11|HqW12] ld 1536
    __bf16* HpsW12_bf = (__bf16*)take(6291456);   // ld 768
    float* gt = C1;

    dim3 blk(256);

    // prep + converts
    prep_kernel<<<25344, blk, 0, stream>>>(W5, W6, W7, W8, W9, W10, W11, W12, W13, W14,
                                           W5t_h, W5t_l, WsQT_h, WsQT_l, W6t_h, W6t_l,
                                           W1112T, W78t, W1314t);
    cvt2_kernel<<<9216, blk, 0, stream>>>(Ha, Ha_h, Ha_l, 2359296);
    cvt2_kernel<<<3072, blk, 0, stream>>>(Hq, Hq_h, Hq_l, 786432);

    // stage 1
    rnorm_kernel<<<3072, blk, 0, stream>>>(Ha, ra);
    rnorm_kernel<<<1024, blk, 0, stream>>>(Hq, rq);
    simmax_kernel<<<1024, blk, 0, stream>>>(Hp, Ha_h, Ha_l, Hq_h, Hq_l, ra, rq, amax);
    score_top2_kernel<<<32, dim3(64), 0, stream>>>(amax, topidx);
    gather_kernel<<<12288, blk, 0, stream>>>(Hp, topidx, HpsF, Hps_h, Hps_l);

    // score-feeding caches (bf16x3)
    mgemm3_kernel<0><<<dim3(48, 12), blk, 0, stream>>>(Ha_h, Ha_l, 768, 3072, W5t_h, W5t_l, C1, 768, nullptr);
    mgemm3_kernel<0><<<dim3(16, 24), blk, 0, stream>>>(Hq_h, Hq_l, 768, 1024, WsQT_h, WsQT_l, HqSens, 1536, nullptr);
    mgemm3_kernel<0><<<dim3(64, 12), blk, 0, stream>>>(Hps_h, Hps_l, 768, 4096, WsQT_h, WsQT_l, cache1, 768, nullptr);
    // S-path products (plain bf16, bf16 out)
    mgemm_kernel<0, 1><<<dim3(16, 24), blk, 0, stream>>>(Hq_h, 768, 1024, W1112T, nullptr, nullptr, 1536, HqS2_bf);
    mgemm_kernel<0, 1><<<dim3(64, 12), blk, 0, stream>>>(Hps_h, 768, 4096, W1112T + (long)768 * 768, nullptr, nullptr, 768, HpsW12_bf);

    // stage-2 QK (12 segs, 24x24)
    {
        QArgs qa{}; int si = 0;
        for (int i = 0; i < 4; i++)
            for (int j = 0; j < 4; j++) {
                if (j == i) continue;
                QSegT& s = qa.s[si];
                s.GL = C1 + (long)i * 24 * 768; s.glB = 73728; s.ldGL = 768;
                s.HY = Ha + (long)j * 24 * 768; s.hyB = 73728; s.ldHY = 768;
                s.G = G2 + (long)si * 18432; s.gB = 576;
                s.X = 24; s.Y = 24;
                si++;
            }
        qkA_kernel<<<12 * 32, blk, 0, stream>>>(qa);
    }
    // hats (12 segs, MFMA bf16x3 -> hi/lo bf16)
    {
        HArgs ha{}; int si = 0;
        for (int i = 0; i < 4; i++) {
            int jj = 0;
            for (int j = 0; j < 4; j++) {
                if (j == i) continue;
                HSeg& s = ha.s[si];
                s.G = G2 + (long)si * 18432; s.gB = 576;
                s.Bh = Ha_h + (long)j * 24 * 768; s.Bl = Ha_l + (long)j * 24 * 768; s.bB = 73728;
                s.outH = hats_h + (long)i * 24 * 2304 + jj * 768;
                s.outL = hats_l + (long)i * 24 * 2304 + jj * 768;
                s.oB = 221184;
                si++; jj++;
            }
        }
        gbm_hats_kernel<<<12 * 32, blk, 0, stream>>>(ha);
    }
    // bar = hats@W6 (bf16x3, f32 + hi out); gt = bar@W78 + b8; Ho
    mgemm3_kernel<1><<<dim3(48, 12), blk, 0, stream>>>(hats_h, hats_l, 2304, 3072, W6t_h, W6t_l, bar, 768, bar_h);
    mgemm_kernel<1, 0><<<dim3(48, 12), blk, 0, stream>>>(bar_h, 768, 3072, W78t, b8, gt, 768, nullptr);
    hogate_kernel<<<9216, blk, 0, stream>>>(gt, bar, Ha, Ho, Ho_h, Ho_l);
    // cache4 = Ho@W10 (bf16x3); HoW11 (plain)
    mgemm3_kernel<0><<<dim3(48, 12), blk, 0, stream>>>(Ho_h, Ho_l, 768, 3072, WsQT_h + (long)768 * 768, WsQT_l + (long)768 * 768, cache4, 768, nullptr);
    mgemm_kernel<0, 1><<<dim3(48, 12), blk, 0, stream>>>(Ho_h, 768, 3072, W1112T, nullptr, nullptr, 768, HoW11_bf);

    // match G offsets (floats, within Gm)
    const long gA0 = 0, gA1 = 131072, gA5 = 524288, gA9 = 622592, gB0 = 720896, gB1 = 851968;

    {
        QArgs qa{};
        qa.s[0].GL = cache1; qa.s[0].glB = 98304; qa.s[0].ldGL = 768;
        qa.s[0].HY = Hq;     qa.s[0].hyB = 24576; qa.s[0].ldHY = 768;
        qa.s[0].G = Gm + gA0; qa.s[0].gB = 4096; qa.s[0].X = 128; qa.s[0].Y = 32;
        for (int i = 0; i < 4; i++) {
            QSegT& a1 = qa.s[1 + i];
            a1.GL = cache1; a1.glB = 98304; a1.ldGL = 768;
            a1.HY = Ho + (long)i * 24 * 768; a1.hyB = 73728; a1.ldHY = 768;
            a1.G = Gm + gA1 + (long)i * 98304; a1.gB = 3072; a1.X = 128; a1.Y = 24;
            QSegT& a5 = qa.s[5 + i];
            a5.GL = HqSens; a5.glB = 49152; a5.ldGL = 1536;
            a5.HY = Ho + (long)i * 24 * 768; a5.hyB = 73728; a5.ldHY = 768;
            a5.G = Gm + gA5 + (long)i * 24576; a5.gB = 768; a5.X = 32; a5.Y = 24;
            QSegT& a9 = qa.s[9 + i];
            a9.GL = cache4 + (long)i * 24 * 768; a9.glB = 73728; a9.ldGL = 768;
            a9.HY = Hq; a9.hyB = 24576; a9.ldHY = 768;
            a9.G = Gm + gA9 + (long)i * 24576; a9.gB = 768; a9.X = 24; a9.Y = 32;
        }
        qkA_kernel<<<13 * 32, blk, 0, stream>>>(qa);
    }
    {
        QArgs qa{};
        qa.s[0].GL = HqSens + 768; qa.s[0].glB = 49152; qa.s[0].ldGL = 1536;
        qa.s[0].HY = HpsF; qa.s[0].hyB = 98304; qa.s[0].ldHY = 768;
        qa.s[0].G = Gm + gB0; qa.s[0].gB = 4096; qa.s[0].X = 32; qa.s[0].Y = 128;
        for (int i = 0; i < 4; i++) {
            QSegT& s = qa.s[1 + i];
            s.GL = cache4 + (long)i * 24 * 768; s.glB = 73728; s.ldGL = 768;
            s.HY = HpsF; s.hyB = 98304; s.ldHY = 768;
            s.G = Gm + gB1 + (long)i * 98304; s.gB = 3072; s.X = 24; s.Y = 128;
        }
        qkB_kernel<<<5 * 32, blk, 0, stream>>>(qa);
    }
    // S (18 segs, MFMA colmax)
    {
        SArgs2 sa{};
        auto set = [&](int k, const float* G, long gB, const __bf16* Bp, long bB, int ldB,
                       float* oF, __bf16* oH, int shape) {
            SSeg2& s = sa.s[k];
            s.G = G; s.gB = gB; s.B = Bp; s.bB = bB; s.ldB = ldB;
            s.outF = oF; s.outH = oH; s.oB = 1536; s.shape = shape;
        };
        set(0, Gm + gA0, 4096, HqS2_bf, 49152, 1536, S, S_h, 0);                       // 128x32
        for (int i = 0; i < 4; i++) {
            set(1 + i, Gm + gA1 + (long)i * 98304, 3072, HoW11_bf + (long)i * 24 * 768, 73728, 768,
                S + (long)(1 + i) * 49152, S_h + (long)(1 + i) * 49152, 1);            // 128x24
            set(5 + i, Gm + gA5 + (long)i * 24576, 768, HoW11_bf + (long)i * 24 * 768, 73728, 768,
                S + (long)(5 + i) * 49152, S_h + (long)(5 + i) * 49152, 2);            // 32x24
        }
        set(9, Gm + gB0, 4096, HpsW12_bf, 98304, 768, S + 768, S_h + 768, 3);          // 32x128
        for (int i = 0; i < 4; i++) {
            set(10 + i, Gm + gB1 + (long)i * 98304, 3072, HpsW12_bf, 98304, 768,
                S + (long)(1 + i) * 49152 + 768, S_h + (long)(1 + i) * 49152 + 768, 4); // 24x128
            set(14 + i, Gm + gA9 + (long)i * 24576, 768, HqS2_bf + 768, 49152, 1536,
                S + (long)(5 + i) * 49152 + 768, S_h + (long)(5 + i) * 49152 + 768, 5); // 24x32
        }
        gbm_s_kernel<<<18 * 32, blk, 0, stream>>>(sa);
    }

    // gating: gts = [Sxy|Syx] @ [W13;W14] + b14 (plain bf16 MFMA)
    mgemm_kernel<1, 0><<<dim3(5, 12), blk, 0, stream>>>(S_h, 1536, 288, W1314t, b14, gts, 768, nullptr);

    logits_kernel<<<128, blk, 0, stream>>>(S, gts, V, lg);
    lsm_kernel<<<1, dim3(32), 0, stream>>>(lg, out);
}

// Round 7
// 536.774 us; speedup vs baseline: 10.0236x; 1.1598x over previous
//
#include <hip/hip_runtime.h>
#include <math.h>

// B=32, N=32, P=64, Q=32, A=24, M=4, L=768, K=2

typedef __bf16 bf16x8 __attribute__((ext_vector_type(8)));
typedef float f32x4 __attribute__((ext_vector_type(4)));

// ---------------- prep: transposed weights (hi/lo bf16 for score-feeding, plain else) ----
__global__ void prep_kernel(const float* __restrict__ W5, const float* __restrict__ W6,
                            const float* __restrict__ W7, const float* __restrict__ W8,
                            const float* __restrict__ W9, const float* __restrict__ W10,
                            const float* __restrict__ W11, const float* __restrict__ W12,
                            const float* __restrict__ W13, const float* __restrict__ W14,
                            __bf16* __restrict__ W5t_h, __bf16* __restrict__ W5t_l,
                            __bf16* __restrict__ WsQT_h, __bf16* __restrict__ WsQT_l,
                            __bf16* __restrict__ W6t_h, __bf16* __restrict__ W6t_l,
                            __bf16* __restrict__ W1112T, __bf16* __restrict__ W78t,
                            __bf16* __restrict__ W1314t) {
    long i = (long)blockIdx.x * 256 + threadIdx.x;
    if (i < 589824) {
        int c = (int)(i / 768), r = (int)(i % 768);
        float v = W5[r * 768 + c];
        __bf16 h = (__bf16)v; W5t_h[i] = h; W5t_l[i] = (__bf16)(v - (float)h);
        return;
    } i -= 589824;
    if (i < 1179648) {
        int c = (int)(i / 768), r = (int)(i % 768);
        float v = (c < 768) ? W9[r * 768 + c] : W10[r * 768 + c - 768];
        __bf16 h = (__bf16)v; WsQT_h[i] = h; WsQT_l[i] = (__bf16)(v - (float)h);
        return;
    } i -= 1179648;
    if (i < 1769472) {
        int c = (int)(i / 2304), r = (int)(i % 2304);
        float v = W6[r * 768 + c];
        __bf16 h = (__bf16)v; W6t_h[i] = h; W6t_l[i] = (__bf16)(v - (float)h);
        return;
    } i -= 1769472;
    if (i < 1179648) {
        int c = (int)(i / 768), r = (int)(i % 768);
        W1112T[i] = (__bf16)((c < 768) ? W11[r * 768 + c] : W12[r * 768 + c - 768]);
        return;
    } i -= 1179648;
    if (i < 589824) {
        int c = (int)(i / 768), r = (int)(i % 768);
        W78t[i] = (__bf16)(W7[r * 768 + c] + W8[r * 768 + c]);
        return;
    } i -= 589824;
    if (i < 1179648) {
        int c = (int)(i / 1536), r = (int)(i % 1536);
        W1314t[i] = (__bf16)((r < 768) ? W13[r * 768 + c] : W14[(r - 768) * 768 + c]);
    }
}

__global__ void cvt2_kernel(const float* __restrict__ src, __bf16* __restrict__ h,
                            __bf16* __restrict__ l, long n) {
    long i = (long)blockIdx.x * 256 + threadIdx.x;
    if (i < n) {
        float v = src[i];
        __bf16 hv = (__bf16)v; h[i] = hv; l[i] = (__bf16)(v - (float)hv);
    }
}

// ---------------- stage 1: scoring ----------------
__global__ void rnorm_kernel(const float* __restrict__ X, float* __restrict__ out) {
    long row = blockIdx.x;
    const float* xr = X + row * 768;
    int t = threadIdx.x;
    float ss = 0.f;
    for (int l = t; l < 768; l += 256) { float v = xr[l]; ss += v * v; }
    for (int o = 32; o; o >>= 1) ss += __shfl_xor(ss, o);
    __shared__ float red[4];
    if ((t & 63) == 0) red[t >> 6] = ss;
    __syncthreads();
    if (t == 0) {
        float tot = red[0] + red[1] + red[2] + red[3];
        out[row] = 1.f / fmaxf(sqrtf(tot), 1e-8f);
    }
}

// MFMA bf16x3 simmax with fused Hp row norms.
__global__ __launch_bounds__(256) void simmax_kernel(
    const float* __restrict__ Hp,
    const __bf16* __restrict__ Ha_h, const __bf16* __restrict__ Ha_l,
    const __bf16* __restrict__ Hq_h, const __bf16* __restrict__ Hq_l,
    const float* __restrict__ ra, const float* __restrict__ rq,
    float* __restrict__ amax) {
    constexpr int LDT = 72;
    __shared__ alignas(16) __bf16 Ah[64 * LDT];
    __shared__ alignas(16) __bf16 Al[64 * LDT];
    __shared__ alignas(16) __bf16 Bh[128 * LDT];
    __shared__ alignas(16) __bf16 Bl[128 * LDT];
    __shared__ float rp_lds[64];
    __shared__ float wred[4][128];
    int b = blockIdx.x >> 5, n = blockIdx.x & 31;
    int t = threadIdx.x;
    const float* Ap = Hp + ((long)b * 2048 + n * 64) * 768;
    int srow = t >> 2, kq = (t & 3) << 4;
    int brow = t >> 1, kh = (t & 1) << 5;
    const __bf16 *Bsh, *Bsl;
    if (brow < 96) {
        Bsh = Ha_h + (long)b * 73728 + (long)brow * 768;
        Bsl = Ha_l + (long)b * 73728 + (long)brow * 768;
    } else {
        Bsh = Hq_h + (long)b * 24576 + (long)(brow - 96) * 768;
        Bsl = Hq_l + (long)b * 24576 + (long)(brow - 96) * 768;
    }
    int w = t >> 6, l = t & 63;
    int fr = l & 15, g = l >> 4;
    int wr = w << 4;
    f32x4 acc[8] = {};
    float ss = 0.f;
    const float* Arow = Ap + (long)srow * 768 + kq;
    for (int k0 = 0; k0 < 768; k0 += 64) {
        float4 av0 = *(const float4*)(Arow + k0 + 0);
        float4 av1 = *(const float4*)(Arow + k0 + 4);
        float4 av2 = *(const float4*)(Arow + k0 + 8);
        float4 av3 = *(const float4*)(Arow + k0 + 12);
        bf16x8 vbh0 = *(const bf16x8*)(Bsh + k0 + kh);
        bf16x8 vbh1 = *(const bf16x8*)(Bsh + k0 + kh + 8);
        bf16x8 vbh2 = *(const bf16x8*)(Bsh + k0 + kh + 16);
        bf16x8 vbh3 = *(const bf16x8*)(Bsh + k0 + kh + 24);
        bf16x8 vbl0 = *(const bf16x8*)(Bsl + k0 + kh);
        bf16x8 vbl1 = *(const bf16x8*)(Bsl + k0 + kh + 8);
        bf16x8 vbl2 = *(const bf16x8*)(Bsl + k0 + kh + 16);
        bf16x8 vbl3 = *(const bf16x8*)(Bsl + k0 + kh + 24);
        float va[16];
        *(float4*)(va + 0) = av0; *(float4*)(va + 4) = av1;
        *(float4*)(va + 8) = av2; *(float4*)(va + 12) = av3;
        bf16x8 h0, h1, l0, l1;
#pragma unroll
        for (int i = 0; i < 8; i++) {
            float v = va[i]; __bf16 hv = (__bf16)v;
            h0[i] = hv; l0[i] = (__bf16)(v - (float)hv); ss += v * v;
            v = va[8 + i]; hv = (__bf16)v;
            h1[i] = hv; l1[i] = (__bf16)(v - (float)hv); ss += v * v;
        }
        __syncthreads();
        *(bf16x8*)(&Ah[srow * LDT + kq]) = h0;
        *(bf16x8*)(&Ah[srow * LDT + kq + 8]) = h1;
        *(bf16x8*)(&Al[srow * LDT + kq]) = l0;
        *(bf16x8*)(&Al[srow * LDT + kq + 8]) = l1;
        *(bf16x8*)(&Bh[brow * LDT + kh]) = vbh0;
        *(bf16x8*)(&Bh[brow * LDT + kh + 8]) = vbh1;
        *(bf16x8*)(&Bh[brow * LDT + kh + 16]) = vbh2;
        *(bf16x8*)(&Bh[brow * LDT + kh + 24]) = vbh3;
        *(bf16x8*)(&Bl[brow * LDT + kh]) = vbl0;
        *(bf16x8*)(&Bl[brow * LDT + kh + 8]) = vbl1;
        *(bf16x8*)(&Bl[brow * LDT + kh + 16]) = vbl2;
        *(bf16x8*)(&Bl[brow * LDT + kh + 24]) = vbl3;
        __syncthreads();
#pragma unroll
        for (int sub = 0; sub < 2; sub++) {
            int kb = sub * 32 + g * 8;
            bf16x8 fah = *(const bf16x8*)(&Ah[(wr + fr) * LDT + kb]);
            bf16x8 fal = *(const bf16x8*)(&Al[(wr + fr) * LDT + kb]);
#pragma unroll
            for (int c = 0; c < 8; c++) {
                bf16x8 fbh = *(const bf16x8*)(&Bh[(c * 16 + fr) * LDT + kb]);
                bf16x8 fbl = *(const bf16x8*)(&Bl[(c * 16 + fr) * LDT + kb]);
                acc[c] = __builtin_amdgcn_mfma_f32_16x16x32_bf16(fah, fbh, acc[c], 0, 0, 0);
                acc[c] = __builtin_amdgcn_mfma_f32_16x16x32_bf16(fah, fbl, acc[c], 0, 0, 0);
                acc[c] = __builtin_amdgcn_mfma_f32_16x16x32_bf16(fal, fbh, acc[c], 0, 0, 0);
            }
        }
    }
    ss += __shfl_xor(ss, 1);
    ss += __shfl_xor(ss, 2);
    if ((t & 3) == 0) rp_lds[srow] = 1.f / fmaxf(sqrtf(ss), 1e-8f);
    __syncthreads();
    float rpv[4];
#pragma unroll
    for (int r = 0; r < 4; r++) rpv[r] = rp_lds[wr + g * 4 + r];
#pragma unroll
    for (int c = 0; c < 8; c++) {
        float mx = acc[c][0] * rpv[0];
        mx = fmaxf(mx, acc[c][1] * rpv[1]);
        mx = fmaxf(mx, acc[c][2] * rpv[2]);
        mx = fmaxf(mx, acc[c][3] * rpv[3]);
        mx = fmaxf(mx, __shfl_xor(mx, 16));
        mx = fmaxf(mx, __shfl_xor(mx, 32));
        if (g == 0) wred[w][c * 16 + fr] = mx;
    }
    __syncthreads();
    if (t < 128) {
        float m = fmaxf(fmaxf(wred[0][t], wred[1][t]), fmaxf(wred[2][t], wred[3][t]));
        float rc = (t < 96) ? ra[b * 96 + t] : rq[b * 32 + (t - 96)];
        amax[((long)b * 32 + n) * 128 + t] = m * rc;
    }
}

__global__ void score_top2_kernel(const float* __restrict__ amax, int* __restrict__ idx) {
    int b = blockIdx.x, t = threadIdx.x;
    __shared__ float sc[32];
    if (t < 32) {
        const float* am = amax + ((long)b * 32 + t) * 128;
        float sa = 0.f, sq = 0.f;
        for (int c = 0; c < 96; c++) sa += am[c];
        for (int c = 96; c < 128; c++) sq += am[c];
        sc[t] = sa / 24.f + sq / 32.f;
    }
    __syncthreads();
    if (t == 0) {
        float m0 = -1e30f; int i0 = 0;
        for (int n = 0; n < 32; n++) if (sc[n] > m0) { m0 = sc[n]; i0 = n; }
        float m1 = -1e30f; int i1 = 0;
        for (int n = 0; n < 32; n++) if (n != i0 && sc[n] > m1) { m1 = sc[n]; i1 = n; }
        idx[b * 2] = i0; idx[b * 2 + 1] = i1;
    }
}

__global__ void gather_kernel(const float* __restrict__ Hp, const int* __restrict__ idx,
                              __bf16* __restrict__ Hps_h, __bf16* __restrict__ Hps_l) {
    long i = (long)blockIdx.x * 256 + threadIdx.x;
    if (i >= (long)32 * 128 * 768) return;
    int l = (int)(i % 768);
    long r = i / 768;
    int x = (int)(r % 128); int b = (int)(r / 128);
    int k = x >> 6, p = x & 63;
    int n = idx[b * 2 + k];
    float v = Hp[((long)b * 2048 + n * 64 + p) * 768 + l];
    __bf16 h = (__bf16)v; Hps_h[i] = h; Hps_l[i] = (__bf16)(v - (float)h);
}

// ---------------- bf16 MFMA GEMM (plain): C = A @ Wt^T [+bias] ----------------
template <int BIASF, int BOUT>
__global__ __launch_bounds__(256) void mgemm_kernel(
    const __bf16* __restrict__ A, int Kdim, int Mtot,
    const __bf16* __restrict__ Wt, const float* __restrict__ bias,
    float* __restrict__ C, int ldc, __bf16* __restrict__ Cb) {
    constexpr int LDT = 80;
    __shared__ alignas(16) __bf16 As[64 * LDT];
    __shared__ alignas(16) __bf16 Bs[64 * LDT];
    int t = threadIdx.x;
    int rowBase = blockIdx.x << 6, colBase = blockIdx.y << 6;
    int srow = t >> 2, skof = (t & 3) << 3;
    int arow = rowBase + srow;
    bool aok = arow < Mtot;
    const __bf16* Ap = A + (long)(aok ? arow : rowBase) * Kdim + skof;
    const __bf16* Wp = Wt + (long)(colBase + srow) * Kdim + skof;
    int w = t >> 6, l = t & 63;
    int wr = (w >> 1) << 5, wc = (w & 1) << 5;
    int fr = l & 15, g = l >> 4;
    f32x4 acc[2][2] = {};
    int nk = Kdim >> 6;
    for (int ks = 0; ks < nk; ks++) {
        bf16x8 a0 = *(const bf16x8*)(Ap);
        bf16x8 a1 = *(const bf16x8*)(Ap + 32);
        bf16x8 w0 = *(const bf16x8*)(Wp);
        bf16x8 w1 = *(const bf16x8*)(Wp + 32);
        Ap += 64; Wp += 64;
        __syncthreads();
        *(bf16x8*)(&As[srow * LDT + skof]) = a0;
        *(bf16x8*)(&As[srow * LDT + 32 + skof]) = a1;
        *(bf16x8*)(&Bs[srow * LDT + skof]) = w0;
        *(bf16x8*)(&Bs[srow * LDT + 32 + skof]) = w1;
        __syncthreads();
#pragma unroll
        for (int sub = 0; sub < 2; sub++) {
            int ko = sub * 32 + g * 8;
            bf16x8 fa0 = *(const bf16x8*)(&As[(wr + fr) * LDT + ko]);
            bf16x8 fa1 = *(const bf16x8*)(&As[(wr + 16 + fr) * LDT + ko]);
            bf16x8 fb0 = *(const bf16x8*)(&Bs[(wc + fr) * LDT + ko]);
            bf16x8 fb1 = *(const bf16x8*)(&Bs[(wc + 16 + fr) * LDT + ko]);
            acc[0][0] = __builtin_amdgcn_mfma_f32_16x16x32_bf16(fa0, fb0, acc[0][0], 0, 0, 0);
            acc[0][1] = __builtin_amdgcn_mfma_f32_16x16x32_bf16(fa0, fb1, acc[0][1], 0, 0, 0);
            acc[1][0] = __builtin_amdgcn_mfma_f32_16x16x32_bf16(fa1, fb0, acc[1][0], 0, 0, 0);
            acc[1][1] = __builtin_amdgcn_mfma_f32_16x16x32_bf16(fa1, fb1, acc[1][1], 0, 0, 0);
        }
    }
#pragma unroll
    for (int fi = 0; fi < 2; fi++)
#pragma unroll
    for (int fj = 0; fj < 2; fj++)
#pragma unroll
    for (int r = 0; r < 4; r++) {
        int row = rowBase + wr + fi * 16 + g * 4 + r;
        int col = colBase + wc + fj * 16 + (l & 15);
        if (row < Mtot) {
            float v = acc[fi][fj][r];
            if (BIASF) v += bias[col];
            if (BOUT == 0) C[(long)row * ldc + col] = v;
            else Cb[(long)row * ldc + col] = (__bf16)v;
        }
    }
}

// ---------------- bf16x3 split-precision MFMA GEMM ----------------
// OUT 0: fp32; 1: fp32 + bf16-hi; 2: bf16 h/l only
template <int OUT>
__global__ __launch_bounds__(256) void mgemm3_kernel(
    const __bf16* __restrict__ Ah, const __bf16* __restrict__ Al, int Kdim, int Mtot,
    const __bf16* __restrict__ Wh, const __bf16* __restrict__ Wl,
    float* __restrict__ C, int ldc, __bf16* __restrict__ Ch, __bf16* __restrict__ Cl) {
    constexpr int LDT = 80;
    __shared__ alignas(16) __bf16 Ahs[64 * LDT];
    __shared__ alignas(16) __bf16 Als[64 * LDT];
    __shared__ alignas(16) __bf16 Bhs[64 * LDT];
    __shared__ alignas(16) __bf16 Bls[64 * LDT];
    int t = threadIdx.x;
    int rowBase = blockIdx.x << 6, colBase = blockIdx.y << 6;
    int srow = t >> 2, skof = (t & 3) << 3;
    int arow = rowBase + srow;
    bool aok = arow < Mtot;
    long aoff = (long)(aok ? arow : rowBase) * Kdim + skof;
    long woff = (long)(colBase + srow) * Kdim + skof;
    const __bf16* Aph = Ah + aoff;
    const __bf16* Apl = Al + aoff;
    const __bf16* Wph = Wh + woff;
    const __bf16* Wpl = Wl + woff;
    int w = t >> 6, l = t & 63;
    int wr = (w >> 1) << 5, wc = (w & 1) << 5;
    int fr = l & 15, g = l >> 4;
    f32x4 acc[2][2] = {};
    int nk = Kdim >> 6;
    for (int ks = 0; ks < nk; ks++) {
        bf16x8 ah0 = *(const bf16x8*)(Aph);      bf16x8 ah1 = *(const bf16x8*)(Aph + 32);
        bf16x8 al0 = *(const bf16x8*)(Apl);      bf16x8 al1 = *(const bf16x8*)(Apl + 32);
        bf16x8 wh0 = *(const bf16x8*)(Wph);      bf16x8 wh1 = *(const bf16x8*)(Wph + 32);
        bf16x8 wl0 = *(const bf16x8*)(Wpl);      bf16x8 wl1 = *(const bf16x8*)(Wpl + 32);
        Aph += 64; Apl += 64; Wph += 64; Wpl += 64;
        __syncthreads();
        *(bf16x8*)(&Ahs[srow * LDT + skof]) = ah0; *(bf16x8*)(&Ahs[srow * LDT + 32 + skof]) = ah1;
        *(bf16x8*)(&Als[srow * LDT + skof]) = al0; *(bf16x8*)(&Als[srow * LDT + 32 + skof]) = al1;
        *(bf16x8*)(&Bhs[srow * LDT + skof]) = wh0; *(bf16x8*)(&Bhs[srow * LDT + 32 + skof]) = wh1;
        *(bf16x8*)(&Bls[srow * LDT + skof]) = wl0; *(bf16x8*)(&Bls[srow * LDT + 32 + skof]) = wl1;
        __syncthreads();
#pragma unroll
        for (int sub = 0; sub < 2; sub++) {
            int ko = sub * 32 + g * 8;
            bf16x8 fah[2], fal[2], fbh[2], fbl[2];
            fah[0] = *(const bf16x8*)(&Ahs[(wr + fr) * LDT + ko]);
            fah[1] = *(const bf16x8*)(&Ahs[(wr + 16 + fr) * LDT + ko]);
            fal[0] = *(const bf16x8*)(&Als[(wr + fr) * LDT + ko]);
            fal[1] = *(const bf16x8*)(&Als[(wr + 16 + fr) * LDT + ko]);
            fbh[0] = *(const bf16x8*)(&Bhs[(wc + fr) * LDT + ko]);
            fbh[1] = *(const bf16x8*)(&Bhs[(wc + 16 + fr) * LDT + ko]);
            fbl[0] = *(const bf16x8*)(&Bls[(wc + fr) * LDT + ko]);
            fbl[1] = *(const bf16x8*)(&Bls[(wc + 16 + fr) * LDT + ko]);
#pragma unroll
            for (int i = 0; i < 2; i++)
#pragma unroll
            for (int j = 0; j < 2; j++) {
                acc[i][j] = __builtin_amdgcn_mfma_f32_16x16x32_bf16(fah[i], fbh[j], acc[i][j], 0, 0, 0);
                acc[i][j] = __builtin_amdgcn_mfma_f32_16x16x32_bf16(fah[i], fbl[j], acc[i][j], 0, 0, 0);
                acc[i][j] = __builtin_amdgcn_mfma_f32_16x16x32_bf16(fal[i], fbh[j], acc[i][j], 0, 0, 0);
            }
        }
    }
#pragma unroll
    for (int fi = 0; fi < 2; fi++)
#pragma unroll
    for (int fj = 0; fj < 2; fj++)
#pragma unroll
    for (int r = 0; r < 4; r++) {
        int row = rowBase + wr + fi * 16 + g * 4 + r;
        int col = colBase + wc + fj * 16 + (l & 15);
        if (row < Mtot) {
            float v = acc[fi][fj][r];
            long o = (long)row * ldc + col;
            if (OUT == 0) { C[o] = v; }
            else if (OUT == 1) { C[o] = v; Ch[o] = (__bf16)v; }
            else {
                __bf16 h = (__bf16)v;
                Ch[o] = h; Cl[o] = (__bf16)(v - (float)h);
            }
        }
    }
}

// ---------------- MFMA bf16x3 QK + fused softmax ----------------
struct QMSeg {
    const __bf16 *GLh, *GLl, *HYh, *HYl;
    float* G;
    int glB, hyB, gB, ldGL, ldHY, shape;
};
struct QMArgs { QMSeg s[18]; };

template <int X, int Y>
__device__ __forceinline__ void qkm_impl(__bf16* SH, float* sc, const QMSeg& sg, int b, int t) {
    constexpr int XR = (X + 15) & ~15;
    constexpr int YR = (Y + 15) & ~15;
    constexpr int LDT = 72;
    constexpr int YC = YR / 16;
    constexpr int F = (XR / 16) * YC;
    constexpr int F4 = F / 4;
    constexpr int YRp = YR + 1;
    __bf16* Ah_ = SH;
    __bf16* Al_ = SH + XR * LDT;
    __bf16* Bh_ = SH + 2 * XR * LDT;
    __bf16* Bl_ = SH + 2 * XR * LDT + YR * LDT;
    int w = t >> 6, l = t & 63, fr = l & 15, g = l >> 4;
    const __bf16* GLbh = sg.GLh + (long)b * sg.glB;
    const __bf16* GLbl = sg.GLl + (long)b * sg.glB;
    const __bf16* HYbh = sg.HYh + (long)b * sg.hyB;
    const __bf16* HYbl = sg.HYl + (long)b * sg.hyB;
    f32x4 acc[F4] = {};
    for (int k0 = 0; k0 < 768; k0 += 64) {
        __syncthreads();
        for (int v = t; v < (XR + YR) * 16; v += 256) {
            int row = v >> 4, sub = v & 15, hl = sub >> 3, k8 = (sub & 7) << 3;
            bf16x8 val = {};
            __bf16* dst;
            if (row < XR) {
                if (row < X)
                    val = *(const bf16x8*)((hl ? GLbl : GLbh) + (long)row * sg.ldGL + k0 + k8);
                dst = (hl ? Al_ : Ah_) + row * LDT + k8;
            } else {
                int r2 = row - XR;
                if (r2 < Y)
                    val = *(const bf16x8*)((hl ? HYbl : HYbh) + (long)r2 * sg.ldHY + k0 + k8);
                dst = (hl ? Bl_ : Bh_) + r2 * LDT + k8;
            }
            *(bf16x8*)dst = val;
        }
        __syncthreads();
#pragma unroll
        for (int sub = 0; sub < 2; sub++) {
            int kb = sub * 32 + g * 8;
#pragma unroll
            for (int ff = 0; ff < F4; ff++) {
                int fidx = w + ff * 4;
                int xm = fidx / YC, yc = fidx % YC;
                bf16x8 fah = *(const bf16x8*)(&Ah_[(xm * 16 + fr) * LDT + kb]);
                bf16x8 fal = *(const bf16x8*)(&Al_[(xm * 16 + fr) * LDT + kb]);
                bf16x8 fbh = *(const bf16x8*)(&Bh_[(yc * 16 + fr) * LDT + kb]);
                bf16x8 fbl = *(const bf16x8*)(&Bl_[(yc * 16 + fr) * LDT + kb]);
                acc[ff] = __builtin_amdgcn_mfma_f32_16x16x32_bf16(fah, fbh, acc[ff], 0, 0, 0);
                acc[ff] = __builtin_amdgcn_mfma_f32_16x16x32_bf16(fah, fbl, acc[ff], 0, 0, 0);
                acc[ff] = __builtin_amdgcn_mfma_f32_16x16x32_bf16(fal, fbh, acc[ff], 0, 0, 0);
            }
        }
    }
#pragma unroll
    for (int ff = 0; ff < F4; ff++) {
        int fidx = w + ff * 4;
        int xm = fidx / YC, yc = fidx % YC;
#pragma unroll
        for (int r = 0; r < 4; r++)
            sc[(xm * 16 + g * 4 + r) * YRp + yc * 16 + fr] = acc[ff][r];
    }
    __syncthreads();
    constexpr int TPR = 256 / XR;
    int row = t / TPR, sub = t & (TPR - 1);
    if (row < X) {
        float* sr = sc + row * YRp;
        float m = -1e30f;
        for (int c = sub; c < Y; c += TPR) m = fmaxf(m, sr[c]);
#pragma unroll
        for (int o = 1; o < TPR; o <<= 1) m = fmaxf(m, __shfl_xor(m, o));
        float s = 0.f;
        for (int c = sub; c < Y; c += TPR) { float e = expf(sr[c] - m); sr[c] = e; s += e; }
#pragma unroll
        for (int o = 1; o < TPR; o <<= 1) s += __shfl_xor(s, o);
        float inv = 1.f / s;
        float* go = sg.G + (long)b * sg.gB + (long)row * Y;
        for (int c = sub; c < Y; c += TPR) go[c] = sr[c] * inv;
    }
}

__global__ __launch_bounds__(256) void qkm_kernel(QMArgs args) {
    __shared__ alignas(16) __bf16 SH[23040];
    __shared__ alignas(16) float sc[4224];
    int seg = blockIdx.x >> 5, b = blockIdx.x & 31;
    QMSeg sg = args.s[seg];
    int t = threadIdx.x;
    switch (sg.shape) {
        case 0: qkm_impl<24, 24>(SH, sc, sg, b, t); break;
        case 1: qkm_impl<128, 32>(SH, sc, sg, b, t); break;
        case 2: qkm_impl<128, 24>(SH, sc, sg, b, t); break;
        case 3: qkm_impl<32, 24>(SH, sc, sg, b, t); break;
        case 4: qkm_impl<24, 32>(SH, sc, sg, b, t); break;
        case 5: qkm_impl<32, 128>(SH, sc, sg, b, t); break;
        default: qkm_impl<24, 128>(SH, sc, sg, b, t); break;
    }
}

// ---------------- MFMA batched G@B ----------------
struct HSeg { const float* G; const __bf16* Bh; const __bf16* Bl;
              __bf16* outH; __bf16* outL; long gB, bB, oB; };
struct HArgs { HSeg s[12]; };

__global__ __launch_bounds__(256) void gbm_hats_kernel(HArgs args) {
    constexpr int R = 24, C = 24, Rk = 32, Ck = 32, Cpad = 40;
    __shared__ alignas(16) __bf16 SH[2 * Rk * Cpad + 2 * 64 * Cpad];
    __bf16* Gh = SH; __bf16* Gl = SH + Rk * Cpad;
    __bf16* Bth = SH + 2 * Rk * Cpad; __bf16* Btl = Bth + 64 * Cpad;
    int seg = blockIdx.x >> 5, b = blockIdx.x & 31;
    HSeg sg = args.s[seg];
    int t = threadIdx.x;
    int w = t >> 6, l = t & 63, fr = l & 15, g = l >> 4;
    const float* Gp = sg.G + (long)b * sg.gB;
    for (int idx = t; idx < Rk * Ck; idx += 256) {
        int r = idx >> 5, k = idx & 31;
        float v = (r < R && k < C) ? Gp[r * C + k] : 0.f;
        __bf16 h = (__bf16)v;
        Gh[r * Cpad + k] = h; Gl[r * Cpad + k] = (__bf16)(v - (float)h);
    }
    const __bf16* Bhb = sg.Bh + (long)b * sg.bB;
    const __bf16* Blb = sg.Bl + (long)b * sg.bB;
    int bl = t & 63, bc0 = t >> 6;
    for (int n0 = 0; n0 < 768; n0 += 64) {
        __syncthreads();
        for (int c = bc0; c < Ck; c += 4) {
            __bf16 hv = (__bf16)0.f, lv = (__bf16)0.f;
            if (c < C) { hv = Bhb[(long)c * 768 + n0 + bl]; lv = Blb[(long)c * 768 + n0 + bl]; }
            Bth[bl * Cpad + c] = hv; Btl[bl * Cpad + c] = lv;
        }
        __syncthreads();
        bf16x8 bh = *(const bf16x8*)(&Bth[(w * 16 + fr) * Cpad + g * 8]);
        bf16x8 blv = *(const bf16x8*)(&Btl[(w * 16 + fr) * Cpad + g * 8]);
        f32x4 acc[2] = {};
#pragma unroll
        for (int m = 0; m < 2; m++) {
            bf16x8 ah = *(const bf16x8*)(&Gh[(m * 16 + fr) * Cpad + g * 8]);
            bf16x8 al = *(const bf16x8*)(&Gl[(m * 16 + fr) * Cpad + g * 8]);
            acc[m] = __builtin_amdgcn_mfma_f32_16x16x32_bf16(ah, bh, acc[m], 0, 0, 0);
            acc[m] = __builtin_amdgcn_mfma_f32_16x16x32_bf16(al, bh, acc[m], 0, 0, 0);
            acc[m] = __builtin_amdgcn_mfma_f32_16x16x32_bf16(ah, blv, acc[m], 0, 0, 0);
        }
#pragma unroll
        for (int m = 0; m < 2; m++)
#pragma unroll
        for (int r = 0; r < 4; r++) {
            int row = m * 16 + g * 4 + r;
            if (row < R) {
                float v = fmaxf(acc[m][r], 0.f);
                __bf16 h = (__bf16)v;
                long o = (long)b * sg.oB + (long)row * 2304 + n0 + w * 16 + fr;
                sg.outH[o] = h; sg.outL[o] = (__bf16)(v - (float)h);
            }
        }
    }
}

struct SSeg2 { const float* G; const __bf16* B; float* outF; __bf16* outH;
               long gB, bB, oB; int ldB, shape; };
struct SArgs2 { SSeg2 s[18]; };

template <int R, int C>
__device__ __forceinline__ void gbm_s_impl(__bf16* SH, const SSeg2& sg, int b, int t) {
    constexpr int Rk = (R + 15) & ~15;
    constexpr int Ck = (C + 31) & ~31;
    constexpr int Cpad = Ck + 8;
    constexpr int NM = Rk / 16;
    __bf16* Gh = SH; __bf16* Gl = SH + Rk * Cpad;
    __bf16* Bt = SH + 2 * Rk * Cpad;
    int w = t >> 6, l = t & 63, fr = l & 15, g = l >> 4;
    const float* Gp = sg.G + (long)b * sg.gB;
    for (int idx = t; idx < Rk * Ck; idx += 256) {
        int r = idx / Ck, k = idx - r * Ck;
        float v = (r < R && k < C) ? Gp[r * C + k] : 0.f;
        __bf16 h = (__bf16)v;
        Gh[r * Cpad + k] = h; Gl[r * Cpad + k] = (__bf16)(v - (float)h);
    }
    const __bf16* Bb = sg.B + (long)b * sg.bB;
    int bl = t & 63, bc0 = t >> 6;
    for (int n0 = 0; n0 < 768; n0 += 64) {
        __syncthreads();
        for (int c = bc0; c < Ck; c += 4) {
            __bf16 hv = (__bf16)0.f;
            if (c < C) hv = Bb[(long)c * sg.ldB + n0 + bl];
            Bt[bl * Cpad + c] = hv;
        }
        __syncthreads();
        f32x4 acc[NM] = {};
#pragma unroll
        for (int ks = 0; ks < Ck; ks += 32) {
            bf16x8 bh = *(const bf16x8*)(&Bt[(w * 16 + fr) * Cpad + ks + g * 8]);
#pragma unroll
            for (int m = 0; m < NM; m++) {
                bf16x8 ah = *(const bf16x8*)(&Gh[(m * 16 + fr) * Cpad + ks + g * 8]);
                bf16x8 al = *(const bf16x8*)(&Gl[(m * 16 + fr) * Cpad + ks + g * 8]);
                acc[m] = __builtin_amdgcn_mfma_f32_16x16x32_bf16(ah, bh, acc[m], 0, 0, 0);
                acc[m] = __builtin_amdgcn_mfma_f32_16x16x32_bf16(al, bh, acc[m], 0, 0, 0);
            }
        }
        float mx = 0.f;
#pragma unroll
        for (int m = 0; m < NM; m++)
#pragma unroll
            for (int r = 0; r < 4; r++) mx = fmaxf(mx, acc[m][r]);
        mx = fmaxf(mx, __shfl_xor(mx, 16));
        mx = fmaxf(mx, __shfl_xor(mx, 32));
        if (g == 0) {
            int col = n0 + w * 16 + fr;
            sg.outF[(long)b * sg.oB + col] = mx;
            sg.outH[(long)b * sg.oB + col] = (__bf16)mx;
        }
    }
}

__global__ __launch_bounds__(256) void gbm_s_kernel(SArgs2 args) {
    __shared__ alignas(16) __bf16 SH[17408];
    int seg = blockIdx.x >> 5, b = blockIdx.x & 31;
    SSeg2 sg = args.s[seg];
    int t = threadIdx.x;
    switch (sg.shape) {
        case 0: gbm_s_impl<128, 32>(SH, sg, b, t); break;
        case 1: gbm_s_impl<128, 24>(SH, sg, b, t); break;
        case 2: gbm_s_impl<32, 24>(SH, sg, b, t); break;
        case 3: gbm_s_impl<32, 128>(SH, sg, b, t); break;
        case 4: gbm_s_impl<24, 128>(SH, sg, b, t); break;
        default: gbm_s_impl<24, 32>(SH, sg, b, t); break;
    }
}

// ---------------- elementwise ----------------
__global__ void hogate_kernel(const float* __restrict__ gt, const float* __restrict__ bar,
                              const float* __restrict__ Ha,
                              __bf16* __restrict__ Ho_h, __bf16* __restrict__ Ho_l) {
    long idx = (long)blockIdx.x * 256 + threadIdx.x;
    if (idx >= (long)32 * 96 * 768) return;
    float g = 1.f / (1.f + expf(-gt[idx]));
    float v = g * Ha[idx] + (1.f - g) * bar[idx];
    __bf16 h = (__bf16)v; Ho_h[idx] = h; Ho_l[idx] = (__bf16)(v - (float)h);
}

__global__ void logits_kernel(const float* __restrict__ S, const float* __restrict__ gts,
                              const float* __restrict__ V, float* __restrict__ lg) {
    int blk = blockIdx.x; int b = blk >> 2, i = blk & 3;
    int t = threadIdx.x;
    int ms[3] = {0, 1 + i, 5 + i};
    float p = 0.f;
    for (int k = 0; k < 3; k++) {
        int m = ms[k];
        const float* Sr = S + (long)m * 49152 + (long)b * 1536;
        const float* gr = gts + ((long)m * 32 + b) * 768;
        const float* Vr = V + k * 768;
        for (int l = t; l < 768; l += 256) {
            float g = 1.f / (1.f + expf(-gr[l]));
            p += (g * Sr[l] + (1.f - g) * Sr[768 + l]) * Vr[l];
        }
    }
    for (int o = 32; o; o >>= 1) p += __shfl_xor(p, o);
    __shared__ float red[4];
    if ((t & 63) == 0) red[t >> 6] = p;
    __syncthreads();
    if (t == 0) lg[blk] = red[0] + red[1] + red[2] + red[3];
}

__global__ void lsm_kernel(const float* __restrict__ lg, float* __restrict__ out) {
    int b = threadIdx.x;
    if (b >= 32) return;
    float x0 = lg[b * 4 + 0], x1 = lg[b * 4 + 1], x2 = lg[b * 4 + 2], x3 = lg[b * 4 + 3];
    float m = fmaxf(fmaxf(x0, x1), fmaxf(x2, x3));
    float s = expf(x0 - m) + expf(x1 - m) + expf(x2 - m) + expf(x3 - m);
    float ls = m + logf(s);
    out[b * 4 + 0] = x0 - ls; out[b * 4 + 1] = x1 - ls;
    out[b * 4 + 2] = x2 - ls; out[b * 4 + 3] = x3 - ls;
}

// ---------------- host ----------------
extern "C" void kernel_launch(void* const* d_in, const int* in_sizes, int n_in,
                              void* d_out, int out_size, void* d_ws, size_t ws_size,
                              hipStream_t stream) {
    const float* Hp  = (const float*)d_in[0];
    const float* Hq  = (const float*)d_in[1];
    const float* Ha  = (const float*)d_in[2];
    const float* W5  = (const float*)d_in[3];
    const float* W6  = (const float*)d_in[4];
    const float* W7  = (const float*)d_in[5];
    const float* W8  = (const float*)d_in[6];
    const float* b8  = (const float*)d_in[7];
    const float* W9  = (const float*)d_in[8];
    const float* W10 = (const float*)d_in[9];
    const float* W11 = (const float*)d_in[10];
    const float* W12 = (const float*)d_in[11];
    const float* W13 = (const float*)d_in[12];
    const float* W14 = (const float*)d_in[13];
    const float* b14 = (const float*)d_in[14];
    const float* V   = (const float*)d_in[15];
    float* out = (float*)d_out;
    (void)in_sizes; (void)n_in; (void)out_size; (void)ws_size;

    char* base = (char*)d_ws;
    size_t off = 0;
    auto take = [&](size_t bytes) { char* p = base + off; off += (bytes + 15) & ~15UL; return p; };

    // bf16 weights
    __bf16* W5t_h  = (__bf16*)take(1179648);
    __bf16* W5t_l  = (__bf16*)take(1179648);
    __bf16* WsQT_h = (__bf16*)take(2359296);
    __bf16* WsQT_l = (__bf16*)take(2359296);
    __bf16* W6t_h  = (__bf16*)take(3538944);
    __bf16* W6t_l  = (__bf16*)take(3538944);
    __bf16* W1112T = (__bf16*)take(2359296);
    __bf16* W78t   = (__bf16*)take(1179648);
    __bf16* W1314t = (__bf16*)take(2359296);
    // small fp32
    float* ra     = (float*)take(12288);
    float* rq     = (float*)take(4096);
    float* amax   = (float*)take(524288);
    int*   topidx = (int*)take(256);
    float* lg     = (float*)take(512);
    // bf16 h/l activations
    __bf16* Ha_h  = (__bf16*)take(4718592);
    __bf16* Ha_l  = (__bf16*)take(4718592);
    __bf16* Hq_h  = (__bf16*)take(1572864);
    __bf16* Hq_l  = (__bf16*)take(1572864);
    __bf16* Hps_h = (__bf16*)take(6291456);
    __bf16* Hps_l = (__bf16*)take(6291456);
    __bf16* C1_h  = (__bf16*)take(4718592);
    __bf16* C1_l  = (__bf16*)take(4718592);
    __bf16* HqS_h = (__bf16*)take(3145728);   // [c2|c3] ld 1536
    __bf16* HqS_l = (__bf16*)take(3145728);
    __bf16* c1_h  = (__bf16*)take(6291456);   // Hps@W9 ld 768
    __bf16* c1_l  = (__bf16*)take(6291456);
    __bf16* c4_h  = (__bf16*)take(4718592);   // Ho@W10 ld 768
    __bf16* c4_l  = (__bf16*)take(4718592);
    __bf16* Ho_h  = (__bf16*)take(4718592);
    __bf16* Ho_l  = (__bf16*)take(4718592);
    __bf16* hats_h = (__bf16*)take(14155776);
    __bf16* hats_l = (__bf16*)take(14155776);
    __bf16* bar_h  = (__bf16*)take(4718592);
    __bf16* HqS2_bf   = (__bf16*)take(3145728);   // [HqW11|HqW12] ld 1536
    __bf16* HpsW12_bf = (__bf16*)take(6291456);   // ld 768
    __bf16* HoW11_bf  = (__bf16*)take(4718592);   // ld 768
    __bf16* S_h    = (__bf16*)take(884736);
    // fp32 buffers
    float* bar  = (float*)take(9437184);
    float* gt   = (float*)take(9437184);
    float* G2   = (float*)take(884736);
    float* Gm   = (float*)take(5111808);
    float* S    = (float*)take(1769472);
    float* gts  = (float*)take(884736);

    dim3 blk(256);

    // prep + converts
    prep_kernel<<<25344, blk, 0, stream>>>(W5, W6, W7, W8, W9, W10, W11, W12, W13, W14,
                                           W5t_h, W5t_l, WsQT_h, WsQT_l, W6t_h, W6t_l,
                                           W1112T, W78t, W1314t);
    cvt2_kernel<<<9216, blk, 0, stream>>>(Ha, Ha_h, Ha_l, 2359296);
    cvt2_kernel<<<3072, blk, 0, stream>>>(Hq, Hq_h, Hq_l, 786432);

    // stage 1
    rnorm_kernel<<<3072, blk, 0, stream>>>(Ha, ra);
    rnorm_kernel<<<1024, blk, 0, stream>>>(Hq, rq);
    simmax_kernel<<<1024, blk, 0, stream>>>(Hp, Ha_h, Ha_l, Hq_h, Hq_l, ra, rq, amax);
    score_top2_kernel<<<32, dim3(64), 0, stream>>>(amax, topidx);
    gather_kernel<<<12288, blk, 0, stream>>>(Hp, topidx, Hps_h, Hps_l);

    // score-feeding caches (bf16x3, h/l outputs)
    mgemm3_kernel<2><<<dim3(48, 12), blk, 0, stream>>>(Ha_h, Ha_l, 768, 3072, W5t_h, W5t_l, nullptr, 768, C1_h, C1_l);
    mgemm3_kernel<2><<<dim3(16, 24), blk, 0, stream>>>(Hq_h, Hq_l, 768, 1024, WsQT_h, WsQT_l, nullptr, 1536, HqS_h, HqS_l);
    mgemm3_kernel<2><<<dim3(64, 12), blk, 0, stream>>>(Hps_h, Hps_l, 768, 4096, WsQT_h, WsQT_l, nullptr, 768, c1_h, c1_l);
    // S-path products (plain bf16, bf16 out)
    mgemm_kernel<0, 1><<<dim3(16, 24), blk, 0, stream>>>(Hq_h, 768, 1024, W1112T, nullptr, nullptr, 1536, HqS2_bf);
    mgemm_kernel<0, 1><<<dim3(64, 12), blk, 0, stream>>>(Hps_h, 768, 4096, W1112T + (long)768 * 768, nullptr, nullptr, 768, HpsW12_bf);

    // stage-2 QK (12 segs 24x24, MFMA bf16x3 + softmax)
    {
        QMArgs qa{}; int si = 0;
        for (int i = 0; i < 4; i++)
            for (int j = 0; j < 4; j++) {
                if (j == i) continue;
                QMSeg& s = qa.s[si];
                s.GLh = C1_h + (long)i * 24 * 768; s.GLl = C1_l + (long)i * 24 * 768;
                s.HYh = Ha_h + (long)j * 24 * 768; s.HYl = Ha_l + (long)j * 24 * 768;
                s.G = G2 + (long)si * 18432;
                s.glB = 73728; s.hyB = 73728; s.gB = 576;
                s.ldGL = 768; s.ldHY = 768; s.shape = 0;
                si++;
            }
        qkm_kernel<<<12 * 32, blk, 0, stream>>>(qa);
    }
    // hats (12 segs, MFMA bf16x3 -> hi/lo bf16)
    {
        HArgs ha{}; int si = 0;
        for (int i = 0; i < 4; i++) {
            int jj = 0;
            for (int j = 0; j < 4; j++) {
                if (j == i) continue;
                HSeg& s = ha.s[si];
                s.G = G2 + (long)si * 18432; s.gB = 576;
                s.Bh = Ha_h + (long)j * 24 * 768; s.Bl = Ha_l + (long)j * 24 * 768; s.bB = 73728;
                s.outH = hats_h + (long)i * 24 * 2304 + jj * 768;
                s.outL = hats_l + (long)i * 24 * 2304 + jj * 768;
                s.oB = 221184;
                si++; jj++;
            }
        }
        gbm_hats_kernel<<<12 * 32, blk, 0, stream>>>(ha);
    }
    // bar = hats@W6 (bf16x3, f32 + hi out); gt = bar@W78 + b8; Ho (h/l only)
    mgemm3_kernel<1><<<dim3(48, 12), blk, 0, stream>>>(hats_h, hats_l, 2304, 3072, W6t_h, W6t_l, bar, 768, bar_h, nullptr);
    mgemm_kernel<1, 0><<<dim3(48, 12), blk, 0, stream>>>(bar_h, 768, 3072, W78t, b8, gt, 768, nullptr);
    hogate_kernel<<<9216, blk, 0, stream>>>(gt, bar, Ha, Ho_h, Ho_l);
    // cache4 = Ho@W10 (bf16x3 h/l); HoW11 (plain)
    mgemm3_kernel<2><<<dim3(48, 12), blk, 0, stream>>>(Ho_h, Ho_l, 768, 3072, WsQT_h + (long)768 * 768, WsQT_l + (long)768 * 768, nullptr, 768, c4_h, c4_l);
    mgemm_kernel<0, 1><<<dim3(48, 12), blk, 0, stream>>>(Ho_h, 768, 3072, W1112T, nullptr, nullptr, 768, HoW11_bf);

    // match G offsets (floats, within Gm)
    const long gA0 = 0, gA1 = 131072, gA5 = 524288, gA9 = 622592, gB0 = 720896, gB1 = 851968;

    // match QK (18 segs, MFMA bf16x3 + softmax)
    {
        QMArgs qa{};
        auto set = [&](int k, const __bf16* GLh, const __bf16* GLl, int glB, int ldGL,
                       const __bf16* HYh, const __bf16* HYl, int hyB, int ldHY,
                       float* G, int gB, int shape) {
            QMSeg& s = qa.s[k];
            s.GLh = GLh; s.GLl = GLl; s.HYh = HYh; s.HYl = HYl; s.G = G;
            s.glB = glB; s.hyB = hyB; s.gB = gB; s.ldGL = ldGL; s.ldHY = ldHY; s.shape = shape;
        };
        set(0, c1_h, c1_l, 98304, 768, Hq_h, Hq_l, 24576, 768, Gm + gA0, 4096, 1);            // (128,32)
        for (int i = 0; i < 4; i++) {
            set(1 + i, c1_h, c1_l, 98304, 768,
                Ho_h + (long)i * 24 * 768, Ho_l + (long)i * 24 * 768, 73728, 768,
                Gm + gA1 + (long)i * 98304, 3072, 2);                                          // (128,24)
            set(5 + i, HqS_h, HqS_l, 49152, 1536,
                Ho_h + (long)i * 24 * 768, Ho_l + (long)i * 24 * 768, 73728, 768,
                Gm + gA5 + (long)i * 24576, 768, 3);                                           // (32,24)
            set(9 + i, c4_h + (long)i * 24 * 768, c4_l + (long)i * 24 * 768, 73728, 768,
                Hq_h, Hq_l, 24576, 768,
                Gm + gA9 + (long)i * 24576, 768, 4);                                           // (24,32)
        }
        set(13, HqS_h + 768, HqS_l + 768, 49152, 1536, Hps_h, Hps_l, 98304, 768,
            Gm + gB0, 4096, 5);                                                                // (32,128)
        for (int i = 0; i < 4; i++)
            set(14 + i, c4_h + (long)i * 24 * 768, c4_l + (long)i * 24 * 768, 73728, 768,
                Hps_h, Hps_l, 98304, 768, Gm + gB1 + (long)i * 98304, 3072, 6);                // (24,128)
        qkm_kernel<<<18 * 32, blk, 0, stream>>>(qa);
    }
    // S (18 segs, MFMA colmax)
    {
        SArgs2 sa{};
        auto set = [&](int k, const float* G, long gB, const __bf16* Bp, long bB, int ldB,
                       float* oF, __bf16* oH, int shape) {
            SSeg2& s = sa.s[k];
            s.G = G; s.gB = gB; s.B = Bp; s.bB = bB; s.ldB = ldB;
            s.outF = oF; s.outH = oH; s.oB = 1536; s.shape = shape;
        };
        set(0, Gm + gA0, 4096, HqS2_bf, 49152, 1536, S, S_h, 0);                       // 128x32
        for (int i = 0; i < 4; i++) {
            set(1 + i, Gm + gA1 + (long)i * 98304, 3072, HoW11_bf + (long)i * 24 * 768, 73728, 768,
                S + (long)(1 + i) * 49152, S_h + (long)(1 + i) * 49152, 1);            // 128x24
            set(5 + i, Gm + gA5 + (long)i * 24576, 768, HoW11_bf + (long)i * 24 * 768, 73728, 768,
                S + (long)(5 + i) * 49152, S_h + (long)(5 + i) * 49152, 2);            // 32x24
        }
        set(9, Gm + gB0, 4096, HpsW12_bf, 98304, 768, S + 768, S_h + 768, 3);          // 32x128
        for (int i = 0; i < 4; i++) {
            set(10 + i, Gm + gB1 + (long)i * 98304, 3072, HpsW12_bf, 98304, 768,
                S + (long)(1 + i) * 49152 + 768, S_h + (long)(1 + i) * 49152 + 768, 4); // 24x128
            set(14 + i, Gm + gA9 + (long)i * 24576, 768, HqS2_bf + 768, 49152, 1536,
                S + (long)(5 + i) * 49152 + 768, S_h + (long)(5 + i) * 49152 + 768, 5); // 24x32
        }
        gbm_s_kernel<<<18 * 32, blk, 0, stream>>>(sa);
    }

    // gating: gts = [Sxy|Syx] @ [W13;W14] + b14 (plain bf16 MFMA)
    mgemm_kernel<1, 0><<<dim3(5, 12), blk, 0, stream>>>(S_h, 1536, 288, W1314t, b14, gts, 768, nullptr);

    logits_kernel<<<128, blk, 0, stream>>>(S, gts, V, lg);
    lsm_kernel<<<1, dim3(32), 0, stream>>>(lg, out);
}